// Round 3
// baseline (19548.445 us; speedup 1.0000x reference)
//
#include <hip/hip_runtime.h>
#include <math.h>

#define BB 4
#define SEQ 512
#define TGT 256
#define DM 512
#define FFD 2048
#define NH 8
#define HD 64
#define NL 6

// ---------------- GEMM: C[M,N] = relu?(alpha*(A @ W^T + bias)) + resid ----------------
// A: M x K (row-major, fp32), W: N x K (row-major, fp32), bias: N (fp32)
template <int RELU>
__global__ __launch_bounds__(256) void gemm_k(
    const float* __restrict__ A, const float* __restrict__ W,
    const float* __restrict__ bias, const float* __restrict__ resid,
    float* __restrict__ C, int M, int N, int K, float alpha)
{
    const int BM = 64, BN = 64, BK = 16;
    __shared__ float As[BM][BK + 1];
    __shared__ float Ws[BN][BK + 1];
    int bm = blockIdx.y * BM, bn = blockIdx.x * BN;
    int tid = threadIdx.x;
    int tr = tid >> 4, tc = tid & 15;
    float acc[4][4] = {};
    for (int k0 = 0; k0 < K; k0 += BK) {
        for (int i = tid; i < BM * BK; i += 256) {
            int r = i >> 4, c = i & 15;
            int gr = bm + r, gc = k0 + c;
            As[r][c] = (gr < M) ? A[(size_t)gr * K + gc] : 0.f;
        }
        for (int i = tid; i < BN * BK; i += 256) {
            int r = i >> 4, c = i & 15;
            int gr = bn + r, gc = k0 + c;
            Ws[r][c] = (gr < N) ? W[(size_t)gr * K + gc] : 0.f;
        }
        __syncthreads();
#pragma unroll
        for (int kk = 0; kk < BK; kk++) {
            float a[4], w[4];
#pragma unroll
            for (int i = 0; i < 4; i++) a[i] = As[tr * 4 + i][kk];
#pragma unroll
            for (int j = 0; j < 4; j++) w[j] = Ws[tc * 4 + j][kk];
#pragma unroll
            for (int i = 0; i < 4; i++)
#pragma unroll
                for (int j = 0; j < 4; j++) acc[i][j] = fmaf(a[i], w[j], acc[i][j]);
        }
        __syncthreads();
    }
#pragma unroll
    for (int i = 0; i < 4; i++) {
        int gr = bm + tr * 4 + i;
        if (gr >= M) continue;
#pragma unroll
        for (int j = 0; j < 4; j++) {
            int gc = bn + tc * 4 + j;
            if (gc >= N) continue;
            float v = (acc[i][j] + bias[gc]) * alpha;
            if (RELU) v = fmaxf(v, 0.f);
            if (resid) v += resid[(size_t)gr * N + gc];
            C[(size_t)gr * N + gc] = v;
        }
    }
}

// ---------------- positional encodings ----------------
__global__ void add_pe_enc(float* __restrict__ x)
{
    int idx = blockIdx.x * blockDim.x + threadIdx.x;
    if (idx >= BB * SEQ * DM) return;
    int c = idx % DM;
    int s = (idx / DM) % SEQ;
    float dv = expf((float)(c & ~1) * (-9.210340371976184f / (float)DM));
    float ang = (float)s * dv;
    x[idx] += (c & 1) ? cosf(ang) : sinf(ang);
}

__global__ void add_pe_dec(float* __restrict__ x, int n)
{
    int idx = blockIdx.x * blockDim.x + threadIdx.x;
    if (idx >= n) return;
    // pe(1,d)[0]: sin(0)=0 on even, cos(0)=1 on odd channels
    if (idx & 1) x[idx] += 1.f;
}

// ---------------- layernorm (row of DM=512, block=256) ----------------
__global__ __launch_bounds__(256) void ln_k(float* __restrict__ x,
                                            const float* __restrict__ g,
                                            const float* __restrict__ b)
{
    int row = blockIdx.x;
    float* xr = x + (size_t)row * DM;
    int tid = threadIdx.x;
    float v0 = xr[tid], v1 = xr[tid + 256];
    __shared__ float red[256];
    red[tid] = v0 + v1;
    __syncthreads();
    for (int st = 128; st > 0; st >>= 1) {
        if (tid < st) red[tid] += red[tid + st];
        __syncthreads();
    }
    float mean = red[0] * (1.f / DM);
    __syncthreads();
    float d0 = v0 - mean, d1 = v1 - mean;
    red[tid] = d0 * d0 + d1 * d1;
    __syncthreads();
    for (int st = 128; st > 0; st >>= 1) {
        if (tid < st) red[tid] += red[tid + st];
        __syncthreads();
    }
    float rstd = rsqrtf(red[0] * (1.f / DM) + 1e-5f);
    xr[tid]       = d0 * rstd * g[tid]       + b[tid];
    xr[tid + 256] = d1 * rstd * g[tid + 256] + b[tid + 256];
}

// ---------------- attention: scores, softmax, AV ----------------
__global__ void scores_k(const float* __restrict__ Q, const float* __restrict__ Km,
                         float* __restrict__ S, int Sq, int Sk, int causal)
{
    int idx = blockIdx.x * blockDim.x + threadIdx.x;
    int total = BB * NH * Sq * Sk;
    if (idx >= total) return;
    int kx = idx % Sk;
    int qx = (idx / Sk) % Sq;
    int h  = (idx / (Sk * Sq)) % NH;
    int b  = idx / (Sk * Sq * NH);
    if (causal && kx > qx) { S[idx] = -1e9f; return; }
    const float* qp = Q + ((size_t)(b * Sq + qx)) * DM + h * HD;
    const float* kp = Km + ((size_t)(b * Sk + kx)) * DM + h * HD;
    float acc = 0.f;
#pragma unroll
    for (int d = 0; d < HD; d++) acc = fmaf(qp[d], kp[d], acc);
    S[idx] = acc * 0.125f;  // 1/sqrt(64)
}

__global__ __launch_bounds__(256) void softmax_k(float* __restrict__ S, int Sk)
{
    float* row = S + (size_t)blockIdx.x * Sk;
    int tid = threadIdx.x;
    __shared__ float red[256];
    float m = -1e30f;
    for (int c = tid; c < Sk; c += 256) m = fmaxf(m, row[c]);
    red[tid] = m;
    __syncthreads();
    for (int st = 128; st > 0; st >>= 1) {
        if (tid < st) red[tid] = fmaxf(red[tid], red[tid + st]);
        __syncthreads();
    }
    m = red[0];
    __syncthreads();
    float s = 0.f;
    for (int c = tid; c < Sk; c += 256) {
        float e = expf(row[c] - m);
        row[c] = e;
        s += e;
    }
    red[tid] = s;
    __syncthreads();
    for (int st = 128; st > 0; st >>= 1) {
        if (tid < st) red[tid] += red[tid + st];
        __syncthreads();
    }
    float inv = 1.f / red[0];
    for (int c = tid; c < Sk; c += 256) row[c] *= inv;
}

__global__ void av_k(const float* __restrict__ S, const float* __restrict__ V,
                     float* __restrict__ O, int Sq, int Sk)
{
    int idx = blockIdx.x * blockDim.x + threadIdx.x;
    int total = BB * Sq * DM;
    if (idx >= total) return;
    int dd = idx % HD;
    int h  = (idx / HD) % NH;
    int qx = (idx / DM) % Sq;
    int b  = idx / (DM * Sq);
    const float* srow = S + ((size_t)(b * NH + h) * Sq + qx) * Sk;
    const float* vp = V + (size_t)b * Sk * DM + h * HD + dd;
    float acc = 0.f;
    for (int kx = 0; kx < Sk; kx++) acc = fmaf(srow[kx], vp[(size_t)kx * DM], acc);
    O[idx] = acc;
}

// ---------------- host orchestration ----------------
static inline dim3 gg(int M, int N) { return dim3((N + 63) / 64, (M + 63) / 64); }

extern "C" void kernel_launch(void* const* d_in, const int* in_sizes, int n_in,
                              void* d_out, int out_size, void* d_ws, size_t ws_size,
                              hipStream_t stream)
{
    const float* src       = (const float*)d_in[0];
    const float* tgt       = (const float*)d_in[1];
    const float* enc_in_w  = (const float*)d_in[2];
    const float* enc_in_b  = (const float*)d_in[3];
    const float* dec_in_w  = (const float*)d_in[4];
    const float* dec_in_b  = (const float*)d_in[5];
    const float* out_w     = (const float*)d_in[6];
    const float* out_b     = (const float*)d_in[7];
    const float* enc_attn_w = (const float*)d_in[8];
    const float* enc_attn_b = (const float*)d_in[9];
    const float* enc_out_w  = (const float*)d_in[10];
    const float* enc_out_b  = (const float*)d_in[11];
    const float* enc_ff1_w  = (const float*)d_in[12];
    const float* enc_ff1_b  = (const float*)d_in[13];
    const float* enc_ff2_w  = (const float*)d_in[14];
    const float* enc_ff2_b  = (const float*)d_in[15];
    const float* enc_ln1_g  = (const float*)d_in[16];
    const float* enc_ln1_b  = (const float*)d_in[17];
    const float* enc_ln2_g  = (const float*)d_in[18];
    const float* enc_ln2_b  = (const float*)d_in[19];
    const float* dec_sa_w     = (const float*)d_in[20];
    const float* dec_sa_b     = (const float*)d_in[21];
    const float* dec_sa_out_w = (const float*)d_in[22];
    const float* dec_sa_out_b = (const float*)d_in[23];
    const float* dec_ca_w     = (const float*)d_in[24];
    const float* dec_ca_b     = (const float*)d_in[25];
    const float* dec_ca_out_w = (const float*)d_in[26];
    const float* dec_ca_out_b = (const float*)d_in[27];
    const float* dec_ff1_w    = (const float*)d_in[28];
    const float* dec_ff1_b    = (const float*)d_in[29];
    const float* dec_ff2_w    = (const float*)d_in[30];
    const float* dec_ff2_b    = (const float*)d_in[31];
    const float* dec_ln1_g    = (const float*)d_in[32];
    const float* dec_ln1_b    = (const float*)d_in[33];
    const float* dec_ln2_g    = (const float*)d_in[34];
    const float* dec_ln2_b    = (const float*)d_in[35];
    const float* dec_ln3_g    = (const float*)d_in[36];
    const float* dec_ln3_b    = (const float*)d_in[37];

    // workspace layout (fp32)
    float* p = (float*)d_ws;
    float* x0  = p; p += (size_t)BB * SEQ * DM;
    float* x1  = p; p += (size_t)BB * SEQ * DM;
    float* qb  = p; p += (size_t)BB * SEQ * DM;
    float* kb  = p; p += (size_t)BB * SEQ * DM;
    float* vb  = p; p += (size_t)BB * SEQ * DM;
    float* tb  = p; p += (size_t)BB * SEQ * DM;
    float* ffb = p; p += (size_t)BB * SEQ * FFD;
    float* sc  = p; p += (size_t)BB * NH * SEQ * SEQ;
    float* y0  = p; p += (size_t)BB * TGT * DM;
    float* y1  = p; p += (size_t)BB * TGT * DM;

    const float SQD = 22.627416997969522f;  // sqrt(512)
    const int ME = BB * SEQ;  // 2048 encoder rows
    const int MD = BB * TGT;  // 1024 decoder rows

    // ===== encoder =====
    gemm_k<0><<<gg(ME, DM), 256, 0, stream>>>(src, enc_in_w, enc_in_b, nullptr, x0, ME, DM, HD, SQD);
    add_pe_enc<<<(ME * DM + 255) / 256, 256, 0, stream>>>(x0);

    float* cur = x0; float* alt = x1;
    for (int i = 0; i < NL; i++) {
        const float* W  = enc_attn_w + (size_t)i * 3 * DM * DM;
        const float* Bw = enc_attn_b + (size_t)i * 3 * DM;
        gemm_k<0><<<gg(ME, DM), 256, 0, stream>>>(cur, W,               Bw,          nullptr, qb, ME, DM, DM, 1.f);
        gemm_k<0><<<gg(ME, DM), 256, 0, stream>>>(cur, W + DM * DM,     Bw + DM,     nullptr, kb, ME, DM, DM, 1.f);
        gemm_k<0><<<gg(ME, DM), 256, 0, stream>>>(cur, W + 2 * DM * DM, Bw + 2 * DM, nullptr, vb, ME, DM, DM, 1.f);
        int tot = BB * NH * SEQ * SEQ;
        scores_k<<<(tot + 255) / 256, 256, 0, stream>>>(qb, kb, sc, SEQ, SEQ, 0);
        softmax_k<<<BB * NH * SEQ, 256, 0, stream>>>(sc, SEQ);
        av_k<<<(ME * DM + 255) / 256, 256, 0, stream>>>(sc, vb, tb, SEQ, SEQ);
        gemm_k<0><<<gg(ME, DM), 256, 0, stream>>>(tb, enc_out_w + (size_t)i * DM * DM, enc_out_b + (size_t)i * DM, cur, alt, ME, DM, DM, 1.f);
        ln_k<<<ME, 256, 0, stream>>>(alt, enc_ln1_g + (size_t)i * DM, enc_ln1_b + (size_t)i * DM);
        { float* t = cur; cur = alt; alt = t; }
        gemm_k<1><<<gg(ME, FFD), 256, 0, stream>>>(cur, enc_ff1_w + (size_t)i * FFD * DM, enc_ff1_b + (size_t)i * FFD, nullptr, ffb, ME, FFD, DM, 1.f);
        gemm_k<0><<<gg(ME, DM), 256, 0, stream>>>(ffb, enc_ff2_w + (size_t)i * DM * FFD, enc_ff2_b + (size_t)i * DM, cur, alt, ME, DM, FFD, 1.f);
        ln_k<<<ME, 256, 0, stream>>>(alt, enc_ln2_g + (size_t)i * DM, enc_ln2_b + (size_t)i * DM);
        { float* t = cur; cur = alt; alt = t; }
    }
    float* mem = cur;  // == x0 (even number of swaps)

    // ===== decoder =====
    gemm_k<0><<<gg(MD, DM), 256, 0, stream>>>(tgt, dec_in_w, dec_in_b, nullptr, y0, MD, DM, HD, SQD);
    add_pe_dec<<<(MD * DM + 255) / 256, 256, 0, stream>>>(y0, MD * DM);

    float* dc = y0; float* da = y1;
    for (int i = 0; i < NL; i++) {
        // self-attention (causal)
        const float* W  = dec_sa_w + (size_t)i * 3 * DM * DM;
        const float* Bw = dec_sa_b + (size_t)i * 3 * DM;
        gemm_k<0><<<gg(MD, DM), 256, 0, stream>>>(dc, W,               Bw,          nullptr, qb, MD, DM, DM, 1.f);
        gemm_k<0><<<gg(MD, DM), 256, 0, stream>>>(dc, W + DM * DM,     Bw + DM,     nullptr, kb, MD, DM, DM, 1.f);
        gemm_k<0><<<gg(MD, DM), 256, 0, stream>>>(dc, W + 2 * DM * DM, Bw + 2 * DM, nullptr, vb, MD, DM, DM, 1.f);
        int tot = BB * NH * TGT * TGT;
        scores_k<<<(tot + 255) / 256, 256, 0, stream>>>(qb, kb, sc, TGT, TGT, 1);
        softmax_k<<<BB * NH * TGT, 256, 0, stream>>>(sc, TGT);
        av_k<<<(MD * DM + 255) / 256, 256, 0, stream>>>(sc, vb, tb, TGT, TGT);
        gemm_k<0><<<gg(MD, DM), 256, 0, stream>>>(tb, dec_sa_out_w + (size_t)i * DM * DM, dec_sa_out_b + (size_t)i * DM, dc, da, MD, DM, DM, 1.f);
        ln_k<<<MD, 256, 0, stream>>>(da, dec_ln1_g + (size_t)i * DM, dec_ln1_b + (size_t)i * DM);
        { float* t = dc; dc = da; da = t; }

        // cross-attention (q from decoder, k/v from encoder memory)
        const float* Wc  = dec_ca_w + (size_t)i * 3 * DM * DM;
        const float* Bc  = dec_ca_b + (size_t)i * 3 * DM;
        gemm_k<0><<<gg(MD, DM), 256, 0, stream>>>(dc,  Wc,               Bc,          nullptr, qb, MD, DM, DM, 1.f);
        gemm_k<0><<<gg(ME, DM), 256, 0, stream>>>(mem, Wc + DM * DM,     Bc + DM,     nullptr, kb, ME, DM, DM, 1.f);
        gemm_k<0><<<gg(ME, DM), 256, 0, stream>>>(mem, Wc + 2 * DM * DM, Bc + 2 * DM, nullptr, vb, ME, DM, DM, 1.f);
        tot = BB * NH * TGT * SEQ;
        scores_k<<<(tot + 255) / 256, 256, 0, stream>>>(qb, kb, sc, TGT, SEQ, 0);
        softmax_k<<<BB * NH * TGT, 256, 0, stream>>>(sc, SEQ);
        av_k<<<(MD * DM + 255) / 256, 256, 0, stream>>>(sc, vb, tb, TGT, SEQ);
        gemm_k<0><<<gg(MD, DM), 256, 0, stream>>>(tb, dec_ca_out_w + (size_t)i * DM * DM, dec_ca_out_b + (size_t)i * DM, dc, da, MD, DM, DM, 1.f);
        ln_k<<<MD, 256, 0, stream>>>(da, dec_ln2_g + (size_t)i * DM, dec_ln2_b + (size_t)i * DM);
        { float* t = dc; dc = da; da = t; }

        // feed-forward
        gemm_k<1><<<gg(MD, FFD), 256, 0, stream>>>(dc, dec_ff1_w + (size_t)i * FFD * DM, dec_ff1_b + (size_t)i * FFD, nullptr, ffb, MD, FFD, DM, 1.f);
        gemm_k<0><<<gg(MD, DM), 256, 0, stream>>>(ffb, dec_ff2_w + (size_t)i * DM * FFD, dec_ff2_b + (size_t)i * DM, dc, da, MD, DM, FFD, 1.f);
        ln_k<<<MD, 256, 0, stream>>>(da, dec_ln3_g + (size_t)i * DM, dec_ln3_b + (size_t)i * DM);
        { float* t = dc; dc = da; da = t; }
    }

    // ===== final projection (fp32 straight into d_out) =====
    gemm_k<0><<<gg(MD, HD), 256, 0, stream>>>(dc, out_w, out_b, nullptr, (float*)d_out, MD, HD, DM, 1.f);
}

// Round 4
// 9414.832 us; speedup vs baseline: 2.0763x; 2.0763x over previous
//
#include <hip/hip_runtime.h>
#include <hip/hip_bf16.h>
#include <math.h>

#define BB 4
#define SEQ 512
#define TGT 256
#define DM 512
#define FFD 2048
#define NH 8
#define HD 64
#define NL 6

typedef __attribute__((ext_vector_type(4))) float f4;
typedef __attribute__((ext_vector_type(4))) unsigned short us4;
typedef __attribute__((ext_vector_type(8))) short s8;

__device__ inline unsigned short f2b(float f) {
    __hip_bfloat16 h = __float2bfloat16(f);
    return *reinterpret_cast<unsigned short*>(&h);
}

// ============ MFMA GEMM: C[M,N] = relu?(alpha*(A @ W^T + bias)) + resid ============
// A: M x K fp32 row-major, W: N x K fp32 row-major. Requires M%128==0, N%128==0, K%32==0.
// 256 threads = 4 waves; block tile 128x128, BK=32; wave tile 64x64 = 4x4 MFMA 16x16x32 bf16.
template <int RELU>
__global__ __launch_bounds__(256) void mgemm_k(
    const float* __restrict__ A, const float* __restrict__ W,
    const float* __restrict__ bias, const float* __restrict__ resid,
    float* __restrict__ C, int M, int N, int K, float alpha)
{
    __shared__ unsigned short As[128][40];   // +8 pad: 80B row, 16B-aligned fragments
    __shared__ unsigned short Bs[128][40];
    const int bm = blockIdx.y * 128, bn = blockIdx.x * 128;
    const int tid = threadIdx.x;
    const int wave = tid >> 6, lane = tid & 63;
    const int wr = (wave >> 1) * 64, wc = (wave & 1) * 64;
    const int lm = lane & 15, quad = lane >> 4;
    const int sr = tid >> 3, scv = (tid & 7) * 4;   // staging: 32 rows/pass, 8 float4 per row

    f4 acc[4][4];
#pragma unroll
    for (int i = 0; i < 4; i++)
#pragma unroll
        for (int j = 0; j < 4; j++) acc[i][j] = (f4)(0.f);

    for (int k0 = 0; k0 < K; k0 += 32) {
#pragma unroll
        for (int pass = 0; pass < 4; pass++) {
            int r = pass * 32 + sr;
            f4 va = *(const f4*)(A + (size_t)(bm + r) * K + k0 + scv);
            f4 vb = *(const f4*)(W + (size_t)(bn + r) * K + k0 + scv);
            us4 ua, ub;
            ua.x = f2b(va.x); ua.y = f2b(va.y); ua.z = f2b(va.z); ua.w = f2b(va.w);
            ub.x = f2b(vb.x); ub.y = f2b(vb.y); ub.z = f2b(vb.z); ub.w = f2b(vb.w);
            *(us4*)&As[r][scv] = ua;
            *(us4*)&Bs[r][scv] = ub;
        }
        __syncthreads();
        s8 af[4], bfr[4];
#pragma unroll
        for (int i = 0; i < 4; i++) af[i] = *(const s8*)&As[wr + i * 16 + lm][quad * 8];
#pragma unroll
        for (int j = 0; j < 4; j++) bfr[j] = *(const s8*)&Bs[wc + j * 16 + lm][quad * 8];
#pragma unroll
        for (int i = 0; i < 4; i++)
#pragma unroll
            for (int j = 0; j < 4; j++)
                acc[i][j] = __builtin_amdgcn_mfma_f32_16x16x32_bf16(af[i], bfr[j], acc[i][j], 0, 0, 0);
        __syncthreads();
    }

#pragma unroll
    for (int j = 0; j < 4; j++) {
        int n = bn + wc + j * 16 + lm;
        float bv = bias[n];
#pragma unroll
        for (int i = 0; i < 4; i++) {
#pragma unroll
            for (int r = 0; r < 4; r++) {
                int m = bm + wr + i * 16 + quad * 4 + r;
                float v = (acc[i][j][r] + bv) * alpha;
                if (RELU) v = fmaxf(v, 0.f);
                size_t off = (size_t)m * N + n;
                if (resid) v += resid[off];
                C[off] = v;
            }
        }
    }
}

// ============ small vector GEMM (final projection, N=64) ============
template <int RELU>
__global__ __launch_bounds__(256) void gemm_k(
    const float* __restrict__ A, const float* __restrict__ W,
    const float* __restrict__ bias, const float* __restrict__ resid,
    float* __restrict__ C, int M, int N, int K, float alpha)
{
    const int BM = 64, BN = 64, BK = 16;
    __shared__ float As[BM][BK + 1];
    __shared__ float Ws[BN][BK + 1];
    int bm = blockIdx.y * BM, bn = blockIdx.x * BN;
    int tid = threadIdx.x;
    int tr = tid >> 4, tc = tid & 15;
    float acc[4][4] = {};
    for (int k0 = 0; k0 < K; k0 += BK) {
        for (int i = tid; i < BM * BK; i += 256) {
            int r = i >> 4, c = i & 15;
            int gr = bm + r, gc = k0 + c;
            As[r][c] = (gr < M) ? A[(size_t)gr * K + gc] : 0.f;
        }
        for (int i = tid; i < BN * BK; i += 256) {
            int r = i >> 4, c = i & 15;
            int gr = bn + r, gc = k0 + c;
            Ws[r][c] = (gr < N) ? W[(size_t)gr * K + gc] : 0.f;
        }
        __syncthreads();
#pragma unroll
        for (int kk = 0; kk < BK; kk++) {
            float a[4], w[4];
#pragma unroll
            for (int i = 0; i < 4; i++) a[i] = As[tr * 4 + i][kk];
#pragma unroll
            for (int j = 0; j < 4; j++) w[j] = Ws[tc * 4 + j][kk];
#pragma unroll
            for (int i = 0; i < 4; i++)
#pragma unroll
                for (int j = 0; j < 4; j++) acc[i][j] = fmaf(a[i], w[j], acc[i][j]);
        }
        __syncthreads();
    }
#pragma unroll
    for (int i = 0; i < 4; i++) {
        int gr = bm + tr * 4 + i;
        if (gr >= M) continue;
#pragma unroll
        for (int j = 0; j < 4; j++) {
            int gc = bn + tc * 4 + j;
            if (gc >= N) continue;
            float v = (acc[i][j] + bias[gc]) * alpha;
            if (RELU) v = fmaxf(v, 0.f);
            if (resid) v += resid[(size_t)gr * N + gc];
            C[(size_t)gr * N + gc] = v;
        }
    }
}

// ---------------- positional encodings ----------------
__global__ void add_pe_enc(float* __restrict__ x)
{
    int idx = blockIdx.x * blockDim.x + threadIdx.x;
    if (idx >= BB * SEQ * DM) return;
    int c = idx % DM;
    int s = (idx / DM) % SEQ;
    float dv = expf((float)(c & ~1) * (-9.210340371976184f / (float)DM));
    float ang = (float)s * dv;
    x[idx] += (c & 1) ? cosf(ang) : sinf(ang);
}

__global__ void add_pe_dec(float* __restrict__ x, int n)
{
    int idx = blockIdx.x * blockDim.x + threadIdx.x;
    if (idx >= n) return;
    if (idx & 1) x[idx] += 1.f;
}

// ---------------- layernorm (row of DM=512, block=256) ----------------
__global__ __launch_bounds__(256) void ln_k(float* __restrict__ x,
                                            const float* __restrict__ g,
                                            const float* __restrict__ b)
{
    int row = blockIdx.x;
    float* xr = x + (size_t)row * DM;
    int tid = threadIdx.x;
    float v0 = xr[tid], v1 = xr[tid + 256];
    __shared__ float red[256];
    red[tid] = v0 + v1;
    __syncthreads();
    for (int st = 128; st > 0; st >>= 1) {
        if (tid < st) red[tid] += red[tid + st];
        __syncthreads();
    }
    float mean = red[0] * (1.f / DM);
    __syncthreads();
    float d0 = v0 - mean, d1 = v1 - mean;
    red[tid] = d0 * d0 + d1 * d1;
    __syncthreads();
    for (int st = 128; st > 0; st >>= 1) {
        if (tid < st) red[tid] += red[tid + st];
        __syncthreads();
    }
    float rstd = rsqrtf(red[0] * (1.f / DM) + 1e-5f);
    xr[tid]       = d0 * rstd * g[tid]       + b[tid];
    xr[tid + 256] = d1 * rstd * g[tid + 256] + b[tid + 256];
}

// ---------------- attention: scores, softmax, AV (strided Q/K/V) ----------------
__global__ void scores_k(const float* __restrict__ Q, int qs,
                         const float* __restrict__ Km, int ks,
                         float* __restrict__ S, int Sq, int Sk, int causal)
{
    int idx = blockIdx.x * blockDim.x + threadIdx.x;
    int total = BB * NH * Sq * Sk;
    if (idx >= total) return;
    int kx = idx % Sk;
    int qx = (idx / Sk) % Sq;
    int h  = (idx / (Sk * Sq)) % NH;
    int b  = idx / (Sk * Sq * NH);
    if (causal && kx > qx) { S[idx] = -1e9f; return; }
    const float* qp = Q + (size_t)(b * Sq + qx) * qs + h * HD;
    const float* kp = Km + (size_t)(b * Sk + kx) * ks + h * HD;
    float acc = 0.f;
#pragma unroll
    for (int d = 0; d < HD; d++) acc = fmaf(qp[d], kp[d], acc);
    S[idx] = acc * 0.125f;
}

__global__ __launch_bounds__(256) void softmax_k(float* __restrict__ S, int Sk)
{
    float* row = S + (size_t)blockIdx.x * Sk;
    int tid = threadIdx.x;
    __shared__ float red[256];
    float m = -1e30f;
    for (int c = tid; c < Sk; c += 256) m = fmaxf(m, row[c]);
    red[tid] = m;
    __syncthreads();
    for (int st = 128; st > 0; st >>= 1) {
        if (tid < st) red[tid] = fmaxf(red[tid], red[tid + st]);
        __syncthreads();
    }
    m = red[0];
    __syncthreads();
    float s = 0.f;
    for (int c = tid; c < Sk; c += 256) {
        float e = expf(row[c] - m);
        row[c] = e;
        s += e;
    }
    red[tid] = s;
    __syncthreads();
    for (int st = 128; st > 0; st >>= 1) {
        if (tid < st) red[tid] += red[tid + st];
        __syncthreads();
    }
    float inv = 1.f / red[0];
    for (int c = tid; c < Sk; c += 256) row[c] *= inv;
}

__global__ void av_k(const float* __restrict__ S, const float* __restrict__ V, int vs,
                     float* __restrict__ O, int Sq, int Sk)
{
    int idx = blockIdx.x * blockDim.x + threadIdx.x;
    int total = BB * Sq * DM;
    if (idx >= total) return;
    int dd = idx % HD;
    int h  = (idx / HD) % NH;
    int qx = (idx / DM) % Sq;
    int b  = idx / (DM * Sq);
    const float* srow = S + ((size_t)(b * NH + h) * Sq + qx) * Sk;
    const float* vp = V + (size_t)(b * Sk) * vs + h * HD + dd;
    float acc = 0.f;
    for (int kx = 0; kx < Sk; kx++) acc = fmaf(srow[kx], vp[(size_t)kx * vs], acc);
    O[idx] = acc;
}

// ---------------- host orchestration ----------------
static inline dim3 mg(int M, int N) { return dim3(N / 128, M / 128); }

extern "C" void kernel_launch(void* const* d_in, const int* in_sizes, int n_in,
                              void* d_out, int out_size, void* d_ws, size_t ws_size,
                              hipStream_t stream)
{
    const float* src       = (const float*)d_in[0];
    const float* tgt       = (const float*)d_in[1];
    const float* enc_in_w  = (const float*)d_in[2];
    const float* enc_in_b  = (const float*)d_in[3];
    const float* dec_in_w  = (const float*)d_in[4];
    const float* dec_in_b  = (const float*)d_in[5];
    const float* out_w     = (const float*)d_in[6];
    const float* out_b     = (const float*)d_in[7];
    const float* enc_attn_w = (const float*)d_in[8];
    const float* enc_attn_b = (const float*)d_in[9];
    const float* enc_out_w  = (const float*)d_in[10];
    const float* enc_out_b  = (const float*)d_in[11];
    const float* enc_ff1_w  = (const float*)d_in[12];
    const float* enc_ff1_b  = (const float*)d_in[13];
    const float* enc_ff2_w  = (const float*)d_in[14];
    const float* enc_ff2_b  = (const float*)d_in[15];
    const float* enc_ln1_g  = (const float*)d_in[16];
    const float* enc_ln1_b  = (const float*)d_in[17];
    const float* enc_ln2_g  = (const float*)d_in[18];
    const float* enc_ln2_b  = (const float*)d_in[19];
    const float* dec_sa_w     = (const float*)d_in[20];
    const float* dec_sa_b     = (const float*)d_in[21];
    const float* dec_sa_out_w = (const float*)d_in[22];
    const float* dec_sa_out_b = (const float*)d_in[23];
    const float* dec_ca_w     = (const float*)d_in[24];
    const float* dec_ca_b     = (const float*)d_in[25];
    const float* dec_ca_out_w = (const float*)d_in[26];
    const float* dec_ca_out_b = (const float*)d_in[27];
    const float* dec_ff1_w    = (const float*)d_in[28];
    const float* dec_ff1_b    = (const float*)d_in[29];
    const float* dec_ff2_w    = (const float*)d_in[30];
    const float* dec_ff2_b    = (const float*)d_in[31];
    const float* dec_ln1_g    = (const float*)d_in[32];
    const float* dec_ln1_b    = (const float*)d_in[33];
    const float* dec_ln2_g    = (const float*)d_in[34];
    const float* dec_ln2_b    = (const float*)d_in[35];
    const float* dec_ln3_g    = (const float*)d_in[36];
    const float* dec_ln3_b    = (const float*)d_in[37];

    // workspace layout (fp32), phase-disjoint unions
    float* p = (float*)d_ws;
    float* x0   = p; p += (size_t)BB * SEQ * DM;        // 1.05M
    float* x1   = p; p += (size_t)BB * SEQ * DM;        // 1.05M
    float* reg1 = p; p += (size_t)BB * SEQ * FFD;       // 4.19M: qkv | ffb | (q + kv)
    float* tb   = p; p += (size_t)BB * SEQ * DM;        // 1.05M
    float* sc   = p; p += (size_t)BB * NH * SEQ * SEQ;  // 8.39M
    float* y0   = p; p += (size_t)BB * TGT * DM;        // 0.52M
    float* y1   = p; p += (size_t)BB * TGT * DM;        // 0.52M

    const float SQD = 22.627416997969522f;  // sqrt(512)
    const int ME = BB * SEQ;  // 2048
    const int MD = BB * TGT;  // 1024

    // ===== encoder =====
    mgemm_k<0><<<mg(ME, DM), 256, 0, stream>>>(src, enc_in_w, enc_in_b, nullptr, x0, ME, DM, HD, SQD);
    add_pe_enc<<<(ME * DM + 255) / 256, 256, 0, stream>>>(x0);

    float* cur = x0; float* alt = x1;
    for (int i = 0; i < NL; i++) {
        const float* W  = enc_attn_w + (size_t)i * 3 * DM * DM;
        const float* Bw = enc_attn_b + (size_t)i * 3 * DM;
        // fused QKV: [ME][1536]
        mgemm_k<0><<<mg(ME, 3 * DM), 256, 0, stream>>>(cur, W, Bw, nullptr, reg1, ME, 3 * DM, DM, 1.f);
        int tot = BB * NH * SEQ * SEQ;
        scores_k<<<(tot + 255) / 256, 256, 0, stream>>>(reg1, 3 * DM, reg1 + DM, 3 * DM, sc, SEQ, SEQ, 0);
        softmax_k<<<BB * NH * SEQ, 256, 0, stream>>>(sc, SEQ);
        av_k<<<(ME * DM + 255) / 256, 256, 0, stream>>>(sc, reg1 + 2 * DM, 3 * DM, tb, SEQ, SEQ);
        mgemm_k<0><<<mg(ME, DM), 256, 0, stream>>>(tb, enc_out_w + (size_t)i * DM * DM, enc_out_b + (size_t)i * DM, cur, alt, ME, DM, DM, 1.f);
        ln_k<<<ME, 256, 0, stream>>>(alt, enc_ln1_g + (size_t)i * DM, enc_ln1_b + (size_t)i * DM);
        { float* t = cur; cur = alt; alt = t; }
        mgemm_k<1><<<mg(ME, FFD), 256, 0, stream>>>(cur, enc_ff1_w + (size_t)i * FFD * DM, enc_ff1_b + (size_t)i * FFD, nullptr, reg1, ME, FFD, DM, 1.f);
        mgemm_k<0><<<mg(ME, DM), 256, 0, stream>>>(reg1, enc_ff2_w + (size_t)i * DM * FFD, enc_ff2_b + (size_t)i * DM, cur, alt, ME, DM, FFD, 1.f);
        ln_k<<<ME, 256, 0, stream>>>(alt, enc_ln2_g + (size_t)i * DM, enc_ln2_b + (size_t)i * DM);
        { float* t = cur; cur = alt; alt = t; }
    }
    float* mem = cur;  // == x0

    // ===== decoder =====
    mgemm_k<0><<<mg(MD, DM), 256, 0, stream>>>(tgt, dec_in_w, dec_in_b, nullptr, y0, MD, DM, HD, SQD);
    add_pe_dec<<<(MD * DM + 255) / 256, 256, 0, stream>>>(y0, MD * DM);

    float* dc = y0; float* da = y1;
    for (int i = 0; i < NL; i++) {
        // --- self-attention (causal), fused QKV [MD][1536] ---
        const float* W  = dec_sa_w + (size_t)i * 3 * DM * DM;
        const float* Bw = dec_sa_b + (size_t)i * 3 * DM;
        mgemm_k<0><<<mg(MD, 3 * DM), 256, 0, stream>>>(dc, W, Bw, nullptr, reg1, MD, 3 * DM, DM, 1.f);
        int tot = BB * NH * TGT * TGT;
        scores_k<<<(tot + 255) / 256, 256, 0, stream>>>(reg1, 3 * DM, reg1 + DM, 3 * DM, sc, TGT, TGT, 1);
        softmax_k<<<BB * NH * TGT, 256, 0, stream>>>(sc, TGT);
        av_k<<<(MD * DM + 255) / 256, 256, 0, stream>>>(sc, reg1 + 2 * DM, 3 * DM, tb, TGT, TGT);
        mgemm_k<0><<<mg(MD, DM), 256, 0, stream>>>(tb, dec_sa_out_w + (size_t)i * DM * DM, dec_sa_out_b + (size_t)i * DM, dc, da, MD, DM, DM, 1.f);
        ln_k<<<MD, 256, 0, stream>>>(da, dec_ln1_g + (size_t)i * DM, dec_ln1_b + (size_t)i * DM);
        { float* t = dc; dc = da; da = t; }

        // --- cross-attention: q from decoder, fused k/v from encoder memory ---
        const float* Wc  = dec_ca_w + (size_t)i * 3 * DM * DM;
        const float* Bc  = dec_ca_b + (size_t)i * 3 * DM;
        float* qb  = reg1;                        // [MD][512]
        float* kvp = reg1 + (size_t)MD * DM;      // [ME][1024]
        mgemm_k<0><<<mg(MD, DM), 256, 0, stream>>>(dc,  Wc, Bc, nullptr, qb, MD, DM, DM, 1.f);
        mgemm_k<0><<<mg(ME, 2 * DM), 256, 0, stream>>>(mem, Wc + (size_t)DM * DM, Bc + DM, nullptr, kvp, ME, 2 * DM, DM, 1.f);
        tot = BB * NH * TGT * SEQ;
        scores_k<<<(tot + 255) / 256, 256, 0, stream>>>(qb, DM, kvp, 2 * DM, sc, TGT, SEQ, 0);
        softmax_k<<<BB * NH * TGT, 256, 0, stream>>>(sc, SEQ);
        av_k<<<(MD * DM + 255) / 256, 256, 0, stream>>>(sc, kvp + DM, 2 * DM, tb, TGT, SEQ);
        mgemm_k<0><<<mg(MD, DM), 256, 0, stream>>>(tb, dec_ca_out_w + (size_t)i * DM * DM, dec_ca_out_b + (size_t)i * DM, dc, da, MD, DM, DM, 1.f);
        ln_k<<<MD, 256, 0, stream>>>(da, dec_ln2_g + (size_t)i * DM, dec_ln2_b + (size_t)i * DM);
        { float* t = dc; dc = da; da = t; }

        // --- feed-forward ---
        mgemm_k<1><<<mg(MD, FFD), 256, 0, stream>>>(dc, dec_ff1_w + (size_t)i * FFD * DM, dec_ff1_b + (size_t)i * FFD, nullptr, reg1, MD, FFD, DM, 1.f);
        mgemm_k<0><<<mg(MD, DM), 256, 0, stream>>>(reg1, dec_ff2_w + (size_t)i * DM * FFD, dec_ff2_b + (size_t)i * DM, dc, da, MD, DM, FFD, 1.f);
        ln_k<<<MD, 256, 0, stream>>>(da, dec_ln3_g + (size_t)i * DM, dec_ln3_b + (size_t)i * DM);
        { float* t = dc; dc = da; da = t; }
    }

    // ===== final projection (N=64, vector GEMM, fp32 into d_out) =====
    gemm_k<0><<<dim3(1, MD / 64), 256, 0, stream>>>(dc, out_w, out_b, nullptr, (float*)d_out, MD, HD, DM, 1.f);
}

// Round 5
// 3935.529 us; speedup vs baseline: 4.9672x; 2.3923x over previous
//
#include <hip/hip_runtime.h>
#include <hip/hip_bf16.h>
#include <math.h>

#define BB 4
#define SEQ 512
#define TGT 256
#define DM 512
#define FFD 2048
#define NH 8
#define HD 64
#define NL 6

typedef __attribute__((ext_vector_type(4))) float f4;
typedef __attribute__((ext_vector_type(4))) unsigned short us4;
typedef __attribute__((ext_vector_type(8))) short s8;

__device__ inline unsigned short f2b(float f) {
    __hip_bfloat16 h = __float2bfloat16(f);
    return *reinterpret_cast<unsigned short*>(&h);
}
__device__ inline float b2f(unsigned short u) {
    unsigned int x = ((unsigned int)u) << 16;
    float f;
    __builtin_memcpy(&f, &x, 4);
    return f;
}

// ============ MFMA GEMM: C[M,N] = relu?(alpha*(A @ W^T + bias)) + resid ============
// A: M x K fp32 row-major, W: N x K fp32 row-major. M%128==0, N%128==0, K%32==0.
template <int RELU>
__global__ __launch_bounds__(256) void mgemm_k(
    const float* __restrict__ A, const float* __restrict__ W,
    const float* __restrict__ bias, const float* __restrict__ resid,
    float* __restrict__ C, int M, int N, int K, float alpha)
{
    __shared__ unsigned short As[128][40];
    __shared__ unsigned short Bs[128][40];
    const int bm = blockIdx.y * 128, bn = blockIdx.x * 128;
    const int tid = threadIdx.x;
    const int wave = tid >> 6, lane = tid & 63;
    const int wr = (wave >> 1) * 64, wc = (wave & 1) * 64;
    const int lm = lane & 15, quad = lane >> 4;
    const int sr = tid >> 3, scv = (tid & 7) * 4;

    f4 acc[4][4];
#pragma unroll
    for (int i = 0; i < 4; i++)
#pragma unroll
        for (int j = 0; j < 4; j++) acc[i][j] = (f4)(0.f);

    for (int k0 = 0; k0 < K; k0 += 32) {
#pragma unroll
        for (int pass = 0; pass < 4; pass++) {
            int r = pass * 32 + sr;
            f4 va = *(const f4*)(A + (size_t)(bm + r) * K + k0 + scv);
            f4 vb = *(const f4*)(W + (size_t)(bn + r) * K + k0 + scv);
            us4 ua, ub;
            ua.x = f2b(va.x); ua.y = f2b(va.y); ua.z = f2b(va.z); ua.w = f2b(va.w);
            ub.x = f2b(vb.x); ub.y = f2b(vb.y); ub.z = f2b(vb.z); ub.w = f2b(vb.w);
            *(us4*)&As[r][scv] = ua;
            *(us4*)&Bs[r][scv] = ub;
        }
        __syncthreads();
        s8 af[4], bfr[4];
#pragma unroll
        for (int i = 0; i < 4; i++) af[i] = *(const s8*)&As[wr + i * 16 + lm][quad * 8];
#pragma unroll
        for (int j = 0; j < 4; j++) bfr[j] = *(const s8*)&Bs[wc + j * 16 + lm][quad * 8];
#pragma unroll
        for (int i = 0; i < 4; i++)
#pragma unroll
            for (int j = 0; j < 4; j++)
                acc[i][j] = __builtin_amdgcn_mfma_f32_16x16x32_bf16(af[i], bfr[j], acc[i][j], 0, 0, 0);
        __syncthreads();
    }

#pragma unroll
    for (int j = 0; j < 4; j++) {
        int n = bn + wc + j * 16 + lm;
        float bv = bias[n];
#pragma unroll
        for (int i = 0; i < 4; i++) {
#pragma unroll
            for (int r = 0; r < 4; r++) {
                int m = bm + wr + i * 16 + quad * 4 + r;
                float v = (acc[i][j][r] + bv) * alpha;
                if (RELU) v = fmaxf(v, 0.f);
                size_t off = (size_t)m * N + n;
                if (resid) v += resid[off];
                C[off] = v;
            }
        }
    }
}

// ============ MFMA attention scores: S[bh][q][k] = bf16(QK^T * 0.125, causal) ============
// Q rows stride qs, K rows stride ks (fp32). Sq%128==0, Sk%128==0. grid (Sk/128, Sq/128, B*NH)
__global__ __launch_bounds__(256) void attn_score_k(
    const float* __restrict__ Q, int qs,
    const float* __restrict__ Kp, int ks,
    unsigned short* __restrict__ S, int Sq, int Sk, int causal)
{
    __shared__ unsigned short Qs[128][72];
    __shared__ unsigned short Ks[128][72];
    const int bn = blockIdx.x * 128, bm = blockIdx.y * 128;
    const int bh = blockIdx.z, b = bh >> 3, h = bh & 7;
    const int tid = threadIdx.x;
    const int wave = tid >> 6, lane = tid & 63;
    const int wr = (wave >> 1) * 64, wc = (wave & 1) * 64;
    const int lm = lane & 15, quad = lane >> 4;
    const int sr = tid >> 4, scv = (tid & 15) * 4;

    const float* Qb = Q + (size_t)(b * Sq + bm) * qs + h * HD;
    const float* Kb = Kp + (size_t)(b * Sk + bn) * ks + h * HD;
#pragma unroll
    for (int pass = 0; pass < 8; pass++) {
        int r = pass * 16 + sr;
        f4 va = *(const f4*)(Qb + (size_t)r * qs + scv);
        f4 vb = *(const f4*)(Kb + (size_t)r * ks + scv);
        us4 ua, ub;
        ua.x = f2b(va.x); ua.y = f2b(va.y); ua.z = f2b(va.z); ua.w = f2b(va.w);
        ub.x = f2b(vb.x); ub.y = f2b(vb.y); ub.z = f2b(vb.z); ub.w = f2b(vb.w);
        *(us4*)&Qs[r][scv] = ua;
        *(us4*)&Ks[r][scv] = ub;
    }
    __syncthreads();

    f4 acc[4][4];
#pragma unroll
    for (int i = 0; i < 4; i++)
#pragma unroll
        for (int j = 0; j < 4; j++) acc[i][j] = (f4)(0.f);
#pragma unroll
    for (int kk = 0; kk < 2; kk++) {
        s8 af[4], bfr[4];
#pragma unroll
        for (int i = 0; i < 4; i++) af[i] = *(const s8*)&Qs[wr + i * 16 + lm][kk * 32 + quad * 8];
#pragma unroll
        for (int j = 0; j < 4; j++) bfr[j] = *(const s8*)&Ks[wc + j * 16 + lm][kk * 32 + quad * 8];
#pragma unroll
        for (int i = 0; i < 4; i++)
#pragma unroll
            for (int j = 0; j < 4; j++)
                acc[i][j] = __builtin_amdgcn_mfma_f32_16x16x32_bf16(af[i], bfr[j], acc[i][j], 0, 0, 0);
    }

    unsigned short* Sb = S + (size_t)bh * Sq * Sk;
#pragma unroll
    for (int j = 0; j < 4; j++) {
        int n = bn + wc + j * 16 + lm;
#pragma unroll
        for (int i = 0; i < 4; i++) {
#pragma unroll
            for (int r = 0; r < 4; r++) {
                int m = bm + wr + i * 16 + quad * 4 + r;
                float v = acc[i][j][r] * 0.125f;
                if (causal && n > m) v = -1e9f;
                Sb[(size_t)m * Sk + n] = f2b(v);
            }
        }
    }
}

// ============ softmax over bf16 rows (in-place). Sk in {256,512}; block=256 ============
__global__ __launch_bounds__(256) void softmax_bf_k(unsigned short* __restrict__ S, int Sk)
{
    unsigned short* row = S + (size_t)blockIdx.x * Sk;
    int tid = threadIdx.x;
    __shared__ float red[256];
    int E = Sk >> 8;  // elems per thread: 1 or 2
    float v[2];
    float m = -1e30f;
    for (int e = 0; e < E; e++) {
        v[e] = b2f(row[tid + e * 256]);
        m = fmaxf(m, v[e]);
    }
    red[tid] = m;
    __syncthreads();
    for (int st = 128; st > 0; st >>= 1) {
        if (tid < st) red[tid] = fmaxf(red[tid], red[tid + st]);
        __syncthreads();
    }
    m = red[0];
    __syncthreads();
    float s = 0.f;
    for (int e = 0; e < E; e++) {
        v[e] = expf(v[e] - m);
        s += v[e];
    }
    red[tid] = s;
    __syncthreads();
    for (int st = 128; st > 0; st >>= 1) {
        if (tid < st) red[tid] += red[tid + st];
        __syncthreads();
    }
    float inv = 1.f / red[0];
    for (int e = 0; e < E; e++) row[tid + e * 256] = f2b(v[e] * inv);
}

// ============ MFMA AV: O[b*Sq+m][h*64+n] = P @ V ============
// P: bf16 [bh][Sq][Sk]; V: fp32 rows stride vs. grid (Sq/128, B*NH)
__global__ __launch_bounds__(256) void attn_av_k(
    const unsigned short* __restrict__ S, const float* __restrict__ V, int vs,
    float* __restrict__ O, int Sq, int Sk)
{
    __shared__ unsigned short Ps[128][40];
    __shared__ unsigned short Vs[64][40];
    const int bm = blockIdx.x * 128;
    const int bh = blockIdx.y, b = bh >> 3, h = bh & 7;
    const int tid = threadIdx.x;
    const int wave = tid >> 6, lane = tid & 63;
    const int lm = lane & 15, quad = lane >> 4;
    const int wr = wave * 32;
    const int spr = tid >> 3, spc = (tid & 7) * 4;
    const int vn = tid & 63, vkb = tid >> 6;

    f4 acc[2][4];
#pragma unroll
    for (int i = 0; i < 2; i++)
#pragma unroll
        for (int j = 0; j < 4; j++) acc[i][j] = (f4)(0.f);

    const unsigned short* Sb = S + (size_t)bh * Sq * Sk + (size_t)bm * Sk;
    const float* Vb = V + (size_t)(b * Sk) * vs + h * HD;

    for (int k0 = 0; k0 < Sk; k0 += 32) {
#pragma unroll
        for (int pass = 0; pass < 4; pass++) {
            int r = pass * 32 + spr;
            *(us4*)&Ps[r][spc] = *(const us4*)(Sb + (size_t)r * Sk + k0 + spc);
        }
#pragma unroll
        for (int pass = 0; pass < 8; pass++) {
            int k = pass * 4 + vkb;
            Vs[vn][k] = f2b(Vb[(size_t)(k0 + k) * vs + vn]);
        }
        __syncthreads();
        s8 bfr[4];
#pragma unroll
        for (int j = 0; j < 4; j++) bfr[j] = *(const s8*)&Vs[j * 16 + lm][quad * 8];
#pragma unroll
        for (int i = 0; i < 2; i++) {
            s8 af = *(const s8*)&Ps[wr + i * 16 + lm][quad * 8];
#pragma unroll
            for (int j = 0; j < 4; j++)
                acc[i][j] = __builtin_amdgcn_mfma_f32_16x16x32_bf16(af, bfr[j], acc[i][j], 0, 0, 0);
        }
        __syncthreads();
    }

#pragma unroll
    for (int i = 0; i < 2; i++) {
#pragma unroll
        for (int j = 0; j < 4; j++) {
            int n = j * 16 + lm;
#pragma unroll
            for (int r = 0; r < 4; r++) {
                int m = bm + wr + i * 16 + quad * 4 + r;
                O[(size_t)(b * Sq + m) * DM + h * HD + n] = acc[i][j][r];
            }
        }
    }
}

// ============ small vector GEMM (final projection, N=64) ============
template <int RELU>
__global__ __launch_bounds__(256) void gemm_k(
    const float* __restrict__ A, const float* __restrict__ W,
    const float* __restrict__ bias, const float* __restrict__ resid,
    float* __restrict__ C, int M, int N, int K, float alpha)
{
    const int BM = 64, BN = 64, BK = 16;
    __shared__ float As[BM][BK + 1];
    __shared__ float Ws[BN][BK + 1];
    int bm = blockIdx.y * BM, bn = blockIdx.x * BN;
    int tid = threadIdx.x;
    int tr = tid >> 4, tc = tid & 15;
    float acc[4][4] = {};
    for (int k0 = 0; k0 < K; k0 += BK) {
        for (int i = tid; i < BM * BK; i += 256) {
            int r = i >> 4, c = i & 15;
            int gr = bm + r, gc = k0 + c;
            As[r][c] = (gr < M) ? A[(size_t)gr * K + gc] : 0.f;
        }
        for (int i = tid; i < BN * BK; i += 256) {
            int r = i >> 4, c = i & 15;
            int gr = bn + r, gc = k0 + c;
            Ws[r][c] = (gr < N) ? W[(size_t)gr * K + gc] : 0.f;
        }
        __syncthreads();
#pragma unroll
        for (int kk = 0; kk < BK; kk++) {
            float a[4], w[4];
#pragma unroll
            for (int i = 0; i < 4; i++) a[i] = As[tr * 4 + i][kk];
#pragma unroll
            for (int j = 0; j < 4; j++) w[j] = Ws[tc * 4 + j][kk];
#pragma unroll
            for (int i = 0; i < 4; i++)
#pragma unroll
                for (int j = 0; j < 4; j++) acc[i][j] = fmaf(a[i], w[j], acc[i][j]);
        }
        __syncthreads();
    }
#pragma unroll
    for (int i = 0; i < 4; i++) {
        int gr = bm + tr * 4 + i;
        if (gr >= M) continue;
#pragma unroll
        for (int j = 0; j < 4; j++) {
            int gc = bn + tc * 4 + j;
            if (gc >= N) continue;
            float v = (acc[i][j] + bias[gc]) * alpha;
            if (RELU) v = fmaxf(v, 0.f);
            if (resid) v += resid[(size_t)gr * N + gc];
            C[(size_t)gr * N + gc] = v;
        }
    }
}

// ---------------- positional encodings ----------------
__global__ void add_pe_enc(float* __restrict__ x)
{
    int idx = blockIdx.x * blockDim.x + threadIdx.x;
    if (idx >= BB * SEQ * DM) return;
    int c = idx % DM;
    int s = (idx / DM) % SEQ;
    float dv = expf((float)(c & ~1) * (-9.210340371976184f / (float)DM));
    float ang = (float)s * dv;
    x[idx] += (c & 1) ? cosf(ang) : sinf(ang);
}

__global__ void add_pe_dec(float* __restrict__ x, int n)
{
    int idx = blockIdx.x * blockDim.x + threadIdx.x;
    if (idx >= n) return;
    if (idx & 1) x[idx] += 1.f;
}

// ---------------- layernorm (row of DM=512, block=256) ----------------
__global__ __launch_bounds__(256) void ln_k(float* __restrict__ x,
                                            const float* __restrict__ g,
                                            const float* __restrict__ b)
{
    int row = blockIdx.x;
    float* xr = x + (size_t)row * DM;
    int tid = threadIdx.x;
    float v0 = xr[tid], v1 = xr[tid + 256];
    __shared__ float red[256];
    red[tid] = v0 + v1;
    __syncthreads();
    for (int st = 128; st > 0; st >>= 1) {
        if (tid < st) red[tid] += red[tid + st];
        __syncthreads();
    }
    float mean = red[0] * (1.f / DM);
    __syncthreads();
    float d0 = v0 - mean, d1 = v1 - mean;
    red[tid] = d0 * d0 + d1 * d1;
    __syncthreads();
    for (int st = 128; st > 0; st >>= 1) {
        if (tid < st) red[tid] += red[tid + st];
        __syncthreads();
    }
    float rstd = rsqrtf(red[0] * (1.f / DM) + 1e-5f);
    xr[tid]       = d0 * rstd * g[tid]       + b[tid];
    xr[tid + 256] = d1 * rstd * g[tid + 256] + b[tid + 256];
}

// ---------------- host orchestration ----------------
static inline dim3 mg(int M, int N) { return dim3(N / 128, M / 128); }

extern "C" void kernel_launch(void* const* d_in, const int* in_sizes, int n_in,
                              void* d_out, int out_size, void* d_ws, size_t ws_size,
                              hipStream_t stream)
{
    const float* src       = (const float*)d_in[0];
    const float* tgt       = (const float*)d_in[1];
    const float* enc_in_w  = (const float*)d_in[2];
    const float* enc_in_b  = (const float*)d_in[3];
    const float* dec_in_w  = (const float*)d_in[4];
    const float* dec_in_b  = (const float*)d_in[5];
    const float* out_w     = (const float*)d_in[6];
    const float* out_b     = (const float*)d_in[7];
    const float* enc_attn_w = (const float*)d_in[8];
    const float* enc_attn_b = (const float*)d_in[9];
    const float* enc_out_w  = (const float*)d_in[10];
    const float* enc_out_b  = (const float*)d_in[11];
    const float* enc_ff1_w  = (const float*)d_in[12];
    const float* enc_ff1_b  = (const float*)d_in[13];
    const float* enc_ff2_w  = (const float*)d_in[14];
    const float* enc_ff2_b  = (const float*)d_in[15];
    const float* enc_ln1_g  = (const float*)d_in[16];
    const float* enc_ln1_b  = (const float*)d_in[17];
    const float* enc_ln2_g  = (const float*)d_in[18];
    const float* enc_ln2_b  = (const float*)d_in[19];
    const float* dec_sa_w     = (const float*)d_in[20];
    const float* dec_sa_b     = (const float*)d_in[21];
    const float* dec_sa_out_w = (const float*)d_in[22];
    const float* dec_sa_out_b = (const float*)d_in[23];
    const float* dec_ca_w     = (const float*)d_in[24];
    const float* dec_ca_b     = (const float*)d_in[25];
    const float* dec_ca_out_w = (const float*)d_in[26];
    const float* dec_ca_out_b = (const float*)d_in[27];
    const float* dec_ff1_w    = (const float*)d_in[28];
    const float* dec_ff1_b    = (const float*)d_in[29];
    const float* dec_ff2_w    = (const float*)d_in[30];
    const float* dec_ff2_b    = (const float*)d_in[31];
    const float* dec_ln1_g    = (const float*)d_in[32];
    const float* dec_ln1_b    = (const float*)d_in[33];
    const float* dec_ln2_g    = (const float*)d_in[34];
    const float* dec_ln2_b    = (const float*)d_in[35];
    const float* dec_ln3_g    = (const float*)d_in[36];
    const float* dec_ln3_b    = (const float*)d_in[37];

    // workspace layout
    float* p = (float*)d_ws;
    float* x0   = p; p += (size_t)BB * SEQ * DM;        // 4 MB
    float* x1   = p; p += (size_t)BB * SEQ * DM;        // 4 MB
    float* reg1 = p; p += (size_t)BB * SEQ * FFD;       // 16.8 MB: qkv | ffb | (q + kv)
    float* tb   = p; p += (size_t)BB * SEQ * DM;        // 4 MB
    unsigned short* scb = (unsigned short*)p; p += (size_t)BB * NH * SEQ * SEQ / 2;  // 16.8 MB bf16
    float* y0   = p; p += (size_t)BB * TGT * DM;        // 2 MB
    float* y1   = p; p += (size_t)BB * TGT * DM;        // 2 MB

    const float SQD = 22.627416997969522f;  // sqrt(512)
    const int ME = BB * SEQ;  // 2048
    const int MD = BB * TGT;  // 1024
    const int BH = BB * NH;   // 32

    // ===== encoder =====
    mgemm_k<0><<<mg(ME, DM), 256, 0, stream>>>(src, enc_in_w, enc_in_b, nullptr, x0, ME, DM, HD, SQD);
    add_pe_enc<<<(ME * DM + 255) / 256, 256, 0, stream>>>(x0);

    float* cur = x0; float* alt = x1;
    for (int i = 0; i < NL; i++) {
        const float* W  = enc_attn_w + (size_t)i * 3 * DM * DM;
        const float* Bw = enc_attn_b + (size_t)i * 3 * DM;
        mgemm_k<0><<<mg(ME, 3 * DM), 256, 0, stream>>>(cur, W, Bw, nullptr, reg1, ME, 3 * DM, DM, 1.f);
        attn_score_k<<<dim3(SEQ / 128, SEQ / 128, BH), 256, 0, stream>>>(reg1, 3 * DM, reg1 + DM, 3 * DM, scb, SEQ, SEQ, 0);
        softmax_bf_k<<<BH * SEQ, 256, 0, stream>>>(scb, SEQ);
        attn_av_k<<<dim3(SEQ / 128, BH), 256, 0, stream>>>(scb, reg1 + 2 * DM, 3 * DM, tb, SEQ, SEQ);
        mgemm_k<0><<<mg(ME, DM), 256, 0, stream>>>(tb, enc_out_w + (size_t)i * DM * DM, enc_out_b + (size_t)i * DM, cur, alt, ME, DM, DM, 1.f);
        ln_k<<<ME, 256, 0, stream>>>(alt, enc_ln1_g + (size_t)i * DM, enc_ln1_b + (size_t)i * DM);
        { float* t = cur; cur = alt; alt = t; }
        mgemm_k<1><<<mg(ME, FFD), 256, 0, stream>>>(cur, enc_ff1_w + (size_t)i * FFD * DM, enc_ff1_b + (size_t)i * FFD, nullptr, reg1, ME, FFD, DM, 1.f);
        mgemm_k<0><<<mg(ME, DM), 256, 0, stream>>>(reg1, enc_ff2_w + (size_t)i * DM * FFD, enc_ff2_b + (size_t)i * DM, cur, alt, ME, DM, FFD, 1.f);
        ln_k<<<ME, 256, 0, stream>>>(alt, enc_ln2_g + (size_t)i * DM, enc_ln2_b + (size_t)i * DM);
        { float* t = cur; cur = alt; alt = t; }
    }
    float* mem = cur;  // == x0

    // ===== decoder =====
    mgemm_k<0><<<mg(MD, DM), 256, 0, stream>>>(tgt, dec_in_w, dec_in_b, nullptr, y0, MD, DM, HD, SQD);
    add_pe_dec<<<(MD * DM + 255) / 256, 256, 0, stream>>>(y0, MD * DM);

    float* dc = y0; float* da = y1;
    for (int i = 0; i < NL; i++) {
        // --- self-attention (causal), fused QKV [MD][1536] ---
        const float* W  = dec_sa_w + (size_t)i * 3 * DM * DM;
        const float* Bw = dec_sa_b + (size_t)i * 3 * DM;
        mgemm_k<0><<<mg(MD, 3 * DM), 256, 0, stream>>>(dc, W, Bw, nullptr, reg1, MD, 3 * DM, DM, 1.f);
        attn_score_k<<<dim3(TGT / 128, TGT / 128, BH), 256, 0, stream>>>(reg1, 3 * DM, reg1 + DM, 3 * DM, scb, TGT, TGT, 1);
        softmax_bf_k<<<BH * TGT, 256, 0, stream>>>(scb, TGT);
        attn_av_k<<<dim3(TGT / 128, BH), 256, 0, stream>>>(scb, reg1 + 2 * DM, 3 * DM, tb, TGT, TGT);
        mgemm_k<0><<<mg(MD, DM), 256, 0, stream>>>(tb, dec_sa_out_w + (size_t)i * DM * DM, dec_sa_out_b + (size_t)i * DM, dc, da, MD, DM, DM, 1.f);
        ln_k<<<MD, 256, 0, stream>>>(da, dec_ln1_g + (size_t)i * DM, dec_ln1_b + (size_t)i * DM);
        { float* t = dc; dc = da; da = t; }

        // --- cross-attention: q from decoder, fused k/v from encoder memory ---
        const float* Wc  = dec_ca_w + (size_t)i * 3 * DM * DM;
        const float* Bc  = dec_ca_b + (size_t)i * 3 * DM;
        float* qb  = reg1;                        // [MD][512]
        float* kvp = reg1 + (size_t)MD * DM;      // [ME][1024]
        mgemm_k<0><<<mg(MD, DM), 256, 0, stream>>>(dc,  Wc, Bc, nullptr, qb, MD, DM, DM, 1.f);
        mgemm_k<0><<<mg(ME, 2 * DM), 256, 0, stream>>>(mem, Wc + (size_t)DM * DM, Bc + DM, nullptr, kvp, ME, 2 * DM, DM, 1.f);
        attn_score_k<<<dim3(SEQ / 128, TGT / 128, BH), 256, 0, stream>>>(qb, DM, kvp, 2 * DM, scb, TGT, SEQ, 0);
        softmax_bf_k<<<BH * TGT, 256, 0, stream>>>(scb, SEQ);
        attn_av_k<<<dim3(TGT / 128, BH), 256, 0, stream>>>(scb, kvp + DM, 2 * DM, tb, TGT, SEQ);
        mgemm_k<0><<<mg(MD, DM), 256, 0, stream>>>(tb, dec_ca_out_w + (size_t)i * DM * DM, dec_ca_out_b + (size_t)i * DM, dc, da, MD, DM, DM, 1.f);
        ln_k<<<MD, 256, 0, stream>>>(da, dec_ln2_g + (size_t)i * DM, dec_ln2_b + (size_t)i * DM);
        { float* t = dc; dc = da; da = t; }

        // --- feed-forward ---
        mgemm_k<1><<<mg(MD, FFD), 256, 0, stream>>>(dc, dec_ff1_w + (size_t)i * FFD * DM, dec_ff1_b + (size_t)i * FFD, nullptr, reg1, MD, FFD, DM, 1.f);
        mgemm_k<0><<<mg(MD, DM), 256, 0, stream>>>(reg1, dec_ff2_w + (size_t)i * DM * FFD, dec_ff2_b + (size_t)i * DM, dc, da, MD, DM, FFD, 1.f);
        ln_k<<<MD, 256, 0, stream>>>(da, dec_ln3_g + (size_t)i * DM, dec_ln3_b + (size_t)i * DM);
        { float* t = dc; dc = da; da = t; }
    }

    // ===== final projection (N=64, vector GEMM, fp32 into d_out) =====
    gemm_k<0><<<dim3(1, MD / 64), 256, 0, stream>>>(dc, out_w, out_b, nullptr, (float*)d_out, MD, HD, DM, 1.f);
}

// Round 6
// 2525.435 us; speedup vs baseline: 7.7406x; 1.5584x over previous
//
#include <hip/hip_runtime.h>
#include <hip/hip_bf16.h>
#include <math.h>

#define BB 4
#define SEQ 512
#define TGT 256
#define DM 512
#define FFD 2048
#define NH 8
#define HD 64
#define NL 6

typedef __attribute__((ext_vector_type(4))) float f4;
typedef __attribute__((ext_vector_type(4))) unsigned short us4;
typedef __attribute__((ext_vector_type(8))) short s8;

__device__ inline unsigned short f2b(float f) {
    __hip_bfloat16 h = __float2bfloat16(f);
    return *reinterpret_cast<unsigned short*>(&h);
}
__device__ inline float b2f(unsigned short u) {
    unsigned int x = ((unsigned int)u) << 16;
    float f;
    __builtin_memcpy(&f, &x, 4);
    return f;
}
__device__ inline us4 cvt4(f4 v) {
    us4 u;
    u.x = f2b(v.x); u.y = f2b(v.y); u.z = f2b(v.z); u.w = f2b(v.w);
    return u;
}

// ============ MFMA GEMM, 64x64 tile, 2-stage pipelined staging ============
// C[M,N] = relu?(alpha*(A @ W^T + bias)) + resid
// A: M x K fp32 row-major, W: N x K fp32 row-major. M%64==0, N%64==0, K%32==0.
// 256 threads = 4 waves; wave tile 32x32 = 2x2 MFMA 16x16x32 bf16.
template <int RELU>
__global__ __launch_bounds__(256) void mgemm_k(
    const float* __restrict__ A, const float* __restrict__ W,
    const float* __restrict__ bias, const float* __restrict__ resid,
    float* __restrict__ C, int M, int N, int K, float alpha)
{
    __shared__ unsigned short As[64][40];
    __shared__ unsigned short Bs[64][40];
    const int bm = blockIdx.y * 64, bn = blockIdx.x * 64;
    const int tid = threadIdx.x;
    const int wave = tid >> 6, lane = tid & 63;
    const int wr = (wave >> 1) * 32, wc = (wave & 1) * 32;
    const int lm = lane & 15, quad = lane >> 4;
    const int sr = tid >> 2;          // 0..63 staging row
    const int scv = (tid & 3) * 8;    // 0,8,16,24 staging col (2 x f4)

    const float* Arow = A + (size_t)(bm + sr) * K + scv;
    const float* Wrow = W + (size_t)(bn + sr) * K + scv;

    // preload k-tile 0
    f4 a0 = *(const f4*)(Arow);
    f4 a1 = *(const f4*)(Arow + 4);
    f4 b0 = *(const f4*)(Wrow);
    f4 b1 = *(const f4*)(Wrow + 4);

    f4 acc[2][2];
#pragma unroll
    for (int i = 0; i < 2; i++)
#pragma unroll
        for (int j = 0; j < 2; j++) acc[i][j] = (f4)(0.f);

    for (int k0 = 0; k0 < K; k0 += 32) {
        *(us4*)&As[sr][scv]     = cvt4(a0);
        *(us4*)&As[sr][scv + 4] = cvt4(a1);
        *(us4*)&Bs[sr][scv]     = cvt4(b0);
        *(us4*)&Bs[sr][scv + 4] = cvt4(b1);
        __syncthreads();
        if (k0 + 32 < K) {  // prefetch next tile; overlaps with MFMA below
            a0 = *(const f4*)(Arow + k0 + 32);
            a1 = *(const f4*)(Arow + k0 + 36);
            b0 = *(const f4*)(Wrow + k0 + 32);
            b1 = *(const f4*)(Wrow + k0 + 36);
        }
        s8 af[2], bfr[2];
#pragma unroll
        for (int i = 0; i < 2; i++) af[i] = *(const s8*)&As[wr + i * 16 + lm][quad * 8];
#pragma unroll
        for (int j = 0; j < 2; j++) bfr[j] = *(const s8*)&Bs[wc + j * 16 + lm][quad * 8];
#pragma unroll
        for (int i = 0; i < 2; i++)
#pragma unroll
            for (int j = 0; j < 2; j++)
                acc[i][j] = __builtin_amdgcn_mfma_f32_16x16x32_bf16(af[i], bfr[j], acc[i][j], 0, 0, 0);
        __syncthreads();
    }

#pragma unroll
    for (int j = 0; j < 2; j++) {
        int n = bn + wc + j * 16 + lm;
        float bv = bias[n];
#pragma unroll
        for (int i = 0; i < 2; i++) {
#pragma unroll
            for (int r = 0; r < 4; r++) {
                int m = bm + wr + i * 16 + quad * 4 + r;
                float v = (acc[i][j][r] + bv) * alpha;
                if (RELU) v = fmaxf(v, 0.f);
                size_t off = (size_t)m * N + n;
                if (resid) v += resid[off];
                C[off] = v;
            }
        }
    }
}

// ============ MFMA attention scores: S[bh][q][k] = bf16(QK^T * 0.125, causal) ============
__global__ __launch_bounds__(256) void attn_score_k(
    const float* __restrict__ Q, int qs,
    const float* __restrict__ Kp, int ks,
    unsigned short* __restrict__ S, int Sq, int Sk, int causal)
{
    __shared__ unsigned short Qs[128][72];
    __shared__ unsigned short Ks[128][72];
    const int bn = blockIdx.x * 128, bm = blockIdx.y * 128;
    const int bh = blockIdx.z, b = bh >> 3, h = bh & 7;
    const int tid = threadIdx.x;
    const int wave = tid >> 6, lane = tid & 63;
    const int wr = (wave >> 1) * 64, wc = (wave & 1) * 64;
    const int lm = lane & 15, quad = lane >> 4;
    const int sr = tid >> 4, scv = (tid & 15) * 4;

    const float* Qb = Q + (size_t)(b * Sq + bm) * qs + h * HD;
    const float* Kb = Kp + (size_t)(b * Sk + bn) * ks + h * HD;
#pragma unroll
    for (int pass = 0; pass < 8; pass++) {
        int r = pass * 16 + sr;
        *(us4*)&Qs[r][scv] = cvt4(*(const f4*)(Qb + (size_t)r * qs + scv));
        *(us4*)&Ks[r][scv] = cvt4(*(const f4*)(Kb + (size_t)r * ks + scv));
    }
    __syncthreads();

    f4 acc[4][4];
#pragma unroll
    for (int i = 0; i < 4; i++)
#pragma unroll
        for (int j = 0; j < 4; j++) acc[i][j] = (f4)(0.f);
#pragma unroll
    for (int kk = 0; kk < 2; kk++) {
        s8 af[4], bfr[4];
#pragma unroll
        for (int i = 0; i < 4; i++) af[i] = *(const s8*)&Qs[wr + i * 16 + lm][kk * 32 + quad * 8];
#pragma unroll
        for (int j = 0; j < 4; j++) bfr[j] = *(const s8*)&Ks[wc + j * 16 + lm][kk * 32 + quad * 8];
#pragma unroll
        for (int i = 0; i < 4; i++)
#pragma unroll
            for (int j = 0; j < 4; j++)
                acc[i][j] = __builtin_amdgcn_mfma_f32_16x16x32_bf16(af[i], bfr[j], acc[i][j], 0, 0, 0);
    }

    unsigned short* Sb = S + (size_t)bh * Sq * Sk;
#pragma unroll
    for (int j = 0; j < 4; j++) {
        int n = bn + wc + j * 16 + lm;
#pragma unroll
        for (int i = 0; i < 4; i++) {
#pragma unroll
            for (int r = 0; r < 4; r++) {
                int m = bm + wr + i * 16 + quad * 4 + r;
                float v = acc[i][j][r] * 0.125f;
                if (causal && n > m) v = -1e9f;
                Sb[(size_t)m * Sk + n] = f2b(v);
            }
        }
    }
}

// ============ softmax over bf16 rows (in-place). Sk in {256,512}; block=256 ============
__global__ __launch_bounds__(256) void softmax_bf_k(unsigned short* __restrict__ S, int Sk)
{
    unsigned short* row = S + (size_t)blockIdx.x * Sk;
    int tid = threadIdx.x;
    __shared__ float red[256];
    int E = Sk >> 8;
    float v[2];
    float m = -1e30f;
    for (int e = 0; e < E; e++) {
        v[e] = b2f(row[tid + e * 256]);
        m = fmaxf(m, v[e]);
    }
    red[tid] = m;
    __syncthreads();
    for (int st = 128; st > 0; st >>= 1) {
        if (tid < st) red[tid] = fmaxf(red[tid], red[tid + st]);
        __syncthreads();
    }
    m = red[0];
    __syncthreads();
    float s = 0.f;
    for (int e = 0; e < E; e++) {
        v[e] = expf(v[e] - m);
        s += v[e];
    }
    red[tid] = s;
    __syncthreads();
    for (int st = 128; st > 0; st >>= 1) {
        if (tid < st) red[tid] += red[tid + st];
        __syncthreads();
    }
    float inv = 1.f / red[0];
    for (int e = 0; e < E; e++) row[tid + e * 256] = f2b(v[e] * inv);
}

// ============ MFMA AV: O[b*Sq+m][h*64+n] = P @ V ============
__global__ __launch_bounds__(256) void attn_av_k(
    const unsigned short* __restrict__ S, const float* __restrict__ V, int vs,
    float* __restrict__ O, int Sq, int Sk)
{
    __shared__ unsigned short Ps[128][40];
    __shared__ unsigned short Vs[64][40];
    const int bm = blockIdx.x * 128;
    const int bh = blockIdx.y, b = bh >> 3, h = bh & 7;
    const int tid = threadIdx.x;
    const int wave = tid >> 6, lane = tid & 63;
    const int lm = lane & 15, quad = lane >> 4;
    const int wr = wave * 32;
    const int spr = tid >> 3, spc = (tid & 7) * 4;
    const int vn = tid & 63, vkb = tid >> 6;

    f4 acc[2][4];
#pragma unroll
    for (int i = 0; i < 2; i++)
#pragma unroll
        for (int j = 0; j < 4; j++) acc[i][j] = (f4)(0.f);

    const unsigned short* Sb = S + (size_t)bh * Sq * Sk + (size_t)bm * Sk;
    const float* Vb = V + (size_t)(b * Sk) * vs + h * HD;

    for (int k0 = 0; k0 < Sk; k0 += 32) {
#pragma unroll
        for (int pass = 0; pass < 4; pass++) {
            int r = pass * 32 + spr;
            *(us4*)&Ps[r][spc] = *(const us4*)(Sb + (size_t)r * Sk + k0 + spc);
        }
#pragma unroll
        for (int pass = 0; pass < 8; pass++) {
            int k = pass * 4 + vkb;
            Vs[vn][k] = f2b(Vb[(size_t)(k0 + k) * vs + vn]);
        }
        __syncthreads();
        s8 bfr[4];
#pragma unroll
        for (int j = 0; j < 4; j++) bfr[j] = *(const s8*)&Vs[j * 16 + lm][quad * 8];
#pragma unroll
        for (int i = 0; i < 2; i++) {
            s8 af = *(const s8*)&Ps[wr + i * 16 + lm][quad * 8];
#pragma unroll
            for (int j = 0; j < 4; j++)
                acc[i][j] = __builtin_amdgcn_mfma_f32_16x16x32_bf16(af, bfr[j], acc[i][j], 0, 0, 0);
        }
        __syncthreads();
    }

#pragma unroll
    for (int i = 0; i < 2; i++) {
#pragma unroll
        for (int j = 0; j < 4; j++) {
            int n = j * 16 + lm;
#pragma unroll
            for (int r = 0; r < 4; r++) {
                int m = bm + wr + i * 16 + quad * 4 + r;
                O[(size_t)(b * Sq + m) * DM + h * HD + n] = acc[i][j][r];
            }
        }
    }
}

// ---------------- positional encodings ----------------
__global__ void add_pe_enc(float* __restrict__ x)
{
    int idx = blockIdx.x * blockDim.x + threadIdx.x;
    if (idx >= BB * SEQ * DM) return;
    int c = idx % DM;
    int s = (idx / DM) % SEQ;
    float dv = expf((float)(c & ~1) * (-9.210340371976184f / (float)DM));
    float ang = (float)s * dv;
    x[idx] += (c & 1) ? cosf(ang) : sinf(ang);
}

__global__ void add_pe_dec(float* __restrict__ x, int n)
{
    int idx = blockIdx.x * blockDim.x + threadIdx.x;
    if (idx >= n) return;
    if (idx & 1) x[idx] += 1.f;
}

// ---------------- layernorm (row of DM=512, block=256) ----------------
__global__ __launch_bounds__(256) void ln_k(float* __restrict__ x,
                                            const float* __restrict__ g,
                                            const float* __restrict__ b)
{
    int row = blockIdx.x;
    float* xr = x + (size_t)row * DM;
    int tid = threadIdx.x;
    float v0 = xr[tid], v1 = xr[tid + 256];
    __shared__ float red[256];
    red[tid] = v0 + v1;
    __syncthreads();
    for (int st = 128; st > 0; st >>= 1) {
        if (tid < st) red[tid] += red[tid + st];
        __syncthreads();
    }
    float mean = red[0] * (1.f / DM);
    __syncthreads();
    float d0 = v0 - mean, d1 = v1 - mean;
    red[tid] = d0 * d0 + d1 * d1;
    __syncthreads();
    for (int st = 128; st > 0; st >>= 1) {
        if (tid < st) red[tid] += red[tid + st];
        __syncthreads();
    }
    float rstd = rsqrtf(red[0] * (1.f / DM) + 1e-5f);
    xr[tid]       = d0 * rstd * g[tid]       + b[tid];
    xr[tid + 256] = d1 * rstd * g[tid + 256] + b[tid + 256];
}

// ---------------- host orchestration ----------------
static inline dim3 mg(int M, int N) { return dim3(N / 64, M / 64); }

extern "C" void kernel_launch(void* const* d_in, const int* in_sizes, int n_in,
                              void* d_out, int out_size, void* d_ws, size_t ws_size,
                              hipStream_t stream)
{
    const float* src       = (const float*)d_in[0];
    const float* tgt       = (const float*)d_in[1];
    const float* enc_in_w  = (const float*)d_in[2];
    const float* enc_in_b  = (const float*)d_in[3];
    const float* dec_in_w  = (const float*)d_in[4];
    const float* dec_in_b  = (const float*)d_in[5];
    const float* out_w     = (const float*)d_in[6];
    const float* out_b     = (const float*)d_in[7];
    const float* enc_attn_w = (const float*)d_in[8];
    const float* enc_attn_b = (const float*)d_in[9];
    const float* enc_out_w  = (const float*)d_in[10];
    const float* enc_out_b  = (const float*)d_in[11];
    const float* enc_ff1_w  = (const float*)d_in[12];
    const float* enc_ff1_b  = (const float*)d_in[13];
    const float* enc_ff2_w  = (const float*)d_in[14];
    const float* enc_ff2_b  = (const float*)d_in[15];
    const float* enc_ln1_g  = (const float*)d_in[16];
    const float* enc_ln1_b  = (const float*)d_in[17];
    const float* enc_ln2_g  = (const float*)d_in[18];
    const float* enc_ln2_b  = (const float*)d_in[19];
    const float* dec_sa_w     = (const float*)d_in[20];
    const float* dec_sa_b     = (const float*)d_in[21];
    const float* dec_sa_out_w = (const float*)d_in[22];
    const float* dec_sa_out_b = (const float*)d_in[23];
    const float* dec_ca_w     = (const float*)d_in[24];
    const float* dec_ca_b     = (const float*)d_in[25];
    const float* dec_ca_out_w = (const float*)d_in[26];
    const float* dec_ca_out_b = (const float*)d_in[27];
    const float* dec_ff1_w    = (const float*)d_in[28];
    const float* dec_ff1_b    = (const float*)d_in[29];
    const float* dec_ff2_w    = (const float*)d_in[30];
    const float* dec_ff2_b    = (const float*)d_in[31];
    const float* dec_ln1_g    = (const float*)d_in[32];
    const float* dec_ln1_b    = (const float*)d_in[33];
    const float* dec_ln2_g    = (const float*)d_in[34];
    const float* dec_ln2_b    = (const float*)d_in[35];
    const float* dec_ln3_g    = (const float*)d_in[36];
    const float* dec_ln3_b    = (const float*)d_in[37];

    // workspace layout
    float* p = (float*)d_ws;
    float* x0   = p; p += (size_t)BB * SEQ * DM;
    float* x1   = p; p += (size_t)BB * SEQ * DM;
    float* reg1 = p; p += (size_t)BB * SEQ * FFD;       // qkv | ffb | (q + kv)
    float* tb   = p; p += (size_t)BB * SEQ * DM;
    unsigned short* scb = (unsigned short*)p; p += (size_t)BB * NH * SEQ * SEQ / 2;
    float* y0   = p; p += (size_t)BB * TGT * DM;
    float* y1   = p; p += (size_t)BB * TGT * DM;

    const float SQD = 22.627416997969522f;  // sqrt(512)
    const int ME = BB * SEQ;  // 2048
    const int MD = BB * TGT;  // 1024
    const int BH = BB * NH;   // 32

    // ===== encoder =====
    mgemm_k<0><<<mg(ME, DM), 256, 0, stream>>>(src, enc_in_w, enc_in_b, nullptr, x0, ME, DM, HD, SQD);
    add_pe_enc<<<(ME * DM + 255) / 256, 256, 0, stream>>>(x0);

    float* cur = x0; float* alt = x1;
    for (int i = 0; i < NL; i++) {
        const float* W  = enc_attn_w + (size_t)i * 3 * DM * DM;
        const float* Bw = enc_attn_b + (size_t)i * 3 * DM;
        mgemm_k<0><<<mg(ME, 3 * DM), 256, 0, stream>>>(cur, W, Bw, nullptr, reg1, ME, 3 * DM, DM, 1.f);
        attn_score_k<<<dim3(SEQ / 128, SEQ / 128, BH), 256, 0, stream>>>(reg1, 3 * DM, reg1 + DM, 3 * DM, scb, SEQ, SEQ, 0);
        softmax_bf_k<<<BH * SEQ, 256, 0, stream>>>(scb, SEQ);
        attn_av_k<<<dim3(SEQ / 128, BH), 256, 0, stream>>>(scb, reg1 + 2 * DM, 3 * DM, tb, SEQ, SEQ);
        mgemm_k<0><<<mg(ME, DM), 256, 0, stream>>>(tb, enc_out_w + (size_t)i * DM * DM, enc_out_b + (size_t)i * DM, cur, alt, ME, DM, DM, 1.f);
        ln_k<<<ME, 256, 0, stream>>>(alt, enc_ln1_g + (size_t)i * DM, enc_ln1_b + (size_t)i * DM);
        { float* t = cur; cur = alt; alt = t; }
        mgemm_k<1><<<mg(ME, FFD), 256, 0, stream>>>(cur, enc_ff1_w + (size_t)i * FFD * DM, enc_ff1_b + (size_t)i * FFD, nullptr, reg1, ME, FFD, DM, 1.f);
        mgemm_k<0><<<mg(ME, DM), 256, 0, stream>>>(reg1, enc_ff2_w + (size_t)i * DM * FFD, enc_ff2_b + (size_t)i * DM, cur, alt, ME, DM, FFD, 1.f);
        ln_k<<<ME, 256, 0, stream>>>(alt, enc_ln2_g + (size_t)i * DM, enc_ln2_b + (size_t)i * DM);
        { float* t = cur; cur = alt; alt = t; }
    }
    float* mem = cur;  // == x0

    // ===== decoder =====
    mgemm_k<0><<<mg(MD, DM), 256, 0, stream>>>(tgt, dec_in_w, dec_in_b, nullptr, y0, MD, DM, HD, SQD);
    add_pe_dec<<<(MD * DM + 255) / 256, 256, 0, stream>>>(y0, MD * DM);

    float* dc = y0; float* da = y1;
    for (int i = 0; i < NL; i++) {
        // --- self-attention (causal), fused QKV ---
        const float* W  = dec_sa_w + (size_t)i * 3 * DM * DM;
        const float* Bw = dec_sa_b + (size_t)i * 3 * DM;
        mgemm_k<0><<<mg(MD, 3 * DM), 256, 0, stream>>>(dc, W, Bw, nullptr, reg1, MD, 3 * DM, DM, 1.f);
        attn_score_k<<<dim3(TGT / 128, TGT / 128, BH), 256, 0, stream>>>(reg1, 3 * DM, reg1 + DM, 3 * DM, scb, TGT, TGT, 1);
        softmax_bf_k<<<BH * TGT, 256, 0, stream>>>(scb, TGT);
        attn_av_k<<<dim3(TGT / 128, BH), 256, 0, stream>>>(scb, reg1 + 2 * DM, 3 * DM, tb, TGT, TGT);
        mgemm_k<0><<<mg(MD, DM), 256, 0, stream>>>(tb, dec_sa_out_w + (size_t)i * DM * DM, dec_sa_out_b + (size_t)i * DM, dc, da, MD, DM, DM, 1.f);
        ln_k<<<MD, 256, 0, stream>>>(da, dec_ln1_g + (size_t)i * DM, dec_ln1_b + (size_t)i * DM);
        { float* t = dc; dc = da; da = t; }

        // --- cross-attention ---
        const float* Wc  = dec_ca_w + (size_t)i * 3 * DM * DM;
        const float* Bc  = dec_ca_b + (size_t)i * 3 * DM;
        float* qb  = reg1;                        // [MD][512]
        float* kvp = reg1 + (size_t)MD * DM;      // [ME][1024]
        mgemm_k<0><<<mg(MD, DM), 256, 0, stream>>>(dc,  Wc, Bc, nullptr, qb, MD, DM, DM, 1.f);
        mgemm_k<0><<<mg(ME, 2 * DM), 256, 0, stream>>>(mem, Wc + (size_t)DM * DM, Bc + DM, nullptr, kvp, ME, 2 * DM, DM, 1.f);
        attn_score_k<<<dim3(SEQ / 128, TGT / 128, BH), 256, 0, stream>>>(qb, DM, kvp, 2 * DM, scb, TGT, SEQ, 0);
        softmax_bf_k<<<BH * TGT, 256, 0, stream>>>(scb, SEQ);
        attn_av_k<<<dim3(TGT / 128, BH), 256, 0, stream>>>(scb, kvp + DM, 2 * DM, tb, TGT, SEQ);
        mgemm_k<0><<<mg(MD, DM), 256, 0, stream>>>(tb, dec_ca_out_w + (size_t)i * DM * DM, dec_ca_out_b + (size_t)i * DM, dc, da, MD, DM, DM, 1.f);
        ln_k<<<MD, 256, 0, stream>>>(da, dec_ln2_g + (size_t)i * DM, dec_ln2_b + (size_t)i * DM);
        { float* t = dc; dc = da; da = t; }

        // --- feed-forward ---
        mgemm_k<1><<<mg(MD, FFD), 256, 0, stream>>>(dc, dec_ff1_w + (size_t)i * FFD * DM, dec_ff1_b + (size_t)i * FFD, nullptr, reg1, MD, FFD, DM, 1.f);
        mgemm_k<0><<<mg(MD, DM), 256, 0, stream>>>(reg1, dec_ff2_w + (size_t)i * DM * FFD, dec_ff2_b + (size_t)i * DM, dc, da, MD, DM, FFD, 1.f);
        ln_k<<<MD, 256, 0, stream>>>(da, dec_ln3_g + (size_t)i * DM, dec_ln3_b + (size_t)i * DM);
        { float* t = dc; dc = da; da = t; }
    }

    // ===== final projection (N=64, MFMA GEMM, fp32 into d_out) =====
    mgemm_k<0><<<mg(MD, HD), 256, 0, stream>>>(dc, out_w, out_b, nullptr, (float*)d_out, MD, HD, DM, 1.f);
}

// Round 7
// 1886.319 us; speedup vs baseline: 10.3633x; 1.3388x over previous
//
#include <hip/hip_runtime.h>
#include <hip/hip_bf16.h>
#include <math.h>

#define BB 4
#define SEQ 512
#define TGT 256
#define DM 512
#define FFD 2048
#define NH 8
#define HD 64
#define NL 6

typedef unsigned short u16;
typedef __attribute__((ext_vector_type(4))) float f4;
typedef __attribute__((ext_vector_type(4))) unsigned short us4;
typedef __attribute__((ext_vector_type(8))) unsigned short us8;
typedef __attribute__((ext_vector_type(8))) short s8;

__device__ inline u16 f2b(float f) {
    __hip_bfloat16 h = __float2bfloat16(f);
    return *reinterpret_cast<u16*>(&h);
}
__device__ inline float b2f(u16 u) {
    unsigned int x = ((unsigned int)u) << 16;
    float f;
    __builtin_memcpy(&f, &x, 4);
    return f;
}
__device__ inline us4 cvt4(f4 v) {
    us4 u;
    u.x = f2b(v.x); u.y = f2b(v.y); u.z = f2b(v.z); u.w = f2b(v.w);
    return u;
}

// ---------------- fp32 -> bf16 cast (4 elems/thread) ----------------
__global__ __launch_bounds__(256) void cast4_k(const float* __restrict__ in,
                                               u16* __restrict__ out, int n4)
{
    int i = blockIdx.x * blockDim.x + threadIdx.x;
    if (i < n4) ((us4*)out)[i] = cvt4(((const f4*)in)[i]);
}

// ============ MFMA GEMM, bf16 in, 64x64 tile, 2-stage pipeline ============
// C[M,N] = relu?(alpha*(A @ W^T + bias)) + resid ; A: MxK bf16, W: NxK bf16.
// M%64==0, N%64==0, K%32==0. Out bf16 (OUTF32=0) or fp32 (OUTF32=1).
template <int RELU, int OUTF32>
__global__ __launch_bounds__(256) void mgemm_k(
    const u16* __restrict__ A, const u16* __restrict__ W,
    const float* __restrict__ bias, const u16* __restrict__ resid,
    void* __restrict__ Cv, int M, int N, int K, float alpha)
{
    __shared__ u16 As[64][40];
    __shared__ u16 Bs[64][40];
    const int bm = blockIdx.y * 64, bn = blockIdx.x * 64;
    const int tid = threadIdx.x;
    const int wave = tid >> 6, lane = tid & 63;
    const int wr = (wave >> 1) * 32, wc = (wave & 1) * 32;
    const int lm = lane & 15, quad = lane >> 4;
    const int sr = tid >> 2;          // 0..63 staging row
    const int sc = (tid & 3) * 8;     // 0,8,16,24 staging col (one us8)

    const u16* Arow = A + (size_t)(bm + sr) * K + sc;
    const u16* Wrow = W + (size_t)(bn + sr) * K + sc;

    us8 a = *(const us8*)(Arow);
    us8 b = *(const us8*)(Wrow);

    f4 acc[2][2];
#pragma unroll
    for (int i = 0; i < 2; i++)
#pragma unroll
        for (int j = 0; j < 2; j++) acc[i][j] = (f4)(0.f);

    for (int k0 = 0; k0 < K; k0 += 32) {
        *(us8*)&As[sr][sc] = a;
        *(us8*)&Bs[sr][sc] = b;
        __syncthreads();
        if (k0 + 32 < K) {  // prefetch next k-tile, overlaps MFMA
            a = *(const us8*)(Arow + k0 + 32);
            b = *(const us8*)(Wrow + k0 + 32);
        }
        s8 af[2], bfr[2];
#pragma unroll
        for (int i = 0; i < 2; i++) af[i] = *(const s8*)&As[wr + i * 16 + lm][quad * 8];
#pragma unroll
        for (int j = 0; j < 2; j++) bfr[j] = *(const s8*)&Bs[wc + j * 16 + lm][quad * 8];
#pragma unroll
        for (int i = 0; i < 2; i++)
#pragma unroll
            for (int j = 0; j < 2; j++)
                acc[i][j] = __builtin_amdgcn_mfma_f32_16x16x32_bf16(af[i], bfr[j], acc[i][j], 0, 0, 0);
        __syncthreads();
    }

#pragma unroll
    for (int j = 0; j < 2; j++) {
        int n = bn + wc + j * 16 + lm;
        float bv = bias[n];
#pragma unroll
        for (int i = 0; i < 2; i++) {
#pragma unroll
            for (int r = 0; r < 4; r++) {
                int m = bm + wr + i * 16 + quad * 4 + r;
                float v = (acc[i][j][r] + bv) * alpha;
                if (RELU) v = fmaxf(v, 0.f);
                size_t off = (size_t)m * N + n;
                if (resid) v += b2f(resid[off]);
                if (OUTF32) ((float*)Cv)[off] = v;
                else        ((u16*)Cv)[off]  = f2b(v);
            }
        }
    }
}

// ============ MFMA attention scores: S[bh][q][k] = bf16(QK^T*0.125, causal) ============
// Q,K bf16, row strides qs/ks. grid (Sk/128, Sq/128, B*NH)
__global__ __launch_bounds__(256) void attn_score_k(
    const u16* __restrict__ Q, int qs,
    const u16* __restrict__ Kp, int ks,
    u16* __restrict__ S, int Sq, int Sk, int causal)
{
    __shared__ u16 Qs[128][72];
    __shared__ u16 Ks[128][72];
    const int bn = blockIdx.x * 128, bm = blockIdx.y * 128;
    const int bh = blockIdx.z, b = bh >> 3, h = bh & 7;
    const int tid = threadIdx.x;
    const int wave = tid >> 6, lane = tid & 63;
    const int wr = (wave >> 1) * 64, wc = (wave & 1) * 64;
    const int lm = lane & 15, quad = lane >> 4;

    const u16* Qb = Q + (size_t)(b * Sq + bm) * qs + h * HD;
    const u16* Kb = Kp + (size_t)(b * Sk + bn) * ks + h * HD;
#pragma unroll
    for (int pass = 0; pass < 4; pass++) {
        int c = pass * 256 + tid;
        int r = c >> 3, col = (c & 7) * 8;
        *(us8*)&Qs[r][col] = *(const us8*)(Qb + (size_t)r * qs + col);
        *(us8*)&Ks[r][col] = *(const us8*)(Kb + (size_t)r * ks + col);
    }
    __syncthreads();

    f4 acc[4][4];
#pragma unroll
    for (int i = 0; i < 4; i++)
#pragma unroll
        for (int j = 0; j < 4; j++) acc[i][j] = (f4)(0.f);
#pragma unroll
    for (int kk = 0; kk < 2; kk++) {
        s8 af[4], bfr[4];
#pragma unroll
        for (int i = 0; i < 4; i++) af[i] = *(const s8*)&Qs[wr + i * 16 + lm][kk * 32 + quad * 8];
#pragma unroll
        for (int j = 0; j < 4; j++) bfr[j] = *(const s8*)&Ks[wc + j * 16 + lm][kk * 32 + quad * 8];
#pragma unroll
        for (int i = 0; i < 4; i++)
#pragma unroll
            for (int j = 0; j < 4; j++)
                acc[i][j] = __builtin_amdgcn_mfma_f32_16x16x32_bf16(af[i], bfr[j], acc[i][j], 0, 0, 0);
    }

    u16* Sb = S + (size_t)bh * Sq * Sk;
#pragma unroll
    for (int j = 0; j < 4; j++) {
        int n = bn + wc + j * 16 + lm;
#pragma unroll
        for (int i = 0; i < 4; i++) {
#pragma unroll
            for (int r = 0; r < 4; r++) {
                int m = bm + wr + i * 16 + quad * 4 + r;
                float v = acc[i][j][r] * 0.125f;
                if (causal && n > m) v = -1e9f;
                Sb[(size_t)m * Sk + n] = f2b(v);
            }
        }
    }
}

// ============ softmax over bf16 rows (in-place), Sk in {256,512} ============
__global__ __launch_bounds__(256) void softmax_bf_k(u16* __restrict__ S, int Sk)
{
    u16* row = S + (size_t)blockIdx.x * Sk;
    int tid = threadIdx.x;
    __shared__ float red[256];
    int E = Sk >> 8;
    float v[2];
    float m = -1e30f;
    for (int e = 0; e < E; e++) {
        v[e] = b2f(row[tid + e * 256]);
        m = fmaxf(m, v[e]);
    }
    red[tid] = m;
    __syncthreads();
    for (int st = 128; st > 0; st >>= 1) {
        if (tid < st) red[tid] = fmaxf(red[tid], red[tid + st]);
        __syncthreads();
    }
    m = red[0];
    __syncthreads();
    float s = 0.f;
    for (int e = 0; e < E; e++) {
        v[e] = expf(v[e] - m);
        s += v[e];
    }
    red[tid] = s;
    __syncthreads();
    for (int st = 128; st > 0; st >>= 1) {
        if (tid < st) red[tid] += red[tid + st];
        __syncthreads();
    }
    float inv = 1.f / red[0];
    for (int e = 0; e < E; e++) row[tid + e * 256] = f2b(v[e] * inv);
}

// ============ MFMA AV: O[b*Sq+m][h*64+n] = P @ V ; P,V,O bf16 ============
__global__ __launch_bounds__(256) void attn_av_k(
    const u16* __restrict__ S, const u16* __restrict__ V, int vs,
    u16* __restrict__ O, int Sq, int Sk)
{
    __shared__ u16 Ps[128][40];
    __shared__ u16 Vs[64][40];
    const int bm = blockIdx.x * 128;
    const int bh = blockIdx.y, b = bh >> 3, h = bh & 7;
    const int tid = threadIdx.x;
    const int wave = tid >> 6, lane = tid & 63;
    const int lm = lane & 15, quad = lane >> 4;
    const int wr = wave * 32;
    const int spr = tid >> 2, spc = (tid & 3) * 8;   // 64 rows/pass, one us8
    const int vn = tid & 63, vkb = tid >> 6;

    f4 acc[2][4];
#pragma unroll
    for (int i = 0; i < 2; i++)
#pragma unroll
        for (int j = 0; j < 4; j++) acc[i][j] = (f4)(0.f);

    const u16* Sb = S + (size_t)bh * Sq * Sk + (size_t)bm * Sk;
    const u16* Vb = V + (size_t)(b * Sk) * vs + h * HD;

    for (int k0 = 0; k0 < Sk; k0 += 32) {
#pragma unroll
        for (int pass = 0; pass < 2; pass++) {
            int r = pass * 64 + spr;
            *(us8*)&Ps[r][spc] = *(const us8*)(Sb + (size_t)r * Sk + k0 + spc);
        }
#pragma unroll
        for (int pass = 0; pass < 8; pass++) {
            int k = pass * 4 + vkb;
            Vs[vn][k] = Vb[(size_t)(k0 + k) * vs + vn];
        }
        __syncthreads();
        s8 bfr[4];
#pragma unroll
        for (int j = 0; j < 4; j++) bfr[j] = *(const s8*)&Vs[j * 16 + lm][quad * 8];
#pragma unroll
        for (int i = 0; i < 2; i++) {
            s8 af = *(const s8*)&Ps[wr + i * 16 + lm][quad * 8];
#pragma unroll
            for (int j = 0; j < 4; j++)
                acc[i][j] = __builtin_amdgcn_mfma_f32_16x16x32_bf16(af, bfr[j], acc[i][j], 0, 0, 0);
        }
        __syncthreads();
    }

#pragma unroll
    for (int i = 0; i < 2; i++) {
#pragma unroll
        for (int j = 0; j < 4; j++) {
            int n = j * 16 + lm;
#pragma unroll
            for (int r = 0; r < 4; r++) {
                int m = bm + wr + i * 16 + quad * 4 + r;
                O[(size_t)(b * Sq + m) * DM + h * HD + n] = f2b(acc[i][j][r]);
            }
        }
    }
}

// ---------------- positional encodings (bf16) ----------------
__global__ void add_pe_enc(u16* __restrict__ x)
{
    int idx = blockIdx.x * blockDim.x + threadIdx.x;
    if (idx >= BB * SEQ * DM) return;
    int c = idx % DM;
    int s = (idx / DM) % SEQ;
    float dv = expf((float)(c & ~1) * (-9.210340371976184f / (float)DM));
    float ang = (float)s * dv;
    x[idx] = f2b(b2f(x[idx]) + ((c & 1) ? cosf(ang) : sinf(ang)));
}

__global__ void add_pe_dec(u16* __restrict__ x, int n)
{
    int idx = blockIdx.x * blockDim.x + threadIdx.x;
    if (idx >= n) return;
    if (idx & 1) x[idx] = f2b(b2f(x[idx]) + 1.f);
}

// ---------------- layernorm (bf16 row of 512, fp32 math) ----------------
__global__ __launch_bounds__(256) void ln_k(u16* __restrict__ x,
                                            const float* __restrict__ g,
                                            const float* __restrict__ b)
{
    int row = blockIdx.x;
    u16* xr = x + (size_t)row * DM;
    int tid = threadIdx.x;
    float v0 = b2f(xr[tid]), v1 = b2f(xr[tid + 256]);
    __shared__ float red[256];
    red[tid] = v0 + v1;
    __syncthreads();
    for (int st = 128; st > 0; st >>= 1) {
        if (tid < st) red[tid] += red[tid + st];
        __syncthreads();
    }
    float mean = red[0] * (1.f / DM);
    __syncthreads();
    float d0 = v0 - mean, d1 = v1 - mean;
    red[tid] = d0 * d0 + d1 * d1;
    __syncthreads();
    for (int st = 128; st > 0; st >>= 1) {
        if (tid < st) red[tid] += red[tid + st];
        __syncthreads();
    }
    float rstd = rsqrtf(red[0] * (1.f / DM) + 1e-5f);
    xr[tid]       = f2b(d0 * rstd * g[tid]       + b[tid]);
    xr[tid + 256] = f2b(d1 * rstd * g[tid + 256] + b[tid + 256]);
}

// ---------------- host orchestration ----------------
static inline dim3 mg(int M, int N) { return dim3(N / 64, M / 64); }
static inline void cast_t(const float* in, u16* out, size_t n, hipStream_t s) {
    int n4 = (int)(n / 4);
    cast4_k<<<(n4 + 255) / 256, 256, 0, s>>>(in, out, n4);
}

extern "C" void kernel_launch(void* const* d_in, const int* in_sizes, int n_in,
                              void* d_out, int out_size, void* d_ws, size_t ws_size,
                              hipStream_t stream)
{
    const float* src       = (const float*)d_in[0];
    const float* tgt       = (const float*)d_in[1];
    const float* enc_in_w  = (const float*)d_in[2];
    const float* enc_in_b  = (const float*)d_in[3];
    const float* dec_in_w  = (const float*)d_in[4];
    const float* dec_in_b  = (const float*)d_in[5];
    const float* out_w     = (const float*)d_in[6];
    const float* out_b     = (const float*)d_in[7];
    const float* enc_attn_w = (const float*)d_in[8];
    const float* enc_attn_b = (const float*)d_in[9];
    const float* enc_out_w  = (const float*)d_in[10];
    const float* enc_out_b  = (const float*)d_in[11];
    const float* enc_ff1_w  = (const float*)d_in[12];
    const float* enc_ff1_b  = (const float*)d_in[13];
    const float* enc_ff2_w  = (const float*)d_in[14];
    const float* enc_ff2_b  = (const float*)d_in[15];
    const float* enc_ln1_g  = (const float*)d_in[16];
    const float* enc_ln1_b  = (const float*)d_in[17];
    const float* enc_ln2_g  = (const float*)d_in[18];
    const float* enc_ln2_b  = (const float*)d_in[19];
    const float* dec_sa_w     = (const float*)d_in[20];
    const float* dec_sa_b     = (const float*)d_in[21];
    const float* dec_sa_out_w = (const float*)d_in[22];
    const float* dec_sa_out_b = (const float*)d_in[23];
    const float* dec_ca_w     = (const float*)d_in[24];
    const float* dec_ca_b     = (const float*)d_in[25];
    const float* dec_ca_out_w = (const float*)d_in[26];
    const float* dec_ca_out_b = (const float*)d_in[27];
    const float* dec_ff1_w    = (const float*)d_in[28];
    const float* dec_ff1_b    = (const float*)d_in[29];
    const float* dec_ff2_w    = (const float*)d_in[30];
    const float* dec_ff2_b    = (const float*)d_in[31];
    const float* dec_ln1_g    = (const float*)d_in[32];
    const float* dec_ln1_b    = (const float*)d_in[33];
    const float* dec_ln2_g    = (const float*)d_in[34];
    const float* dec_ln2_b    = (const float*)d_in[35];
    const float* dec_ln3_g    = (const float*)d_in[36];
    const float* dec_ln3_b    = (const float*)d_in[37];

    // ---- workspace (all bf16 / u16) ----
    u16* p = (u16*)d_ws;
    u16* xa   = p; p += (size_t)BB * SEQ * DM;        // 1.05M elems
    u16* xb   = p; p += (size_t)BB * SEQ * DM;
    u16* reg1 = p; p += (size_t)BB * SEQ * FFD;       // 4.19M: qkv | ffb | (q + kv)
    u16* tbuf = p; p += (size_t)BB * SEQ * DM;
    u16* scb  = p; p += (size_t)BB * NH * SEQ * SEQ;  // 8.39M
    u16* ya   = p; p += (size_t)BB * TGT * DM;
    u16* yb   = p; p += (size_t)BB * TGT * DM;
    u16* wb   = p;                                    // phase-shared weight region (~50.6 MB)

    const float SQD = 22.627416997969522f;  // sqrt(512)
    const int ME = BB * SEQ;  // 2048
    const int MD = BB * TGT;  // 1024
    const int BH = BB * NH;   // 32

    const size_t SZ_ATTN = (size_t)NL * 3 * DM * DM;   // 4718592
    const size_t SZ_OUT  = (size_t)NL * DM * DM;       // 1572864
    const size_t SZ_FF1  = (size_t)NL * FFD * DM;      // 6291456
    const size_t SZ_FF2  = (size_t)NL * DM * FFD;      // 6291456

    // ===== phase E: cast encoder weights + src =====
    u16* q = wb;
    u16* src_b     = q; q += (size_t)BB * SEQ * HD;
    u16* enc_in_wb = q; q += (size_t)DM * HD;
    u16* enc_at_wb = q; q += SZ_ATTN;
    u16* enc_ow_wb = q; q += SZ_OUT;
    u16* enc_f1_wb = q; q += SZ_FF1;
    u16* enc_f2_wb = q; q += SZ_FF2;
    cast_t(src,        src_b,     (size_t)BB * SEQ * HD, stream);
    cast_t(enc_in_w,   enc_in_wb, (size_t)DM * HD,       stream);
    cast_t(enc_attn_w, enc_at_wb, SZ_ATTN,               stream);
    cast_t(enc_out_w,  enc_ow_wb, SZ_OUT,                stream);
    cast_t(enc_ff1_w,  enc_f1_wb, SZ_FF1,                stream);
    cast_t(enc_ff2_w,  enc_f2_wb, SZ_FF2,                stream);

    // ===== encoder =====
    mgemm_k<0, 0><<<mg(ME, DM), 256, 0, stream>>>(src_b, enc_in_wb, enc_in_b, nullptr, xa, ME, DM, HD, SQD);
    add_pe_enc<<<(ME * DM + 255) / 256, 256, 0, stream>>>(xa);

    u16* cur = xa; u16* alt = xb;
    for (int i = 0; i < NL; i++) {
        const u16* W = enc_at_wb + (size_t)i * 3 * DM * DM;
        const float* Bw = enc_attn_b + (size_t)i * 3 * DM;
        mgemm_k<0, 0><<<mg(ME, 3 * DM), 256, 0, stream>>>(cur, W, Bw, nullptr, reg1, ME, 3 * DM, DM, 1.f);
        attn_score_k<<<dim3(SEQ / 128, SEQ / 128, BH), 256, 0, stream>>>(reg1, 3 * DM, reg1 + DM, 3 * DM, scb, SEQ, SEQ, 0);
        softmax_bf_k<<<BH * SEQ, 256, 0, stream>>>(scb, SEQ);
        attn_av_k<<<dim3(SEQ / 128, BH), 256, 0, stream>>>(scb, reg1 + 2 * DM, 3 * DM, tbuf, SEQ, SEQ);
        mgemm_k<0, 0><<<mg(ME, DM), 256, 0, stream>>>(tbuf, enc_ow_wb + (size_t)i * DM * DM, enc_out_b + (size_t)i * DM, cur, alt, ME, DM, DM, 1.f);
        ln_k<<<ME, 256, 0, stream>>>(alt, enc_ln1_g + (size_t)i * DM, enc_ln1_b + (size_t)i * DM);
        { u16* t = cur; cur = alt; alt = t; }
        mgemm_k<1, 0><<<mg(ME, FFD), 256, 0, stream>>>(cur, enc_f1_wb + (size_t)i * FFD * DM, enc_ff1_b + (size_t)i * FFD, nullptr, reg1, ME, FFD, DM, 1.f);
        mgemm_k<0, 0><<<mg(ME, DM), 256, 0, stream>>>(reg1, enc_f2_wb + (size_t)i * DM * FFD, enc_ff2_b + (size_t)i * DM, cur, alt, ME, DM, FFD, 1.f);
        ln_k<<<ME, 256, 0, stream>>>(alt, enc_ln2_g + (size_t)i * DM, enc_ln2_b + (size_t)i * DM);
        { u16* t = cur; cur = alt; alt = t; }
    }
    u16* mem = cur;  // xa (even swaps) — not in wb region, survives phase D

    // ===== phase D: cast decoder weights + tgt (reuse wb region) =====
    q = wb;
    u16* tgt_b       = q; q += (size_t)BB * TGT * HD;
    u16* dec_in_wb   = q; q += (size_t)DM * HD;
    u16* out_wb      = q; q += (size_t)HD * DM;
    u16* dec_sa_wb   = q; q += SZ_ATTN;
    u16* dec_sao_wb  = q; q += SZ_OUT;
    u16* dec_ca_wb   = q; q += SZ_ATTN;
    u16* dec_cao_wb  = q; q += SZ_OUT;
    u16* dec_f1_wb   = q; q += SZ_FF1;
    u16* dec_f2_wb   = q; q += SZ_FF2;
    cast_t(tgt,          tgt_b,      (size_t)BB * TGT * HD, stream);
    cast_t(dec_in_w,     dec_in_wb,  (size_t)DM * HD,       stream);
    cast_t(out_w,        out_wb,     (size_t)HD * DM,       stream);
    cast_t(dec_sa_w,     dec_sa_wb,  SZ_ATTN,               stream);
    cast_t(dec_sa_out_w, dec_sao_wb, SZ_OUT,                stream);
    cast_t(dec_ca_w,     dec_ca_wb,  SZ_ATTN,               stream);
    cast_t(dec_ca_out_w, dec_cao_wb, SZ_OUT,                stream);
    cast_t(dec_ff1_w,    dec_f1_wb,  SZ_FF1,                stream);
    cast_t(dec_ff2_w,    dec_f2_wb,  SZ_FF2,                stream);

    // ===== decoder =====
    mgemm_k<0, 0><<<mg(MD, DM), 256, 0, stream>>>(tgt_b, dec_in_wb, dec_in_b, nullptr, ya, MD, DM, HD, SQD);
    add_pe_dec<<<(MD * DM + 255) / 256, 256, 0, stream>>>(ya, MD * DM);

    u16* dc = ya; u16* da = yb;
    for (int i = 0; i < NL; i++) {
        // --- self-attention (causal), fused QKV ---
        const u16* W = dec_sa_wb + (size_t)i * 3 * DM * DM;
        const float* Bw = dec_sa_b + (size_t)i * 3 * DM;
        mgemm_k<0, 0><<<mg(MD, 3 * DM), 256, 0, stream>>>(dc, W, Bw, nullptr, reg1, MD, 3 * DM, DM, 1.f);
        attn_score_k<<<dim3(TGT / 128, TGT / 128, BH), 256, 0, stream>>>(reg1, 3 * DM, reg1 + DM, 3 * DM, scb, TGT, TGT, 1);
        softmax_bf_k<<<BH * TGT, 256, 0, stream>>>(scb, TGT);
        attn_av_k<<<dim3(TGT / 128, BH), 256, 0, stream>>>(scb, reg1 + 2 * DM, 3 * DM, tbuf, TGT, TGT);
        mgemm_k<0, 0><<<mg(MD, DM), 256, 0, stream>>>(tbuf, dec_sao_wb + (size_t)i * DM * DM, dec_sa_out_b + (size_t)i * DM, dc, da, MD, DM, DM, 1.f);
        ln_k<<<MD, 256, 0, stream>>>(da, dec_ln1_g + (size_t)i * DM, dec_ln1_b + (size_t)i * DM);
        { u16* t = dc; dc = da; da = t; }

        // --- cross-attention ---
        const u16* Wc = dec_ca_wb + (size_t)i * 3 * DM * DM;
        const float* Bc = dec_ca_b + (size_t)i * 3 * DM;
        u16* qb  = reg1;                        // [MD][512]
        u16* kvp = reg1 + (size_t)MD * DM;      // [ME][1024]
        mgemm_k<0, 0><<<mg(MD, DM), 256, 0, stream>>>(dc, Wc, Bc, nullptr, qb, MD, DM, DM, 1.f);
        mgemm_k<0, 0><<<mg(ME, 2 * DM), 256, 0, stream>>>(mem, Wc + (size_t)DM * DM, Bc + DM, nullptr, kvp, ME, 2 * DM, DM, 1.f);
        attn_score_k<<<dim3(SEQ / 128, TGT / 128, BH), 256, 0, stream>>>(qb, DM, kvp, 2 * DM, scb, TGT, SEQ, 0);
        softmax_bf_k<<<BH * TGT, 256, 0, stream>>>(scb, SEQ);
        attn_av_k<<<dim3(TGT / 128, BH), 256, 0, stream>>>(scb, kvp + DM, 2 * DM, tbuf, TGT, SEQ);
        mgemm_k<0, 0><<<mg(MD, DM), 256, 0, stream>>>(tbuf, dec_cao_wb + (size_t)i * DM * DM, dec_ca_out_b + (size_t)i * DM, dc, da, MD, DM, DM, 1.f);
        ln_k<<<MD, 256, 0, stream>>>(da, dec_ln2_g + (size_t)i * DM, dec_ln2_b + (size_t)i * DM);
        { u16* t = dc; dc = da; da = t; }

        // --- feed-forward ---
        mgemm_k<1, 0><<<mg(MD, FFD), 256, 0, stream>>>(dc, dec_f1_wb + (size_t)i * FFD * DM, dec_ff1_b + (size_t)i * FFD, nullptr, reg1, MD, FFD, DM, 1.f);
        mgemm_k<0, 0><<<mg(MD, DM), 256, 0, stream>>>(reg1, dec_f2_wb + (size_t)i * DM * FFD, dec_ff2_b + (size_t)i * DM, dc, da, MD, DM, FFD, 1.f);
        ln_k<<<MD, 256, 0, stream>>>(da, dec_ln3_g + (size_t)i * DM, dec_ln3_b + (size_t)i * DM);
        { u16* t = dc; dc = da; da = t; }
    }

    // ===== final projection (N=64, fp32 into d_out) =====
    mgemm_k<0, 1><<<mg(MD, HD), 256, 0, stream>>>(dc, out_wb, out_b, nullptr, (float*)d_out, MD, HD, DM, 1.f);
}

// Round 8
// 1703.090 us; speedup vs baseline: 11.4782x; 1.1076x over previous
//
#include <hip/hip_runtime.h>
#include <hip/hip_bf16.h>
#include <math.h>

#define BB 4
#define SEQ 512
#define TGT 256
#define DM 512
#define FFD 2048
#define NH 8
#define HD 64
#define NL 6

typedef unsigned short u16;
typedef __attribute__((ext_vector_type(4))) float f4;
typedef __attribute__((ext_vector_type(4))) unsigned short us4;
typedef __attribute__((ext_vector_type(8))) unsigned short us8;
typedef __attribute__((ext_vector_type(8))) short s8;

__device__ inline u16 f2b(float f) {
    __hip_bfloat16 h = __float2bfloat16(f);
    return *reinterpret_cast<u16*>(&h);
}
__device__ inline float b2f(u16 u) {
    unsigned int x = ((unsigned int)u) << 16;
    float f;
    __builtin_memcpy(&f, &x, 4);
    return f;
}
__device__ inline us4 cvt4(f4 v) {
    us4 u;
    u.x = f2b(v.x); u.y = f2b(v.y); u.z = f2b(v.z); u.w = f2b(v.w);
    return u;
}

// ---------------- fp32 -> bf16 cast (4 elems/thread) ----------------
__global__ __launch_bounds__(256) void cast4_k(const float* __restrict__ in,
                                               u16* __restrict__ out, int n4)
{
    int i = blockIdx.x * blockDim.x + threadIdx.x;
    if (i < n4) ((us4*)out)[i] = cvt4(((const f4*)in)[i]);
}

// ============ MFMA GEMM, bf16, BMx64 tile, BK=64, double-buffered LDS ============
// C[M,N] = relu?(alpha*(A @ W^T + bias)) + resid ; A: MxK bf16, W: NxK bf16.
// M%BM==0, N%64==0, K%64==0. BM in {64,32}. One barrier per k-iteration.
template <int RELU, int OUTF32, int BM>
__global__ __launch_bounds__(256) void mgemm_k(
    const u16* __restrict__ A, const u16* __restrict__ W,
    const float* __restrict__ bias, const u16* __restrict__ resid,
    void* __restrict__ Cv, int M, int N, int K, float alpha)
{
    constexpr int MI = BM / 32;               // acc rows per wave (2 or 1)
    __shared__ u16 As[2][BM][72];             // BK=64 cols + 8 pad
    __shared__ u16 Bs[2][64][72];
    const int bm = blockIdx.y * BM, bn = blockIdx.x * 64;
    const int tid = threadIdx.x;
    const int wave = tid >> 6, lane = tid & 63;
    const int wr = (wave >> 1) * (BM / 2), wc = (wave & 1) * 32;
    const int lm = lane & 15, quad = lane >> 4;
    // B staging: 64 rows, 4 threads/row, 16 u16 each
    const int sbr = tid >> 2, sbc = (tid & 3) * 16;
    // A staging: BM rows; BM==64: same as B; BM==32: 8 threads/row, 8 u16 each
    const int sar = (BM == 64) ? (tid >> 2) : (tid >> 3);
    const int sac = (BM == 64) ? ((tid & 3) * 16) : ((tid & 7) * 8);

    const u16* Arow = A + (size_t)(bm + sar) * K + sac;
    const u16* Wrow = W + (size_t)(bn + sbr) * K + sbc;

    us8 a0 = *(const us8*)(Arow);
    us8 a1;
    if (BM == 64) a1 = *(const us8*)(Arow + 8);
    us8 b0 = *(const us8*)(Wrow);
    us8 b1 = *(const us8*)(Wrow + 8);

    f4 acc[MI][2];
#pragma unroll
    for (int i = 0; i < MI; i++)
#pragma unroll
        for (int j = 0; j < 2; j++) acc[i][j] = (f4)(0.f);

    const int nk = K >> 6;
    *(us8*)&As[0][sar][sac] = a0;
    if (BM == 64) *(us8*)&As[0][sar][sac + 8] = a1;
    *(us8*)&Bs[0][sbr][sbc] = b0;
    *(us8*)&Bs[0][sbr][sbc + 8] = b1;
    __syncthreads();

    for (int t = 0; t < nk; t++) {
        const int cb = t & 1;
        if (t + 1 < nk) {  // global prefetch overlaps MFMA below
            int off = (t + 1) << 6;
            a0 = *(const us8*)(Arow + off);
            if (BM == 64) a1 = *(const us8*)(Arow + off + 8);
            b0 = *(const us8*)(Wrow + off);
            b1 = *(const us8*)(Wrow + off + 8);
        }
#pragma unroll
        for (int ks = 0; ks < 2; ks++) {
            s8 af[MI], bfr[2];
#pragma unroll
            for (int i = 0; i < MI; i++) af[i] = *(const s8*)&As[cb][wr + i * 16 + lm][ks * 32 + quad * 8];
#pragma unroll
            for (int j = 0; j < 2; j++) bfr[j] = *(const s8*)&Bs[cb][wc + j * 16 + lm][ks * 32 + quad * 8];
#pragma unroll
            for (int i = 0; i < MI; i++)
#pragma unroll
                for (int j = 0; j < 2; j++)
                    acc[i][j] = __builtin_amdgcn_mfma_f32_16x16x32_bf16(af[i], bfr[j], acc[i][j], 0, 0, 0);
        }
        if (t + 1 < nk) {
            const int nb = cb ^ 1;
            *(us8*)&As[nb][sar][sac] = a0;
            if (BM == 64) *(us8*)&As[nb][sar][sac + 8] = a1;
            *(us8*)&Bs[nb][sbr][sbc] = b0;
            *(us8*)&Bs[nb][sbr][sbc + 8] = b1;
            __syncthreads();
        }
    }

#pragma unroll
    for (int j = 0; j < 2; j++) {
        int n = bn + wc + j * 16 + lm;
        float bv = bias[n];
#pragma unroll
        for (int i = 0; i < MI; i++) {
#pragma unroll
            for (int r = 0; r < 4; r++) {
                int m = bm + wr + i * 16 + quad * 4 + r;
                float v = (acc[i][j][r] + bv) * alpha;
                if (RELU) v = fmaxf(v, 0.f);
                size_t off = (size_t)m * N + n;
                if (resid) v += b2f(resid[off]);
                if (OUTF32) ((float*)Cv)[off] = v;
                else        ((u16*)Cv)[off]  = f2b(v);
            }
        }
    }
}

// ============ MFMA attention scores: S[bh][q][k] = bf16(QK^T*0.125, causal) ============
__global__ __launch_bounds__(256) void attn_score_k(
    const u16* __restrict__ Q, int qs,
    const u16* __restrict__ Kp, int ks,
    u16* __restrict__ S, int Sq, int Sk, int causal)
{
    __shared__ u16 Qs[128][72];
    __shared__ u16 Ks[128][72];
    const int bn = blockIdx.x * 128, bm = blockIdx.y * 128;
    const int bh = blockIdx.z, b = bh >> 3, h = bh & 7;
    const int tid = threadIdx.x;
    const int wave = tid >> 6, lane = tid & 63;
    const int wr = (wave >> 1) * 64, wc = (wave & 1) * 64;
    const int lm = lane & 15, quad = lane >> 4;

    const u16* Qb = Q + (size_t)(b * Sq + bm) * qs + h * HD;
    const u16* Kb = Kp + (size_t)(b * Sk + bn) * ks + h * HD;
#pragma unroll
    for (int pass = 0; pass < 4; pass++) {
        int c = pass * 256 + tid;
        int r = c >> 3, col = (c & 7) * 8;
        *(us8*)&Qs[r][col] = *(const us8*)(Qb + (size_t)r * qs + col);
        *(us8*)&Ks[r][col] = *(const us8*)(Kb + (size_t)r * ks + col);
    }
    __syncthreads();

    f4 acc[4][4];
#pragma unroll
    for (int i = 0; i < 4; i++)
#pragma unroll
        for (int j = 0; j < 4; j++) acc[i][j] = (f4)(0.f);
#pragma unroll
    for (int kk = 0; kk < 2; kk++) {
        s8 af[4], bfr[4];
#pragma unroll
        for (int i = 0; i < 4; i++) af[i] = *(const s8*)&Qs[wr + i * 16 + lm][kk * 32 + quad * 8];
#pragma unroll
        for (int j = 0; j < 4; j++) bfr[j] = *(const s8*)&Ks[wc + j * 16 + lm][kk * 32 + quad * 8];
#pragma unroll
        for (int i = 0; i < 4; i++)
#pragma unroll
            for (int j = 0; j < 4; j++)
                acc[i][j] = __builtin_amdgcn_mfma_f32_16x16x32_bf16(af[i], bfr[j], acc[i][j], 0, 0, 0);
    }

    u16* Sb = S + (size_t)bh * Sq * Sk;
#pragma unroll
    for (int j = 0; j < 4; j++) {
        int n = bn + wc + j * 16 + lm;
#pragma unroll
        for (int i = 0; i < 4; i++) {
#pragma unroll
            for (int r = 0; r < 4; r++) {
                int m = bm + wr + i * 16 + quad * 4 + r;
                float v = acc[i][j][r] * 0.125f;
                if (causal && n > m) v = -1e9f;
                Sb[(size_t)m * Sk + n] = f2b(v);
            }
        }
    }
}

// ============ softmax over bf16 rows (in-place), Sk in {256,512} ============
__global__ __launch_bounds__(256) void softmax_bf_k(u16* __restrict__ S, int Sk)
{
    u16* row = S + (size_t)blockIdx.x * Sk;
    int tid = threadIdx.x;
    __shared__ float red[256];
    int E = Sk >> 8;
    float v[2];
    float m = -1e30f;
    for (int e = 0; e < E; e++) {
        v[e] = b2f(row[tid + e * 256]);
        m = fmaxf(m, v[e]);
    }
    red[tid] = m;
    __syncthreads();
    for (int st = 128; st > 0; st >>= 1) {
        if (tid < st) red[tid] = fmaxf(red[tid], red[tid + st]);
        __syncthreads();
    }
    m = red[0];
    __syncthreads();
    float s = 0.f;
    for (int e = 0; e < E; e++) {
        v[e] = expf(v[e] - m);
        s += v[e];
    }
    red[tid] = s;
    __syncthreads();
    for (int st = 128; st > 0; st >>= 1) {
        if (tid < st) red[tid] += red[tid + st];
        __syncthreads();
    }
    float inv = 1.f / red[0];
    for (int e = 0; e < E; e++) row[tid + e * 256] = f2b(v[e] * inv);
}

// ============ MFMA AV: O[b*Sq+m][h*64+n] = P @ V ; P,V,O bf16 ============
__global__ __launch_bounds__(256) void attn_av_k(
    const u16* __restrict__ S, const u16* __restrict__ V, int vs,
    u16* __restrict__ O, int Sq, int Sk)
{
    __shared__ u16 Ps[128][40];
    __shared__ u16 Vs[64][40];
    const int bm = blockIdx.x * 128;
    const int bh = blockIdx.y, b = bh >> 3, h = bh & 7;
    const int tid = threadIdx.x;
    const int wave = tid >> 6, lane = tid & 63;
    const int lm = lane & 15, quad = lane >> 4;
    const int wr = wave * 32;
    const int spr = tid >> 2, spc = (tid & 3) * 8;
    const int vn = tid & 63, vkb = tid >> 6;

    f4 acc[2][4];
#pragma unroll
    for (int i = 0; i < 2; i++)
#pragma unroll
        for (int j = 0; j < 4; j++) acc[i][j] = (f4)(0.f);

    const u16* Sb = S + (size_t)bh * Sq * Sk + (size_t)bm * Sk;
    const u16* Vb = V + (size_t)(b * Sk) * vs + h * HD;

    for (int k0 = 0; k0 < Sk; k0 += 32) {
#pragma unroll
        for (int pass = 0; pass < 2; pass++) {
            int r = pass * 64 + spr;
            *(us8*)&Ps[r][spc] = *(const us8*)(Sb + (size_t)r * Sk + k0 + spc);
        }
#pragma unroll
        for (int pass = 0; pass < 8; pass++) {
            int k = pass * 4 + vkb;
            Vs[vn][k] = Vb[(size_t)(k0 + k) * vs + vn];
        }
        __syncthreads();
        s8 bfr[4];
#pragma unroll
        for (int j = 0; j < 4; j++) bfr[j] = *(const s8*)&Vs[j * 16 + lm][quad * 8];
#pragma unroll
        for (int i = 0; i < 2; i++) {
            s8 af = *(const s8*)&Ps[wr + i * 16 + lm][quad * 8];
#pragma unroll
            for (int j = 0; j < 4; j++)
                acc[i][j] = __builtin_amdgcn_mfma_f32_16x16x32_bf16(af, bfr[j], acc[i][j], 0, 0, 0);
        }
        __syncthreads();
    }

#pragma unroll
    for (int i = 0; i < 2; i++) {
#pragma unroll
        for (int j = 0; j < 4; j++) {
            int n = j * 16 + lm;
#pragma unroll
            for (int r = 0; r < 4; r++) {
                int m = bm + wr + i * 16 + quad * 4 + r;
                O[(size_t)(b * Sq + m) * DM + h * HD + n] = f2b(acc[i][j][r]);
            }
        }
    }
}

// ---------------- positional encodings (bf16) ----------------
__global__ void add_pe_enc(u16* __restrict__ x)
{
    int idx = blockIdx.x * blockDim.x + threadIdx.x;
    if (idx >= BB * SEQ * DM) return;
    int c = idx % DM;
    int s = (idx / DM) % SEQ;
    float dv = expf((float)(c & ~1) * (-9.210340371976184f / (float)DM));
    float ang = (float)s * dv;
    x[idx] = f2b(b2f(x[idx]) + ((c & 1) ? cosf(ang) : sinf(ang)));
}

__global__ void add_pe_dec(u16* __restrict__ x, int n)
{
    int idx = blockIdx.x * blockDim.x + threadIdx.x;
    if (idx >= n) return;
    if (idx & 1) x[idx] = f2b(b2f(x[idx]) + 1.f);
}

// ---------------- layernorm (bf16 row of 512, fp32 math) ----------------
__global__ __launch_bounds__(256) void ln_k(u16* __restrict__ x,
                                            const float* __restrict__ g,
                                            const float* __restrict__ b)
{
    int row = blockIdx.x;
    u16* xr = x + (size_t)row * DM;
    int tid = threadIdx.x;
    float v0 = b2f(xr[tid]), v1 = b2f(xr[tid + 256]);
    __shared__ float red[256];
    red[tid] = v0 + v1;
    __syncthreads();
    for (int st = 128; st > 0; st >>= 1) {
        if (tid < st) red[tid] += red[tid + st];
        __syncthreads();
    }
    float mean = red[0] * (1.f / DM);
    __syncthreads();
    float d0 = v0 - mean, d1 = v1 - mean;
    red[tid] = d0 * d0 + d1 * d1;
    __syncthreads();
    for (int st = 128; st > 0; st >>= 1) {
        if (tid < st) red[tid] += red[tid + st];
        __syncthreads();
    }
    float rstd = rsqrtf(red[0] * (1.f / DM) + 1e-5f);
    xr[tid]       = f2b(d0 * rstd * g[tid]       + b[tid]);
    xr[tid + 256] = f2b(d1 * rstd * g[tid + 256] + b[tid + 256]);
}

// ---------------- host orchestration ----------------
static inline dim3 mg64(int M, int N) { return dim3(N / 64, M / 64); }
static inline dim3 mg32(int M, int N) { return dim3(N / 64, M / 32); }
static inline void cast_t(const float* in, u16* out, size_t n, hipStream_t s) {
    int n4 = (int)(n / 4);
    cast4_k<<<(n4 + 255) / 256, 256, 0, s>>>(in, out, n4);
}

extern "C" void kernel_launch(void* const* d_in, const int* in_sizes, int n_in,
                              void* d_out, int out_size, void* d_ws, size_t ws_size,
                              hipStream_t stream)
{
    const float* src       = (const float*)d_in[0];
    const float* tgt       = (const float*)d_in[1];
    const float* enc_in_w  = (const float*)d_in[2];
    const float* enc_in_b  = (const float*)d_in[3];
    const float* dec_in_w  = (const float*)d_in[4];
    const float* dec_in_b  = (const float*)d_in[5];
    const float* out_w     = (const float*)d_in[6];
    const float* out_b     = (const float*)d_in[7];
    const float* enc_attn_w = (const float*)d_in[8];
    const float* enc_attn_b = (const float*)d_in[9];
    const float* enc_out_w  = (const float*)d_in[10];
    const float* enc_out_b  = (const float*)d_in[11];
    const float* enc_ff1_w  = (const float*)d_in[12];
    const float* enc_ff1_b  = (const float*)d_in[13];
    const float* enc_ff2_w  = (const float*)d_in[14];
    const float* enc_ff2_b  = (const float*)d_in[15];
    const float* enc_ln1_g  = (const float*)d_in[16];
    const float* enc_ln1_b  = (const float*)d_in[17];
    const float* enc_ln2_g  = (const float*)d_in[18];
    const float* enc_ln2_b  = (const float*)d_in[19];
    const float* dec_sa_w     = (const float*)d_in[20];
    const float* dec_sa_b     = (const float*)d_in[21];
    const float* dec_sa_out_w = (const float*)d_in[22];
    const float* dec_sa_out_b = (const float*)d_in[23];
    const float* dec_ca_w     = (const float*)d_in[24];
    const float* dec_ca_b     = (const float*)d_in[25];
    const float* dec_ca_out_w = (const float*)d_in[26];
    const float* dec_ca_out_b = (const float*)d_in[27];
    const float* dec_ff1_w    = (const float*)d_in[28];
    const float* dec_ff1_b    = (const float*)d_in[29];
    const float* dec_ff2_w    = (const float*)d_in[30];
    const float* dec_ff2_b    = (const float*)d_in[31];
    const float* dec_ln1_g    = (const float*)d_in[32];
    const float* dec_ln1_b    = (const float*)d_in[33];
    const float* dec_ln2_g    = (const float*)d_in[34];
    const float* dec_ln2_b    = (const float*)d_in[35];
    const float* dec_ln3_g    = (const float*)d_in[36];
    const float* dec_ln3_b    = (const float*)d_in[37];

    // ---- workspace (all bf16 / u16) ----
    u16* p = (u16*)d_ws;
    u16* xa   = p; p += (size_t)BB * SEQ * DM;
    u16* xb   = p; p += (size_t)BB * SEQ * DM;
    u16* reg1 = p; p += (size_t)BB * SEQ * FFD;       // qkv | ffb | (q + kv)
    u16* tbuf = p; p += (size_t)BB * SEQ * DM;
    u16* scb  = p; p += (size_t)BB * NH * SEQ * SEQ;
    u16* ya   = p; p += (size_t)BB * TGT * DM;
    u16* yb   = p; p += (size_t)BB * TGT * DM;
    u16* wb   = p;                                    // phase-shared weight region

    const float SQD = 22.627416997969522f;  // sqrt(512)
    const int ME = BB * SEQ;  // 2048
    const int MD = BB * TGT;  // 1024
    const int BH = BB * NH;   // 32

    const size_t SZ_ATTN = (size_t)NL * 3 * DM * DM;
    const size_t SZ_OUT  = (size_t)NL * DM * DM;
    const size_t SZ_FF1  = (size_t)NL * FFD * DM;
    const size_t SZ_FF2  = (size_t)NL * DM * FFD;

    // ===== phase E: cast encoder weights + src =====
    u16* q = wb;
    u16* src_b     = q; q += (size_t)BB * SEQ * HD;
    u16* enc_in_wb = q; q += (size_t)DM * HD;
    u16* enc_at_wb = q; q += SZ_ATTN;
    u16* enc_ow_wb = q; q += SZ_OUT;
    u16* enc_f1_wb = q; q += SZ_FF1;
    u16* enc_f2_wb = q; q += SZ_FF2;
    cast_t(src,        src_b,     (size_t)BB * SEQ * HD, stream);
    cast_t(enc_in_w,   enc_in_wb, (size_t)DM * HD,       stream);
    cast_t(enc_attn_w, enc_at_wb, SZ_ATTN,               stream);
    cast_t(enc_out_w,  enc_ow_wb, SZ_OUT,                stream);
    cast_t(enc_ff1_w,  enc_f1_wb, SZ_FF1,                stream);
    cast_t(enc_ff2_w,  enc_f2_wb, SZ_FF2,                stream);

    // ===== encoder =====
    mgemm_k<0, 0, 64><<<mg64(ME, DM), 256, 0, stream>>>(src_b, enc_in_wb, enc_in_b, nullptr, xa, ME, DM, HD, SQD);
    add_pe_enc<<<(ME * DM + 255) / 256, 256, 0, stream>>>(xa);

    u16* cur = xa; u16* alt = xb;
    for (int i = 0; i < NL; i++) {
        const u16* W = enc_at_wb + (size_t)i * 3 * DM * DM;
        const float* Bw = enc_attn_b + (size_t)i * 3 * DM;
        mgemm_k<0, 0, 64><<<mg64(ME, 3 * DM), 256, 0, stream>>>(cur, W, Bw, nullptr, reg1, ME, 3 * DM, DM, 1.f);
        attn_score_k<<<dim3(SEQ / 128, SEQ / 128, BH), 256, 0, stream>>>(reg1, 3 * DM, reg1 + DM, 3 * DM, scb, SEQ, SEQ, 0);
        softmax_bf_k<<<BH * SEQ, 256, 0, stream>>>(scb, SEQ);
        attn_av_k<<<dim3(SEQ / 128, BH), 256, 0, stream>>>(scb, reg1 + 2 * DM, 3 * DM, tbuf, SEQ, SEQ);
        mgemm_k<0, 0, 32><<<mg32(ME, DM), 256, 0, stream>>>(tbuf, enc_ow_wb + (size_t)i * DM * DM, enc_out_b + (size_t)i * DM, cur, alt, ME, DM, DM, 1.f);
        ln_k<<<ME, 256, 0, stream>>>(alt, enc_ln1_g + (size_t)i * DM, enc_ln1_b + (size_t)i * DM);
        { u16* t = cur; cur = alt; alt = t; }
        mgemm_k<1, 0, 64><<<mg64(ME, FFD), 256, 0, stream>>>(cur, enc_f1_wb + (size_t)i * FFD * DM, enc_ff1_b + (size_t)i * FFD, nullptr, reg1, ME, FFD, DM, 1.f);
        mgemm_k<0, 0, 32><<<mg32(ME, DM), 256, 0, stream>>>(reg1, enc_f2_wb + (size_t)i * DM * FFD, enc_ff2_b + (size_t)i * DM, cur, alt, ME, DM, FFD, 1.f);
        ln_k<<<ME, 256, 0, stream>>>(alt, enc_ln2_g + (size_t)i * DM, enc_ln2_b + (size_t)i * DM);
        { u16* t = cur; cur = alt; alt = t; }
    }
    u16* mem = cur;  // xa (even swaps) — outside wb region, survives phase D

    // ===== phase D: cast decoder weights + tgt (reuse wb region) =====
    q = wb;
    u16* tgt_b       = q; q += (size_t)BB * TGT * HD;
    u16* dec_in_wb   = q; q += (size_t)DM * HD;
    u16* out_wb      = q; q += (size_t)HD * DM;
    u16* dec_sa_wb   = q; q += SZ_ATTN;
    u16* dec_sao_wb  = q; q += SZ_OUT;
    u16* dec_ca_wb   = q; q += SZ_ATTN;
    u16* dec_cao_wb  = q; q += SZ_OUT;
    u16* dec_f1_wb   = q; q += SZ_FF1;
    u16* dec_f2_wb   = q; q += SZ_FF2;
    cast_t(tgt,          tgt_b,      (size_t)BB * TGT * HD, stream);
    cast_t(dec_in_w,     dec_in_wb,  (size_t)DM * HD,       stream);
    cast_t(out_w,        out_wb,     (size_t)HD * DM,       stream);
    cast_t(dec_sa_w,     dec_sa_wb,  SZ_ATTN,               stream);
    cast_t(dec_sa_out_w, dec_sao_wb, SZ_OUT,                stream);
    cast_t(dec_ca_w,     dec_ca_wb,  SZ_ATTN,               stream);
    cast_t(dec_ca_out_w, dec_cao_wb, SZ_OUT,                stream);
    cast_t(dec_ff1_w,    dec_f1_wb,  SZ_FF1,                stream);
    cast_t(dec_ff2_w,    dec_f2_wb,  SZ_FF2,                stream);

    // ===== decoder =====
    mgemm_k<0, 0, 32><<<mg32(MD, DM), 256, 0, stream>>>(tgt_b, dec_in_wb, dec_in_b, nullptr, ya, MD, DM, HD, SQD);
    add_pe_dec<<<(MD * DM + 255) / 256, 256, 0, stream>>>(ya, MD * DM);

    u16* dc = ya; u16* da = yb;
    for (int i = 0; i < NL; i++) {
        // --- self-attention (causal), fused QKV ---
        const u16* W = dec_sa_wb + (size_t)i * 3 * DM * DM;
        const float* Bw = dec_sa_b + (size_t)i * 3 * DM;
        mgemm_k<0, 0, 64><<<mg64(MD, 3 * DM), 256, 0, stream>>>(dc, W, Bw, nullptr, reg1, MD, 3 * DM, DM, 1.f);
        attn_score_k<<<dim3(TGT / 128, TGT / 128, BH), 256, 0, stream>>>(reg1, 3 * DM, reg1 + DM, 3 * DM, scb, TGT, TGT, 1);
        softmax_bf_k<<<BH * TGT, 256, 0, stream>>>(scb, TGT);
        attn_av_k<<<dim3(TGT / 128, BH), 256, 0, stream>>>(scb, reg1 + 2 * DM, 3 * DM, tbuf, TGT, TGT);
        mgemm_k<0, 0, 32><<<mg32(MD, DM), 256, 0, stream>>>(tbuf, dec_sao_wb + (size_t)i * DM * DM, dec_sa_out_b + (size_t)i * DM, dc, da, MD, DM, DM, 1.f);
        ln_k<<<MD, 256, 0, stream>>>(da, dec_ln1_g + (size_t)i * DM, dec_ln1_b + (size_t)i * DM);
        { u16* t = dc; dc = da; da = t; }

        // --- cross-attention ---
        const u16* Wc = dec_ca_wb + (size_t)i * 3 * DM * DM;
        const float* Bc = dec_ca_b + (size_t)i * 3 * DM;
        u16* qb  = reg1;                        // [MD][512]
        u16* kvp = reg1 + (size_t)MD * DM;      // [ME][1024]
        mgemm_k<0, 0, 32><<<mg32(MD, DM), 256, 0, stream>>>(dc, Wc, Bc, nullptr, qb, MD, DM, DM, 1.f);
        mgemm_k<0, 0, 64><<<mg64(ME, 2 * DM), 256, 0, stream>>>(mem, Wc + (size_t)DM * DM, Bc + DM, nullptr, kvp, ME, 2 * DM, DM, 1.f);
        attn_score_k<<<dim3(SEQ / 128, TGT / 128, BH), 256, 0, stream>>>(qb, DM, kvp, 2 * DM, scb, TGT, SEQ, 0);
        softmax_bf_k<<<BH * TGT, 256, 0, stream>>>(scb, SEQ);
        attn_av_k<<<dim3(TGT / 128, BH), 256, 0, stream>>>(scb, kvp + DM, 2 * DM, tbuf, TGT, SEQ);
        mgemm_k<0, 0, 32><<<mg32(MD, DM), 256, 0, stream>>>(tbuf, dec_cao_wb + (size_t)i * DM * DM, dec_ca_out_b + (size_t)i * DM, dc, da, MD, DM, DM, 1.f);
        ln_k<<<MD, 256, 0, stream>>>(da, dec_ln2_g + (size_t)i * DM, dec_ln2_b + (size_t)i * DM);
        { u16* t = dc; dc = da; da = t; }

        // --- feed-forward ---
        mgemm_k<1, 0, 64><<<mg64(MD, FFD), 256, 0, stream>>>(dc, dec_f1_wb + (size_t)i * FFD * DM, dec_ff1_b + (size_t)i * FFD, nullptr, reg1, MD, FFD, DM, 1.f);
        mgemm_k<0, 0, 32><<<mg32(MD, DM), 256, 0, stream>>>(reg1, dec_f2_wb + (size_t)i * DM * FFD, dec_ff2_b + (size_t)i * DM, dc, da, MD, DM, FFD, 1.f);
        ln_k<<<MD, 256, 0, stream>>>(da, dec_ln3_g + (size_t)i * DM, dec_ln3_b + (size_t)i * DM);
        { u16* t = dc; dc = da; da = t; }
    }

    // ===== final projection (N=64, fp32 into d_out) =====
    mgemm_k<0, 1, 32><<<mg32(MD, HD), 256, 0, stream>>>(dc, out_wb, out_b, nullptr, (float*)d_out, MD, HD, DM, 1.f);
}

// Round 9
// 1318.105 us; speedup vs baseline: 14.8307x; 1.2921x over previous
//
#include <hip/hip_runtime.h>
#include <hip/hip_bf16.h>
#include <math.h>

#define BB 4
#define SEQ 512
#define TGT 256
#define DM 512
#define FFD 2048
#define NH 8
#define HD 64
#define NL 6

typedef unsigned short u16;
typedef __attribute__((ext_vector_type(4))) float f4;
typedef __attribute__((ext_vector_type(4))) unsigned short us4;
typedef __attribute__((ext_vector_type(8))) unsigned short us8;
typedef __attribute__((ext_vector_type(8))) short s8;

__device__ inline u16 f2b(float f) {
    __hip_bfloat16 h = __float2bfloat16(f);
    return *reinterpret_cast<u16*>(&h);
}
__device__ inline float b2f(u16 u) {
    unsigned int x = ((unsigned int)u) << 16;
    float f;
    __builtin_memcpy(&f, &x, 4);
    return f;
}
__device__ inline us4 cvt4(f4 v) {
    us4 u;
    u.x = f2b(v.x); u.y = f2b(v.y); u.z = f2b(v.z); u.w = f2b(v.w);
    return u;
}

// ---------------- fp32 -> bf16 cast (4 elems/thread) ----------------
__global__ __launch_bounds__(256) void cast4_k(const float* __restrict__ in,
                                               u16* __restrict__ out, int n4)
{
    int i = blockIdx.x * blockDim.x + threadIdx.x;
    if (i < n4) ((us4*)out)[i] = cvt4(((const f4*)in)[i]);
}

// ============ MFMA GEMM, bf16, BMx64 tile, BK=64, double-buffered LDS ============
template <int RELU, int OUTF32, int BM>
__global__ __launch_bounds__(256) void mgemm_k(
    const u16* __restrict__ A, const u16* __restrict__ W,
    const float* __restrict__ bias, const u16* __restrict__ resid,
    void* __restrict__ Cv, int M, int N, int K, float alpha)
{
    constexpr int MI = BM / 32;
    __shared__ u16 As[2][BM][72];
    __shared__ u16 Bs[2][64][72];
    const int bm = blockIdx.y * BM, bn = blockIdx.x * 64;
    const int tid = threadIdx.x;
    const int wave = tid >> 6, lane = tid & 63;
    const int wr = (wave >> 1) * (BM / 2), wc = (wave & 1) * 32;
    const int lm = lane & 15, quad = lane >> 4;
    const int sbr = tid >> 2, sbc = (tid & 3) * 16;
    const int sar = (BM == 64) ? (tid >> 2) : (tid >> 3);
    const int sac = (BM == 64) ? ((tid & 3) * 16) : ((tid & 7) * 8);

    const u16* Arow = A + (size_t)(bm + sar) * K + sac;
    const u16* Wrow = W + (size_t)(bn + sbr) * K + sbc;

    us8 a0 = *(const us8*)(Arow);
    us8 a1;
    if (BM == 64) a1 = *(const us8*)(Arow + 8);
    us8 b0 = *(const us8*)(Wrow);
    us8 b1 = *(const us8*)(Wrow + 8);

    f4 acc[MI][2];
#pragma unroll
    for (int i = 0; i < MI; i++)
#pragma unroll
        for (int j = 0; j < 2; j++) acc[i][j] = (f4)(0.f);

    const int nk = K >> 6;
    *(us8*)&As[0][sar][sac] = a0;
    if (BM == 64) *(us8*)&As[0][sar][sac + 8] = a1;
    *(us8*)&Bs[0][sbr][sbc] = b0;
    *(us8*)&Bs[0][sbr][sbc + 8] = b1;
    __syncthreads();

    for (int t = 0; t < nk; t++) {
        const int cb = t & 1;
        if (t + 1 < nk) {
            int off = (t + 1) << 6;
            a0 = *(const us8*)(Arow + off);
            if (BM == 64) a1 = *(const us8*)(Arow + off + 8);
            b0 = *(const us8*)(Wrow + off);
            b1 = *(const us8*)(Wrow + off + 8);
        }
#pragma unroll
        for (int ks = 0; ks < 2; ks++) {
            s8 af[MI], bfr[2];
#pragma unroll
            for (int i = 0; i < MI; i++) af[i] = *(const s8*)&As[cb][wr + i * 16 + lm][ks * 32 + quad * 8];
#pragma unroll
            for (int j = 0; j < 2; j++) bfr[j] = *(const s8*)&Bs[cb][wc + j * 16 + lm][ks * 32 + quad * 8];
#pragma unroll
            for (int i = 0; i < MI; i++)
#pragma unroll
                for (int j = 0; j < 2; j++)
                    acc[i][j] = __builtin_amdgcn_mfma_f32_16x16x32_bf16(af[i], bfr[j], acc[i][j], 0, 0, 0);
        }
        if (t + 1 < nk) {
            const int nb = cb ^ 1;
            *(us8*)&As[nb][sar][sac] = a0;
            if (BM == 64) *(us8*)&As[nb][sar][sac + 8] = a1;
            *(us8*)&Bs[nb][sbr][sbc] = b0;
            *(us8*)&Bs[nb][sbr][sbc + 8] = b1;
            __syncthreads();
        }
    }

#pragma unroll
    for (int j = 0; j < 2; j++) {
        int n = bn + wc + j * 16 + lm;
        float bv = bias[n];
#pragma unroll
        for (int i = 0; i < MI; i++) {
#pragma unroll
            for (int r = 0; r < 4; r++) {
                int m = bm + wr + i * 16 + quad * 4 + r;
                float v = (acc[i][j][r] + bv) * alpha;
                if (RELU) v = fmaxf(v, 0.f);
                size_t off = (size_t)m * N + n;
                if (resid) v += b2f(resid[off]);
                if (OUTF32) ((float*)Cv)[off] = v;
                else        ((u16*)Cv)[off]  = f2b(v);
            }
        }
    }
}

// ============ Fused flash attention ============
// O[b*Sq+m][h*HD+d] = softmax(Q K^T * 0.125 [+causal]) @ V  — all bf16, fp32 state.
// Q rows stride qs, K stride ks, V stride vs; O stride DM. grid (Sq/64, B*NH), 256 thr.
// Per wave: 16 q-rows. K/V tiles of 128.
template <int CAUSAL>
__global__ __launch_bounds__(256) void flash_k(
    const u16* __restrict__ Q, int qs,
    const u16* __restrict__ Kp, int ks,
    const u16* __restrict__ V, int vs,
    u16* __restrict__ O, int Sq, int Sk)
{
    __shared__ u16 Qs[64][72];
    __shared__ u16 Ks[128][72];
    __shared__ u16 Vs[64][136];       // transposed: Vs[d][kv]
    __shared__ u16 Ps[4][16][136];    // per-wave P tile
    const int bm = blockIdx.x * 64;
    const int bh = blockIdx.y, b = bh >> 3, h = bh & 7;
    const int tid = threadIdx.x;
    const int wave = tid >> 6, lane = tid & 63;
    const int lm = lane & 15, quad = lane >> 4;

    // stage Q tile (64x64)
    const u16* Qb = Q + (size_t)(b * Sq + bm) * qs + h * HD;
    {
        int r = tid >> 2, c = (tid & 3) * 16;
        *(us8*)&Qs[r][c]     = *(const us8*)(Qb + (size_t)r * qs + c);
        *(us8*)&Qs[r][c + 8] = *(const us8*)(Qb + (size_t)r * qs + c + 8);
    }

    float mrow[4], lrow[4];
    f4 o[4];
#pragma unroll
    for (int r = 0; r < 4; r++) { mrow[r] = -1e30f; lrow[r] = 0.f; }
#pragma unroll
    for (int nt = 0; nt < 4; nt++) o[nt] = (f4)(0.f);

    const u16* Kb = Kp + (size_t)(b * Sk) * ks + h * HD;
    const u16* Vb = V + (size_t)(b * Sk) * vs + h * HD;
    int nkt = Sk >> 7;
    if (CAUSAL) { int lim = (bm + 63) / 128 + 1; if (lim < nkt) nkt = lim; }

    const int vd = tid & 63, vkb = tid >> 6;
    const int kr = tid >> 3, kc8 = (tid & 7) * 8;

    for (int kt = 0; kt < nkt; kt++) {
        const u16* Kt = Kb + ((size_t)kt << 7) * ks;
        const u16* Vt = Vb + ((size_t)kt << 7) * vs;
#pragma unroll
        for (int p = 0; p < 4; p++) {
            int r = p * 32 + kr;
            *(us8*)&Ks[r][kc8] = *(const us8*)(Kt + (size_t)r * ks + kc8);
        }
#pragma unroll
        for (int p = 0; p < 32; p++) {
            int kv = p * 4 + vkb;
            Vs[vd][kv] = Vt[(size_t)kv * vs + vd];
        }
        __syncthreads();

        // S = Q K^T  (wave's 16 q-rows x 128 kv)
        f4 sa[8];
#pragma unroll
        for (int nt = 0; nt < 8; nt++) sa[nt] = (f4)(0.f);
#pragma unroll
        for (int ks2 = 0; ks2 < 2; ks2++) {
            s8 aq = *(const s8*)&Qs[wave * 16 + lm][ks2 * 32 + quad * 8];
#pragma unroll
            for (int nt = 0; nt < 8; nt++) {
                s8 bk = *(const s8*)&Ks[nt * 16 + lm][ks2 * 32 + quad * 8];
                sa[nt] = __builtin_amdgcn_mfma_f32_16x16x32_bf16(aq, bk, sa[nt], 0, 0, 0);
            }
        }
        // scale + mask + tile row-max
        float tmx[4] = {-1e30f, -1e30f, -1e30f, -1e30f};
#pragma unroll
        for (int nt = 0; nt < 8; nt++) {
#pragma unroll
            for (int r = 0; r < 4; r++) {
                float v = sa[nt][r] * 0.125f;
                if (CAUSAL) {
                    int col = (kt << 7) + nt * 16 + lm;
                    int row = bm + wave * 16 + quad * 4 + r;
                    if (col > row) v = -1e30f;
                }
                sa[nt][r] = v;
                tmx[r] = fmaxf(tmx[r], v);
            }
        }
#pragma unroll
        for (int st = 1; st < 16; st <<= 1)
#pragma unroll
            for (int r = 0; r < 4; r++) tmx[r] = fmaxf(tmx[r], __shfl_xor(tmx[r], st));
        // online update
        float al[4];
#pragma unroll
        for (int r = 0; r < 4; r++) {
            float mn = fmaxf(mrow[r], tmx[r]);
            al[r] = __expf(mrow[r] - mn);
            mrow[r] = mn;
        }
        float ts[4] = {0.f, 0.f, 0.f, 0.f};
#pragma unroll
        for (int nt = 0; nt < 8; nt++) {
#pragma unroll
            for (int r = 0; r < 4; r++) {
                float pe = __expf(sa[nt][r] - mrow[r]);
                sa[nt][r] = pe;
                ts[r] += pe;
            }
        }
#pragma unroll
        for (int st = 1; st < 16; st <<= 1)
#pragma unroll
            for (int r = 0; r < 4; r++) ts[r] += __shfl_xor(ts[r], st);
#pragma unroll
        for (int r = 0; r < 4; r++) lrow[r] = lrow[r] * al[r] + ts[r];
#pragma unroll
        for (int nt = 0; nt < 4; nt++)
#pragma unroll
            for (int r = 0; r < 4; r++) o[nt][r] *= al[r];
        // P -> LDS (C-layout to A-layout transform)
#pragma unroll
        for (int nt = 0; nt < 8; nt++)
#pragma unroll
            for (int r = 0; r < 4; r++)
                Ps[wave][quad * 4 + r][nt * 16 + lm] = f2b(sa[nt][r]);
        // PV
#pragma unroll
        for (int kc = 0; kc < 4; kc++) {
            s8 ap = *(const s8*)&Ps[wave][lm][kc * 32 + quad * 8];
#pragma unroll
            for (int nt = 0; nt < 4; nt++) {
                s8 bv = *(const s8*)&Vs[nt * 16 + lm][kc * 32 + quad * 8];
                o[nt] = __builtin_amdgcn_mfma_f32_16x16x32_bf16(ap, bv, o[nt], 0, 0, 0);
            }
        }
        __syncthreads();
    }

    float inv[4];
#pragma unroll
    for (int r = 0; r < 4; r++) inv[r] = 1.f / lrow[r];
#pragma unroll
    for (int nt = 0; nt < 4; nt++) {
#pragma unroll
        for (int r = 0; r < 4; r++) {
            int m = bm + wave * 16 + quad * 4 + r;
            O[(size_t)(b * Sq + m) * DM + h * HD + nt * 16 + lm] = f2b(o[nt][r] * inv[r]);
        }
    }
}

// ---------------- positional encodings (bf16) ----------------
__global__ void add_pe_enc(u16* __restrict__ x)
{
    int idx = blockIdx.x * blockDim.x + threadIdx.x;
    if (idx >= BB * SEQ * DM) return;
    int c = idx % DM;
    int s = (idx / DM) % SEQ;
    float dv = expf((float)(c & ~1) * (-9.210340371976184f / (float)DM));
    float ang = (float)s * dv;
    x[idx] = f2b(b2f(x[idx]) + ((c & 1) ? cosf(ang) : sinf(ang)));
}

__global__ void add_pe_dec(u16* __restrict__ x, int n)
{
    int idx = blockIdx.x * blockDim.x + threadIdx.x;
    if (idx >= n) return;
    if (idx & 1) x[idx] = f2b(b2f(x[idx]) + 1.f);
}

// ---------------- layernorm (bf16 row of 512, fp32 math) ----------------
__global__ __launch_bounds__(256) void ln_k(u16* __restrict__ x,
                                            const float* __restrict__ g,
                                            const float* __restrict__ b)
{
    int row = blockIdx.x;
    u16* xr = x + (size_t)row * DM;
    int tid = threadIdx.x;
    float v0 = b2f(xr[tid]), v1 = b2f(xr[tid + 256]);
    __shared__ float red[256];
    red[tid] = v0 + v1;
    __syncthreads();
    for (int st = 128; st > 0; st >>= 1) {
        if (tid < st) red[tid] += red[tid + st];
        __syncthreads();
    }
    float mean = red[0] * (1.f / DM);
    __syncthreads();
    float d0 = v0 - mean, d1 = v1 - mean;
    red[tid] = d0 * d0 + d1 * d1;
    __syncthreads();
    for (int st = 128; st > 0; st >>= 1) {
        if (tid < st) red[tid] += red[tid + st];
        __syncthreads();
    }
    float rstd = rsqrtf(red[0] * (1.f / DM) + 1e-5f);
    xr[tid]       = f2b(d0 * rstd * g[tid]       + b[tid]);
    xr[tid + 256] = f2b(d1 * rstd * g[tid + 256] + b[tid + 256]);
}

// ---------------- host orchestration ----------------
static inline dim3 mg64(int M, int N) { return dim3(N / 64, M / 64); }
static inline dim3 mg32(int M, int N) { return dim3(N / 64, M / 32); }
static inline void cast_t(const float* in, u16* out, size_t n, hipStream_t s) {
    int n4 = (int)(n / 4);
    cast4_k<<<(n4 + 255) / 256, 256, 0, s>>>(in, out, n4);
}

extern "C" void kernel_launch(void* const* d_in, const int* in_sizes, int n_in,
                              void* d_out, int out_size, void* d_ws, size_t ws_size,
                              hipStream_t stream)
{
    const float* src       = (const float*)d_in[0];
    const float* tgt       = (const float*)d_in[1];
    const float* enc_in_w  = (const float*)d_in[2];
    const float* enc_in_b  = (const float*)d_in[3];
    const float* dec_in_w  = (const float*)d_in[4];
    const float* dec_in_b  = (const float*)d_in[5];
    const float* out_w     = (const float*)d_in[6];
    const float* out_b     = (const float*)d_in[7];
    const float* enc_attn_w = (const float*)d_in[8];
    const float* enc_attn_b = (const float*)d_in[9];
    const float* enc_out_w  = (const float*)d_in[10];
    const float* enc_out_b  = (const float*)d_in[11];
    const float* enc_ff1_w  = (const float*)d_in[12];
    const float* enc_ff1_b  = (const float*)d_in[13];
    const float* enc_ff2_w  = (const float*)d_in[14];
    const float* enc_ff2_b  = (const float*)d_in[15];
    const float* enc_ln1_g  = (const float*)d_in[16];
    const float* enc_ln1_b  = (const float*)d_in[17];
    const float* enc_ln2_g  = (const float*)d_in[18];
    const float* enc_ln2_b  = (const float*)d_in[19];
    const float* dec_sa_w     = (const float*)d_in[20];
    const float* dec_sa_b     = (const float*)d_in[21];
    const float* dec_sa_out_w = (const float*)d_in[22];
    const float* dec_sa_out_b = (const float*)d_in[23];
    const float* dec_ca_w     = (const float*)d_in[24];
    const float* dec_ca_b     = (const float*)d_in[25];
    const float* dec_ca_out_w = (const float*)d_in[26];
    const float* dec_ca_out_b = (const float*)d_in[27];
    const float* dec_ff1_w    = (const float*)d_in[28];
    const float* dec_ff1_b    = (const float*)d_in[29];
    const float* dec_ff2_w    = (const float*)d_in[30];
    const float* dec_ff2_b    = (const float*)d_in[31];
    const float* dec_ln1_g    = (const float*)d_in[32];
    const float* dec_ln1_b    = (const float*)d_in[33];
    const float* dec_ln2_g    = (const float*)d_in[34];
    const float* dec_ln2_b    = (const float*)d_in[35];
    const float* dec_ln3_g    = (const float*)d_in[36];
    const float* dec_ln3_b    = (const float*)d_in[37];

    // ---- workspace (bf16 / u16) ----
    u16* p = (u16*)d_ws;
    u16* xa   = p; p += (size_t)BB * SEQ * DM;
    u16* xb   = p; p += (size_t)BB * SEQ * DM;
    u16* reg1 = p; p += (size_t)BB * SEQ * FFD;       // qkv | ffb | (q + kv)
    u16* tbuf = p; p += (size_t)BB * SEQ * DM;
    u16* ya   = p; p += (size_t)BB * TGT * DM;
    u16* yb   = p; p += (size_t)BB * TGT * DM;
    u16* wb   = p;                                    // phase-shared weight region

    const float SQD = 22.627416997969522f;  // sqrt(512)
    const int ME = BB * SEQ;  // 2048
    const int MD = BB * TGT;  // 1024
    const int BH = BB * NH;   // 32

    const size_t SZ_ATTN = (size_t)NL * 3 * DM * DM;
    const size_t SZ_OUT  = (size_t)NL * DM * DM;
    const size_t SZ_FF1  = (size_t)NL * FFD * DM;
    const size_t SZ_FF2  = (size_t)NL * DM * FFD;

    // ===== phase E: cast encoder weights + src =====
    u16* q = wb;
    u16* src_b     = q; q += (size_t)BB * SEQ * HD;
    u16* enc_in_wb = q; q += (size_t)DM * HD;
    u16* enc_at_wb = q; q += SZ_ATTN;
    u16* enc_ow_wb = q; q += SZ_OUT;
    u16* enc_f1_wb = q; q += SZ_FF1;
    u16* enc_f2_wb = q; q += SZ_FF2;
    cast_t(src,        src_b,     (size_t)BB * SEQ * HD, stream);
    cast_t(enc_in_w,   enc_in_wb, (size_t)DM * HD,       stream);
    cast_t(enc_attn_w, enc_at_wb, SZ_ATTN,               stream);
    cast_t(enc_out_w,  enc_ow_wb, SZ_OUT,                stream);
    cast_t(enc_ff1_w,  enc_f1_wb, SZ_FF1,                stream);
    cast_t(enc_ff2_w,  enc_f2_wb, SZ_FF2,                stream);

    // ===== encoder =====
    mgemm_k<0, 0, 64><<<mg64(ME, DM), 256, 0, stream>>>(src_b, enc_in_wb, enc_in_b, nullptr, xa, ME, DM, HD, SQD);
    add_pe_enc<<<(ME * DM + 255) / 256, 256, 0, stream>>>(xa);

    u16* cur = xa; u16* alt = xb;
    for (int i = 0; i < NL; i++) {
        const u16* W = enc_at_wb + (size_t)i * 3 * DM * DM;
        const float* Bw = enc_attn_b + (size_t)i * 3 * DM;
        mgemm_k<0, 0, 64><<<mg64(ME, 3 * DM), 256, 0, stream>>>(cur, W, Bw, nullptr, reg1, ME, 3 * DM, DM, 1.f);
        flash_k<0><<<dim3(SEQ / 64, BH), 256, 0, stream>>>(reg1, 3 * DM, reg1 + DM, 3 * DM, reg1 + 2 * DM, 3 * DM, tbuf, SEQ, SEQ);
        mgemm_k<0, 0, 32><<<mg32(ME, DM), 256, 0, stream>>>(tbuf, enc_ow_wb + (size_t)i * DM * DM, enc_out_b + (size_t)i * DM, cur, alt, ME, DM, DM, 1.f);
        ln_k<<<ME, 256, 0, stream>>>(alt, enc_ln1_g + (size_t)i * DM, enc_ln1_b + (size_t)i * DM);
        { u16* t = cur; cur = alt; alt = t; }
        mgemm_k<1, 0, 64><<<mg64(ME, FFD), 256, 0, stream>>>(cur, enc_f1_wb + (size_t)i * FFD * DM, enc_ff1_b + (size_t)i * FFD, nullptr, reg1, ME, FFD, DM, 1.f);
        mgemm_k<0, 0, 32><<<mg32(ME, DM), 256, 0, stream>>>(reg1, enc_f2_wb + (size_t)i * DM * FFD, enc_ff2_b + (size_t)i * DM, cur, alt, ME, DM, FFD, 1.f);
        ln_k<<<ME, 256, 0, stream>>>(alt, enc_ln2_g + (size_t)i * DM, enc_ln2_b + (size_t)i * DM);
        { u16* t = cur; cur = alt; alt = t; }
    }
    u16* mem = cur;  // xa (even swaps) — outside wb region, survives phase D

    // ===== phase D: cast decoder weights + tgt (reuse wb region) =====
    q = wb;
    u16* tgt_b       = q; q += (size_t)BB * TGT * HD;
    u16* dec_in_wb   = q; q += (size_t)DM * HD;
    u16* out_wb      = q; q += (size_t)HD * DM;
    u16* dec_sa_wb   = q; q += SZ_ATTN;
    u16* dec_sao_wb  = q; q += SZ_OUT;
    u16* dec_ca_wb   = q; q += SZ_ATTN;
    u16* dec_cao_wb  = q; q += SZ_OUT;
    u16* dec_f1_wb   = q; q += SZ_FF1;
    u16* dec_f2_wb   = q; q += SZ_FF2;
    cast_t(tgt,          tgt_b,      (size_t)BB * TGT * HD, stream);
    cast_t(dec_in_w,     dec_in_wb,  (size_t)DM * HD,       stream);
    cast_t(out_w,        out_wb,     (size_t)HD * DM,       stream);
    cast_t(dec_sa_w,     dec_sa_wb,  SZ_ATTN,               stream);
    cast_t(dec_sa_out_w, dec_sao_wb, SZ_OUT,                stream);
    cast_t(dec_ca_w,     dec_ca_wb,  SZ_ATTN,               stream);
    cast_t(dec_ca_out_w, dec_cao_wb, SZ_OUT,                stream);
    cast_t(dec_ff1_w,    dec_f1_wb,  SZ_FF1,                stream);
    cast_t(dec_ff2_w,    dec_f2_wb,  SZ_FF2,                stream);

    // ===== decoder =====
    mgemm_k<0, 0, 32><<<mg32(MD, DM), 256, 0, stream>>>(tgt_b, dec_in_wb, dec_in_b, nullptr, ya, MD, DM, HD, SQD);
    add_pe_dec<<<(MD * DM + 255) / 256, 256, 0, stream>>>(ya, MD * DM);

    u16* dc = ya; u16* da = yb;
    for (int i = 0; i < NL; i++) {
        // --- self-attention (causal), fused QKV ---
        const u16* W = dec_sa_wb + (size_t)i * 3 * DM * DM;
        const float* Bw = dec_sa_b + (size_t)i * 3 * DM;
        mgemm_k<0, 0, 64><<<mg64(MD, 3 * DM), 256, 0, stream>>>(dc, W, Bw, nullptr, reg1, MD, 3 * DM, DM, 1.f);
        flash_k<1><<<dim3(TGT / 64, BH), 256, 0, stream>>>(reg1, 3 * DM, reg1 + DM, 3 * DM, reg1 + 2 * DM, 3 * DM, tbuf, TGT, TGT);
        mgemm_k<0, 0, 32><<<mg32(MD, DM), 256, 0, stream>>>(tbuf, dec_sao_wb + (size_t)i * DM * DM, dec_sa_out_b + (size_t)i * DM, dc, da, MD, DM, DM, 1.f);
        ln_k<<<MD, 256, 0, stream>>>(da, dec_ln1_g + (size_t)i * DM, dec_ln1_b + (size_t)i * DM);
        { u16* t = dc; dc = da; da = t; }

        // --- cross-attention ---
        const u16* Wc = dec_ca_wb + (size_t)i * 3 * DM * DM;
        const float* Bc = dec_ca_b + (size_t)i * 3 * DM;
        u16* qbuf = reg1;                        // [MD][512]
        u16* kvp  = reg1 + (size_t)MD * DM;      // [ME][1024]
        mgemm_k<0, 0, 32><<<mg32(MD, DM), 256, 0, stream>>>(dc, Wc, Bc, nullptr, qbuf, MD, DM, DM, 1.f);
        mgemm_k<0, 0, 64><<<mg64(ME, 2 * DM), 256, 0, stream>>>(mem, Wc + (size_t)DM * DM, Bc + DM, nullptr, kvp, ME, 2 * DM, DM, 1.f);
        flash_k<0><<<dim3(TGT / 64, BH), 256, 0, stream>>>(qbuf, DM, kvp, 2 * DM, kvp + DM, 2 * DM, tbuf, TGT, SEQ);
        mgemm_k<0, 0, 32><<<mg32(MD, DM), 256, 0, stream>>>(tbuf, dec_cao_wb + (size_t)i * DM * DM, dec_ca_out_b + (size_t)i * DM, dc, da, MD, DM, DM, 1.f);
        ln_k<<<MD, 256, 0, stream>>>(da, dec_ln2_g + (size_t)i * DM, dec_ln2_b + (size_t)i * DM);
        { u16* t = dc; dc = da; da = t; }

        // --- feed-forward ---
        mgemm_k<1, 0, 64><<<mg64(MD, FFD), 256, 0, stream>>>(dc, dec_f1_wb + (size_t)i * FFD * DM, dec_ff1_b + (size_t)i * FFD, nullptr, reg1, MD, FFD, DM, 1.f);
        mgemm_k<0, 0, 32><<<mg32(MD, DM), 256, 0, stream>>>(reg1, dec_f2_wb + (size_t)i * DM * FFD, dec_ff2_b + (size_t)i * DM, dc, da, MD, DM, FFD, 1.f);
        ln_k<<<MD, 256, 0, stream>>>(da, dec_ln3_g + (size_t)i * DM, dec_ln3_b + (size_t)i * DM);
        { u16* t = dc; dc = da; da = t; }
    }

    // ===== final projection (N=64, fp32 into d_out) =====
    mgemm_k<0, 1, 32><<<mg32(MD, HD), 256, 0, stream>>>(dc, out_wb, out_b, nullptr, (float*)d_out, MD, HD, DM, 1.f);
}

// Round 10
// 1276.354 us; speedup vs baseline: 15.3159x; 1.0327x over previous
//
#include <hip/hip_runtime.h>
#include <hip/hip_bf16.h>
#include <math.h>

#define BB 4
#define SEQ 512
#define TGT 256
#define DM 512
#define FFD 2048
#define NH 8
#define HD 64
#define NL 6

typedef unsigned short u16;
typedef __attribute__((ext_vector_type(4))) float f4;
typedef __attribute__((ext_vector_type(4))) unsigned short us4;
typedef __attribute__((ext_vector_type(8))) unsigned short us8;
typedef __attribute__((ext_vector_type(8))) short s8;

__device__ inline u16 f2b(float f) {
    __hip_bfloat16 h = __float2bfloat16(f);
    return *reinterpret_cast<u16*>(&h);
}
__device__ inline float b2f(u16 u) {
    unsigned int x = ((unsigned int)u) << 16;
    float f;
    __builtin_memcpy(&f, &x, 4);
    return f;
}
__device__ inline us4 cvt4(f4 v) {
    us4 u;
    u.x = f2b(v.x); u.y = f2b(v.y); u.z = f2b(v.z); u.w = f2b(v.w);
    return u;
}

// ---------------- batched fp32 -> bf16 cast, up to 24 segments ----------------
struct CastSegs {
    const float* src[24];
    u16* dst[24];
    int cum[25];   // cumulative n4
    int nseg;
};

__global__ __launch_bounds__(256) void castseg_k(CastSegs cs)
{
    int i = blockIdx.x * blockDim.x + threadIdx.x;
    if (i >= cs.cum[cs.nseg]) return;
    int s = 0;
    while (i >= cs.cum[s + 1]) s++;
    int local = i - cs.cum[s];
    ((us4*)cs.dst[s])[local] = cvt4(((const f4*)cs.src[s])[local]);
}

// ---------------- stack decoder cross-attn KV biases: [6][1024] fp32 ----------------
__global__ void kvbias_k(const float* __restrict__ dec_ca_b, float* __restrict__ out)
{
    int idx = blockIdx.x * blockDim.x + threadIdx.x;
    if (idx >= NL * 2 * DM) return;
    int layer = idx >> 10, j = idx & 1023;
    out[idx] = dec_ca_b[layer * 3 * DM + DM + j];
}

// ============ MFMA GEMM, bf16, BMx64 tile, BK=64, double-buffered LDS ============
// PE: 0 none, 1 add encoder sinusoidal pe(m&511, n), 2 add decoder pe row 0 (odd n +1)
template <int RELU, int OUTF32, int BM, int PE>
__global__ __launch_bounds__(256) void mgemm_k(
    const u16* __restrict__ A, const u16* __restrict__ W,
    const float* __restrict__ bias, const u16* __restrict__ resid,
    void* __restrict__ Cv, int M, int N, int K, float alpha)
{
    constexpr int MI = BM / 32;
    __shared__ u16 As[2][BM][72];
    __shared__ u16 Bs[2][64][72];
    const int bm = blockIdx.y * BM, bn = blockIdx.x * 64;
    const int tid = threadIdx.x;
    const int wave = tid >> 6, lane = tid & 63;
    const int wr = (wave >> 1) * (BM / 2), wc = (wave & 1) * 32;
    const int lm = lane & 15, quad = lane >> 4;
    const int sbr = tid >> 2, sbc = (tid & 3) * 16;
    const int sar = (BM == 64) ? (tid >> 2) : (tid >> 3);
    const int sac = (BM == 64) ? ((tid & 3) * 16) : ((tid & 7) * 8);

    const u16* Arow = A + (size_t)(bm + sar) * K + sac;
    const u16* Wrow = W + (size_t)(bn + sbr) * K + sbc;

    us8 a0 = *(const us8*)(Arow);
    us8 a1;
    if (BM == 64) a1 = *(const us8*)(Arow + 8);
    us8 b0 = *(const us8*)(Wrow);
    us8 b1 = *(const us8*)(Wrow + 8);

    f4 acc[MI][2];
#pragma unroll
    for (int i = 0; i < MI; i++)
#pragma unroll
        for (int j = 0; j < 2; j++) acc[i][j] = (f4)(0.f);

    const int nk = K >> 6;
    *(us8*)&As[0][sar][sac] = a0;
    if (BM == 64) *(us8*)&As[0][sar][sac + 8] = a1;
    *(us8*)&Bs[0][sbr][sbc] = b0;
    *(us8*)&Bs[0][sbr][sbc + 8] = b1;
    __syncthreads();

    for (int t = 0; t < nk; t++) {
        const int cb = t & 1;
        if (t + 1 < nk) {
            int off = (t + 1) << 6;
            a0 = *(const us8*)(Arow + off);
            if (BM == 64) a1 = *(const us8*)(Arow + off + 8);
            b0 = *(const us8*)(Wrow + off);
            b1 = *(const us8*)(Wrow + off + 8);
        }
#pragma unroll
        for (int ks = 0; ks < 2; ks++) {
            s8 af[MI], bfr[2];
#pragma unroll
            for (int i = 0; i < MI; i++) af[i] = *(const s8*)&As[cb][wr + i * 16 + lm][ks * 32 + quad * 8];
#pragma unroll
            for (int j = 0; j < 2; j++) bfr[j] = *(const s8*)&Bs[cb][wc + j * 16 + lm][ks * 32 + quad * 8];
#pragma unroll
            for (int i = 0; i < MI; i++)
#pragma unroll
                for (int j = 0; j < 2; j++)
                    acc[i][j] = __builtin_amdgcn_mfma_f32_16x16x32_bf16(af[i], bfr[j], acc[i][j], 0, 0, 0);
        }
        if (t + 1 < nk) {
            const int nb = cb ^ 1;
            *(us8*)&As[nb][sar][sac] = a0;
            if (BM == 64) *(us8*)&As[nb][sar][sac + 8] = a1;
            *(us8*)&Bs[nb][sbr][sbc] = b0;
            *(us8*)&Bs[nb][sbr][sbc + 8] = b1;
            __syncthreads();
        }
    }

#pragma unroll
    for (int j = 0; j < 2; j++) {
        int n = bn + wc + j * 16 + lm;
        float bv = bias[n];
        float dv = 0.f;
        if (PE == 1) dv = expf((float)(n & ~1) * (-9.210340371976184f / (float)DM));
#pragma unroll
        for (int i = 0; i < MI; i++) {
#pragma unroll
            for (int r = 0; r < 4; r++) {
                int m = bm + wr + i * 16 + quad * 4 + r;
                float v = (acc[i][j][r] + bv) * alpha;
                if (PE == 1) {
                    float ang = (float)(m & (SEQ - 1)) * dv;
                    v += (n & 1) ? cosf(ang) : sinf(ang);
                }
                if (PE == 2) { if (n & 1) v += 1.f; }
                if (RELU) v = fmaxf(v, 0.f);
                size_t off = (size_t)m * N + n;
                if (resid) v += b2f(resid[off]);
                if (OUTF32) ((float*)Cv)[off] = v;
                else        ((u16*)Cv)[off]  = f2b(v);
            }
        }
    }
}

// ============ Fused flash attention (verified R8 structure) ============
template <int CAUSAL>
__global__ __launch_bounds__(256) void flash_k(
    const u16* __restrict__ Q, int qs,
    const u16* __restrict__ Kp, int ks,
    const u16* __restrict__ V, int vs,
    u16* __restrict__ O, int Sq, int Sk)
{
    __shared__ u16 Qs[64][72];
    __shared__ u16 Ks[128][72];
    __shared__ u16 Vs[64][136];
    __shared__ u16 Ps[4][16][136];
    const int bm = blockIdx.x * 64;
    const int bh = blockIdx.y, b = bh >> 3, h = bh & 7;
    const int tid = threadIdx.x;
    const int wave = tid >> 6, lane = tid & 63;
    const int lm = lane & 15, quad = lane >> 4;

    const u16* Qb = Q + (size_t)(b * Sq + bm) * qs + h * HD;
    {
        int r = tid >> 2, c = (tid & 3) * 16;
        *(us8*)&Qs[r][c]     = *(const us8*)(Qb + (size_t)r * qs + c);
        *(us8*)&Qs[r][c + 8] = *(const us8*)(Qb + (size_t)r * qs + c + 8);
    }

    float mrow[4], lrow[4];
    f4 o[4];
#pragma unroll
    for (int r = 0; r < 4; r++) { mrow[r] = -1e30f; lrow[r] = 0.f; }
#pragma unroll
    for (int nt = 0; nt < 4; nt++) o[nt] = (f4)(0.f);

    const u16* Kb = Kp + (size_t)(b * Sk) * ks + h * HD;
    const u16* Vb = V + (size_t)(b * Sk) * vs + h * HD;
    int nkt = Sk >> 7;
    if (CAUSAL) { int lim = (bm + 63) / 128 + 1; if (lim < nkt) nkt = lim; }

    const int vd = tid & 63, vkb = tid >> 6;
    const int kr = tid >> 3, kc8 = (tid & 7) * 8;

    for (int kt = 0; kt < nkt; kt++) {
        const u16* Kt = Kb + ((size_t)kt << 7) * ks;
        const u16* Vt = Vb + ((size_t)kt << 7) * vs;
#pragma unroll
        for (int p = 0; p < 4; p++) {
            int r = p * 32 + kr;
            *(us8*)&Ks[r][kc8] = *(const us8*)(Kt + (size_t)r * ks + kc8);
        }
#pragma unroll
        for (int p = 0; p < 32; p++) {
            int kv = p * 4 + vkb;
            Vs[vd][kv] = Vt[(size_t)kv * vs + vd];
        }
        __syncthreads();

        f4 sa[8];
#pragma unroll
        for (int nt = 0; nt < 8; nt++) sa[nt] = (f4)(0.f);
#pragma unroll
        for (int ks2 = 0; ks2 < 2; ks2++) {
            s8 aq = *(const s8*)&Qs[wave * 16 + lm][ks2 * 32 + quad * 8];
#pragma unroll
            for (int nt = 0; nt < 8; nt++) {
                s8 bk = *(const s8*)&Ks[nt * 16 + lm][ks2 * 32 + quad * 8];
                sa[nt] = __builtin_amdgcn_mfma_f32_16x16x32_bf16(aq, bk, sa[nt], 0, 0, 0);
            }
        }
        float tmx[4] = {-1e30f, -1e30f, -1e30f, -1e30f};
#pragma unroll
        for (int nt = 0; nt < 8; nt++) {
#pragma unroll
            for (int r = 0; r < 4; r++) {
                float v = sa[nt][r] * 0.125f;
                if (CAUSAL) {
                    int col = (kt << 7) + nt * 16 + lm;
                    int row = bm + wave * 16 + quad * 4 + r;
                    if (col > row) v = -1e30f;
                }
                sa[nt][r] = v;
                tmx[r] = fmaxf(tmx[r], v);
            }
        }
#pragma unroll
        for (int st = 1; st < 16; st <<= 1)
#pragma unroll
            for (int r = 0; r < 4; r++) tmx[r] = fmaxf(tmx[r], __shfl_xor(tmx[r], st));
        float al[4];
#pragma unroll
        for (int r = 0; r < 4; r++) {
            float mn = fmaxf(mrow[r], tmx[r]);
            al[r] = __expf(mrow[r] - mn);
            mrow[r] = mn;
        }
        float ts[4] = {0.f, 0.f, 0.f, 0.f};
#pragma unroll
        for (int nt = 0; nt < 8; nt++) {
#pragma unroll
            for (int r = 0; r < 4; r++) {
                float pe = __expf(sa[nt][r] - mrow[r]);
                sa[nt][r] = pe;
                ts[r] += pe;
            }
        }
#pragma unroll
        for (int st = 1; st < 16; st <<= 1)
#pragma unroll
            for (int r = 0; r < 4; r++) ts[r] += __shfl_xor(ts[r], st);
#pragma unroll
        for (int r = 0; r < 4; r++) lrow[r] = lrow[r] * al[r] + ts[r];
#pragma unroll
        for (int nt = 0; nt < 4; nt++)
#pragma unroll
            for (int r = 0; r < 4; r++) o[nt][r] *= al[r];
#pragma unroll
        for (int nt = 0; nt < 8; nt++)
#pragma unroll
            for (int r = 0; r < 4; r++)
                Ps[wave][quad * 4 + r][nt * 16 + lm] = f2b(sa[nt][r]);
#pragma unroll
        for (int kc = 0; kc < 4; kc++) {
            s8 ap = *(const s8*)&Ps[wave][lm][kc * 32 + quad * 8];
#pragma unroll
            for (int nt = 0; nt < 4; nt++) {
                s8 bv = *(const s8*)&Vs[nt * 16 + lm][kc * 32 + quad * 8];
                o[nt] = __builtin_amdgcn_mfma_f32_16x16x32_bf16(ap, bv, o[nt], 0, 0, 0);
            }
        }
        __syncthreads();
    }

    float inv[4];
#pragma unroll
    for (int r = 0; r < 4; r++) inv[r] = 1.f / lrow[r];
#pragma unroll
    for (int nt = 0; nt < 4; nt++) {
#pragma unroll
        for (int r = 0; r < 4; r++) {
            int m = bm + wave * 16 + quad * 4 + r;
            O[(size_t)(b * Sq + m) * DM + h * HD + nt * 16 + lm] = f2b(o[nt][r] * inv[r]);
        }
    }
}

// ---------------- layernorm (bf16 row of 512, fp32 math) ----------------
__global__ __launch_bounds__(256) void ln_k(u16* __restrict__ x,
                                            const float* __restrict__ g,
                                            const float* __restrict__ b)
{
    int row = blockIdx.x;
    u16* xr = x + (size_t)row * DM;
    int tid = threadIdx.x;
    float v0 = b2f(xr[tid]), v1 = b2f(xr[tid + 256]);
    __shared__ float red[256];
    red[tid] = v0 + v1;
    __syncthreads();
    for (int st = 128; st > 0; st >>= 1) {
        if (tid < st) red[tid] += red[tid + st];
        __syncthreads();
    }
    float mean = red[0] * (1.f / DM);
    __syncthreads();
    float d0 = v0 - mean, d1 = v1 - mean;
    red[tid] = d0 * d0 + d1 * d1;
    __syncthreads();
    for (int st = 128; st > 0; st >>= 1) {
        if (tid < st) red[tid] += red[tid + st];
        __syncthreads();
    }
    float rstd = rsqrtf(red[0] * (1.f / DM) + 1e-5f);
    xr[tid]       = f2b(d0 * rstd * g[tid]       + b[tid]);
    xr[tid + 256] = f2b(d1 * rstd * g[tid + 256] + b[tid + 256]);
}

// ---------------- host orchestration ----------------
static inline dim3 mg64(int M, int N) { return dim3(N / 64, M / 64); }
static inline dim3 mg32(int M, int N) { return dim3(N / 64, M / 32); }

extern "C" void kernel_launch(void* const* d_in, const int* in_sizes, int n_in,
                              void* d_out, int out_size, void* d_ws, size_t ws_size,
                              hipStream_t stream)
{
    const float* src       = (const float*)d_in[0];
    const float* tgt       = (const float*)d_in[1];
    const float* enc_in_w  = (const float*)d_in[2];
    const float* enc_in_b  = (const float*)d_in[3];
    const float* dec_in_w  = (const float*)d_in[4];
    const float* dec_in_b  = (const float*)d_in[5];
    const float* out_w     = (const float*)d_in[6];
    const float* out_b     = (const float*)d_in[7];
    const float* enc_attn_w = (const float*)d_in[8];
    const float* enc_attn_b = (const float*)d_in[9];
    const float* enc_out_w  = (const float*)d_in[10];
    const float* enc_out_b  = (const float*)d_in[11];
    const float* enc_ff1_w  = (const float*)d_in[12];
    const float* enc_ff1_b  = (const float*)d_in[13];
    const float* enc_ff2_w  = (const float*)d_in[14];
    const float* enc_ff2_b  = (const float*)d_in[15];
    const float* enc_ln1_g  = (const float*)d_in[16];
    const float* enc_ln1_b  = (const float*)d_in[17];
    const float* enc_ln2_g  = (const float*)d_in[18];
    const float* enc_ln2_b  = (const float*)d_in[19];
    const float* dec_sa_w     = (const float*)d_in[20];
    const float* dec_sa_b     = (const float*)d_in[21];
    const float* dec_sa_out_w = (const float*)d_in[22];
    const float* dec_sa_out_b = (const float*)d_in[23];
    const float* dec_ca_w     = (const float*)d_in[24];
    const float* dec_ca_b     = (const float*)d_in[25];
    const float* dec_ca_out_w = (const float*)d_in[26];
    const float* dec_ca_out_b = (const float*)d_in[27];
    const float* dec_ff1_w    = (const float*)d_in[28];
    const float* dec_ff1_b    = (const float*)d_in[29];
    const float* dec_ff2_w    = (const float*)d_in[30];
    const float* dec_ff2_b    = (const float*)d_in[31];
    const float* dec_ln1_g    = (const float*)d_in[32];
    const float* dec_ln1_b    = (const float*)d_in[33];
    const float* dec_ln2_g    = (const float*)d_in[34];
    const float* dec_ln2_b    = (const float*)d_in[35];
    const float* dec_ln3_g    = (const float*)d_in[36];
    const float* dec_ln3_b    = (const float*)d_in[37];

    const int ME = BB * SEQ;  // 2048
    const int MD = BB * TGT;  // 1024
    const int BH = BB * NH;   // 32
    const float SQD = 22.627416997969522f;  // sqrt(512)

    const size_t SZ_ATTN = (size_t)NL * 3 * DM * DM;
    const size_t SZ_OUT  = (size_t)NL * DM * DM;
    const size_t SZ_FF   = (size_t)NL * FFD * DM;

    // ---- workspace layout (u16 units; fp32 sections first for alignment) ----
    float* fp = (float*)d_ws;
    float* kvbias = fp; fp += NL * 2 * DM;            // 6144 fp32
    u16* p = (u16*)fp;
    u16* xa   = p; p += (size_t)ME * DM;
    u16* xb   = p; p += (size_t)ME * DM;
    u16* reg1 = p; p += (size_t)ME * FFD;             // qkv | ffb | q
    u16* tbuf = p; p += (size_t)ME * DM;
    u16* ya   = p; p += (size_t)MD * DM;
    u16* yb   = p; p += (size_t)MD * DM;
    u16* kvall = p; p += (size_t)ME * NL * 2 * DM;    // [2048][6144]
    u16* src_b     = p; p += (size_t)ME * HD;
    u16* tgt_b     = p; p += (size_t)MD * HD;
    u16* enc_in_wb = p; p += (size_t)DM * HD;
    u16* dec_in_wb = p; p += (size_t)DM * HD;
    u16* out_wb    = p; p += (size_t)HD * DM;
    u16* enc_at_wb = p; p += SZ_ATTN;
    u16* enc_ow_wb = p; p += SZ_OUT;
    u16* enc_f1_wb = p; p += SZ_FF;
    u16* enc_f2_wb = p; p += SZ_FF;
    u16* dec_sa_wb = p; p += SZ_ATTN;
    u16* dec_sao_wb = p; p += SZ_OUT;
    u16* dec_ca_wb = p; p += SZ_ATTN;
    u16* dec_cao_wb = p; p += SZ_OUT;
    u16* dec_f1_wb = p; p += SZ_FF;
    u16* dec_f2_wb = p; p += SZ_FF;
    u16* kvstack   = p; p += (size_t)NL * 2 * DM * DM;  // [6144][512]

    // ===== single batched cast (21 segments) =====
    CastSegs cs;
    int ns = 0;
    auto seg = [&](const float* s, u16* d, size_t n) {
        cs.src[ns] = s; cs.dst[ns] = d;
        cs.cum[ns + 1] = cs.cum[ns] + (int)(n / 4);
        ns++;
    };
    cs.cum[0] = 0;
    seg(src,          src_b,     (size_t)ME * HD);
    seg(tgt,          tgt_b,     (size_t)MD * HD);
    seg(enc_in_w,     enc_in_wb, (size_t)DM * HD);
    seg(dec_in_w,     dec_in_wb, (size_t)DM * HD);
    seg(out_w,        out_wb,    (size_t)HD * DM);
    seg(enc_attn_w,   enc_at_wb, SZ_ATTN);
    seg(enc_out_w,    enc_ow_wb, SZ_OUT);
    seg(enc_ff1_w,    enc_f1_wb, SZ_FF);
    seg(enc_ff2_w,    enc_f2_wb, SZ_FF);
    seg(dec_sa_w,     dec_sa_wb, SZ_ATTN);
    seg(dec_sa_out_w, dec_sao_wb, SZ_OUT);
    seg(dec_ca_w,     dec_ca_wb, SZ_ATTN);
    seg(dec_ca_out_w, dec_cao_wb, SZ_OUT);
    seg(dec_ff1_w,    dec_f1_wb, SZ_FF);
    seg(dec_ff2_w,    dec_f2_wb, SZ_FF);
    for (int i = 0; i < NL; i++)  // gather KV weight rows into stacked [6144][512]
        seg(dec_ca_w + (size_t)i * 3 * DM * DM + (size_t)DM * DM,
            kvstack + (size_t)i * 2 * DM * DM, (size_t)2 * DM * DM);
    cs.nseg = ns;
    castseg_k<<<(cs.cum[ns] + 255) / 256, 256, 0, stream>>>(cs);
    kvbias_k<<<(NL * 2 * DM + 255) / 256, 256, 0, stream>>>(dec_ca_b, kvbias);

    // ===== encoder =====
    mgemm_k<0, 0, 64, 1><<<mg64(ME, DM), 256, 0, stream>>>(src_b, enc_in_wb, enc_in_b, nullptr, xa, ME, DM, HD, SQD);

    u16* cur = xa; u16* alt = xb;
    for (int i = 0; i < NL; i++) {
        const u16* W = enc_at_wb + (size_t)i * 3 * DM * DM;
        const float* Bw = enc_attn_b + (size_t)i * 3 * DM;
        mgemm_k<0, 0, 64, 0><<<mg64(ME, 3 * DM), 256, 0, stream>>>(cur, W, Bw, nullptr, reg1, ME, 3 * DM, DM, 1.f);
        flash_k<0><<<dim3(SEQ / 64, BH), 256, 0, stream>>>(reg1, 3 * DM, reg1 + DM, 3 * DM, reg1 + 2 * DM, 3 * DM, tbuf, SEQ, SEQ);
        mgemm_k<0, 0, 32, 0><<<mg32(ME, DM), 256, 0, stream>>>(tbuf, enc_ow_wb + (size_t)i * DM * DM, enc_out_b + (size_t)i * DM, cur, alt, ME, DM, DM, 1.f);
        ln_k<<<ME, 256, 0, stream>>>(alt, enc_ln1_g + (size_t)i * DM, enc_ln1_b + (size_t)i * DM);
        { u16* t = cur; cur = alt; alt = t; }
        mgemm_k<1, 0, 64, 0><<<mg64(ME, FFD), 256, 0, stream>>>(cur, enc_f1_wb + (size_t)i * FFD * DM, enc_ff1_b + (size_t)i * FFD, nullptr, reg1, ME, FFD, DM, 1.f);
        mgemm_k<0, 0, 32, 0><<<mg32(ME, DM), 256, 0, stream>>>(reg1, enc_f2_wb + (size_t)i * DM * FFD, enc_ff2_b + (size_t)i * DM, cur, alt, ME, DM, FFD, 1.f);
        ln_k<<<ME, 256, 0, stream>>>(alt, enc_ln2_g + (size_t)i * DM, enc_ln2_b + (size_t)i * DM);
        { u16* t = cur; cur = alt; alt = t; }
    }
    u16* mem = cur;  // xa (even swaps)

    // ===== all 6 layers' cross-attn K/V projections in one GEMM =====
    // kvall[row][i*1024 + c] ; layer i: K at +0, V at +512, row stride 6144
    mgemm_k<0, 0, 64, 0><<<mg64(ME, NL * 2 * DM), 256, 0, stream>>>(mem, kvstack, kvbias, nullptr, kvall, ME, NL * 2 * DM, DM, 1.f);

    // ===== decoder =====
    mgemm_k<0, 0, 32, 2><<<mg32(MD, DM), 256, 0, stream>>>(tgt_b, dec_in_wb, dec_in_b, nullptr, ya, MD, DM, HD, SQD);

    u16* dc = ya; u16* da = yb;
    for (int i = 0; i < NL; i++) {
        // --- self-attention (causal), fused QKV ---
        const u16* W = dec_sa_wb + (size_t)i * 3 * DM * DM;
        const float* Bw = dec_sa_b + (size_t)i * 3 * DM;
        mgemm_k<0, 0, 64, 0><<<mg64(MD, 3 * DM), 256, 0, stream>>>(dc, W, Bw, nullptr, reg1, MD, 3 * DM, DM, 1.f);
        flash_k<1><<<dim3(TGT / 64, BH), 256, 0, stream>>>(reg1, 3 * DM, reg1 + DM, 3 * DM, reg1 + 2 * DM, 3 * DM, tbuf, TGT, TGT);
        mgemm_k<0, 0, 32, 0><<<mg32(MD, DM), 256, 0, stream>>>(tbuf, dec_sao_wb + (size_t)i * DM * DM, dec_sa_out_b + (size_t)i * DM, dc, da, MD, DM, DM, 1.f);
        ln_k<<<MD, 256, 0, stream>>>(da, dec_ln1_g + (size_t)i * DM, dec_ln1_b + (size_t)i * DM);
        { u16* t = dc; dc = da; da = t; }

        // --- cross-attention (K/V precomputed in kvall) ---
        const u16* Wc = dec_ca_wb + (size_t)i * 3 * DM * DM;
        const float* Bc = dec_ca_b + (size_t)i * 3 * DM;
        u16* qbuf = reg1;
        mgemm_k<0, 0, 32, 0><<<mg32(MD, DM), 256, 0, stream>>>(dc, Wc, Bc, nullptr, qbuf, MD, DM, DM, 1.f);
        const u16* kvl = kvall + (size_t)i * 2 * DM;
        flash_k<0><<<dim3(TGT / 64, BH), 256, 0, stream>>>(qbuf, DM, kvl, NL * 2 * DM, kvl + DM, NL * 2 * DM, tbuf, TGT, SEQ);
        mgemm_k<0, 0, 32, 0><<<mg32(MD, DM), 256, 0, stream>>>(tbuf, dec_cao_wb + (size_t)i * DM * DM, dec_ca_out_b + (size_t)i * DM, dc, da, MD, DM, DM, 1.f);
        ln_k<<<MD, 256, 0, stream>>>(da, dec_ln2_g + (size_t)i * DM, dec_ln2_b + (size_t)i * DM);
        { u16* t = dc; dc = da; da = t; }

        // --- feed-forward ---
        mgemm_k<1, 0, 64, 0><<<mg64(MD, FFD), 256, 0, stream>>>(dc, dec_f1_wb + (size_t)i * FFD * DM, dec_ff1_b + (size_t)i * FFD, nullptr, reg1, MD, FFD, DM, 1.f);
        mgemm_k<0, 0, 32, 0><<<mg32(MD, DM), 256, 0, stream>>>(reg1, dec_f2_wb + (size_t)i * DM * FFD, dec_ff2_b + (size_t)i * DM, dc, da, MD, DM, FFD, 1.f);
        ln_k<<<MD, 256, 0, stream>>>(da, dec_ln3_g + (size_t)i * DM, dec_ln3_b + (size_t)i * DM);
        { u16* t = dc; dc = da; da = t; }
    }

    // ===== final projection (N=64, fp32 into d_out) =====
    mgemm_k<0, 1, 32, 0><<<mg32(MD, HD), 256, 0, stream>>>(dc, out_wb, out_b, nullptr, (float*)d_out, MD, HD, DM, 1.f);
}

// Round 11
// 1259.283 us; speedup vs baseline: 15.5235x; 1.0136x over previous
//
#include <hip/hip_runtime.h>
#include <hip/hip_bf16.h>
#include <math.h>

#define BB 4
#define SEQ 512
#define TGT 256
#define DM 512
#define FFD 2048
#define NH 8
#define HD 64
#define NL 6

typedef unsigned short u16;
typedef __attribute__((ext_vector_type(4))) float f4;
typedef __attribute__((ext_vector_type(4))) unsigned short us4;
typedef __attribute__((ext_vector_type(8))) unsigned short us8;
typedef __attribute__((ext_vector_type(8))) short s8;

__device__ inline u16 f2b(float f) {
    __hip_bfloat16 h = __float2bfloat16(f);
    return *reinterpret_cast<u16*>(&h);
}
__device__ inline float b2f(u16 u) {
    unsigned int x = ((unsigned int)u) << 16;
    float f;
    __builtin_memcpy(&f, &x, 4);
    return f;
}
__device__ inline us4 cvt4(f4 v) {
    us4 u;
    u.x = f2b(v.x); u.y = f2b(v.y); u.z = f2b(v.z); u.w = f2b(v.w);
    return u;
}

// ---------------- batched fp32 -> bf16 cast, 8 elems/thread ----------------
struct CastSegs {
    const float* src[24];
    u16* dst[24];
    int cum[25];   // cumulative n8 (groups of 8 elements)
    int nseg;
};

__global__ __launch_bounds__(256) void castseg_k(CastSegs cs)
{
    int i = blockIdx.x * blockDim.x + threadIdx.x;
    if (i >= cs.cum[cs.nseg]) return;
    int s = 0;
    while (i >= cs.cum[s + 1]) s++;
    int local = i - cs.cum[s];
    const f4* sp = (const f4*)cs.src[s] + (size_t)local * 2;
    f4 lo = sp[0], hi = sp[1];
    us4 ul = cvt4(lo), uh = cvt4(hi);
    us8 o;
#pragma unroll
    for (int e = 0; e < 4; e++) { o[e] = ul[e]; o[e + 4] = uh[e]; }
    ((us8*)cs.dst[s])[local] = o;
}

// ---------------- stack decoder cross-attn KV biases: [6][1024] fp32 ----------------
__global__ void kvbias_k(const float* __restrict__ dec_ca_b, float* __restrict__ out)
{
    int idx = blockIdx.x * blockDim.x + threadIdx.x;
    if (idx >= NL * 2 * DM) return;
    int layer = idx >> 10, j = idx & 1023;
    out[idx] = dec_ca_b[layer * 3 * DM + DM + j];
}

// ============ MFMA GEMM, bf16, BMx64 tile, BK=64, double-buffered LDS ============
// PE: 0 none, 1 encoder sinusoidal pe, 2 decoder pe row 0
template <int RELU, int OUTF32, int BM, int PE>
__global__ __launch_bounds__(256) void mgemm_k(
    const u16* __restrict__ A, const u16* __restrict__ W,
    const float* __restrict__ bias, const u16* __restrict__ resid,
    void* __restrict__ Cv, int M, int N, int K, float alpha)
{
    constexpr int MI = BM / 32;
    __shared__ u16 As[2][BM][72];
    __shared__ u16 Bs[2][64][72];
    const int bm = blockIdx.y * BM, bn = blockIdx.x * 64;
    const int tid = threadIdx.x;
    const int wave = tid >> 6, lane = tid & 63;
    const int wr = (wave >> 1) * (BM / 2), wc = (wave & 1) * 32;
    const int lm = lane & 15, quad = lane >> 4;
    const int sbr = tid >> 2, sbc = (tid & 3) * 16;
    const int sar = (BM == 64) ? (tid >> 2) : (tid >> 3);
    const int sac = (BM == 64) ? ((tid & 3) * 16) : ((tid & 7) * 8);

    const u16* Arow = A + (size_t)(bm + sar) * K + sac;
    const u16* Wrow = W + (size_t)(bn + sbr) * K + sbc;

    us8 a0 = *(const us8*)(Arow);
    us8 a1;
    if (BM == 64) a1 = *(const us8*)(Arow + 8);
    us8 b0 = *(const us8*)(Wrow);
    us8 b1 = *(const us8*)(Wrow + 8);

    f4 acc[MI][2];
#pragma unroll
    for (int i = 0; i < MI; i++)
#pragma unroll
        for (int j = 0; j < 2; j++) acc[i][j] = (f4)(0.f);

    const int nk = K >> 6;
    *(us8*)&As[0][sar][sac] = a0;
    if (BM == 64) *(us8*)&As[0][sar][sac + 8] = a1;
    *(us8*)&Bs[0][sbr][sbc] = b0;
    *(us8*)&Bs[0][sbr][sbc + 8] = b1;
    __syncthreads();

    for (int t = 0; t < nk; t++) {
        const int cb = t & 1;
        if (t + 1 < nk) {
            int off = (t + 1) << 6;
            a0 = *(const us8*)(Arow + off);
            if (BM == 64) a1 = *(const us8*)(Arow + off + 8);
            b0 = *(const us8*)(Wrow + off);
            b1 = *(const us8*)(Wrow + off + 8);
        }
#pragma unroll
        for (int ks = 0; ks < 2; ks++) {
            s8 af[MI], bfr[2];
#pragma unroll
            for (int i = 0; i < MI; i++) af[i] = *(const s8*)&As[cb][wr + i * 16 + lm][ks * 32 + quad * 8];
#pragma unroll
            for (int j = 0; j < 2; j++) bfr[j] = *(const s8*)&Bs[cb][wc + j * 16 + lm][ks * 32 + quad * 8];
#pragma unroll
            for (int i = 0; i < MI; i++)
#pragma unroll
                for (int j = 0; j < 2; j++)
                    acc[i][j] = __builtin_amdgcn_mfma_f32_16x16x32_bf16(af[i], bfr[j], acc[i][j], 0, 0, 0);
        }
        if (t + 1 < nk) {
            const int nb = cb ^ 1;
            *(us8*)&As[nb][sar][sac] = a0;
            if (BM == 64) *(us8*)&As[nb][sar][sac + 8] = a1;
            *(us8*)&Bs[nb][sbr][sbc] = b0;
            *(us8*)&Bs[nb][sbr][sbc + 8] = b1;
            __syncthreads();
        }
    }

#pragma unroll
    for (int j = 0; j < 2; j++) {
        int n = bn + wc + j * 16 + lm;
        float bv = bias[n];
        float dv = 0.f;
        if (PE == 1) dv = expf((float)(n & ~1) * (-9.210340371976184f / (float)DM));
#pragma unroll
        for (int i = 0; i < MI; i++) {
#pragma unroll
            for (int r = 0; r < 4; r++) {
                int m = bm + wr + i * 16 + quad * 4 + r;
                float v = (acc[i][j][r] + bv) * alpha;
                if (PE == 1) {
                    float ang = (float)(m & (SEQ - 1)) * dv;
                    v += (n & 1) ? cosf(ang) : sinf(ang);
                }
                if (PE == 2) { if (n & 1) v += 1.f; }
                if (RELU) v = fmaxf(v, 0.f);
                size_t off = (size_t)m * N + n;
                if (resid) v += b2f(resid[off]);
                if (OUTF32) ((float*)Cv)[off] = v;
                else        ((u16*)Cv)[off]  = f2b(v);
            }
        }
    }
}

// ============ MFMA GEMM, 64x128 tile, BK=64, dbuf — for N%128==0 GEMMs ============
// 16 MFMA per barrier. C bf16 = relu?(A @ W^T + bias). No resid/alpha/PE.
template <int RELU>
__global__ __launch_bounds__(256) void mgemm128_k(
    const u16* __restrict__ A, const u16* __restrict__ W,
    const float* __restrict__ bias, u16* __restrict__ C,
    int M, int N, int K)
{
    __shared__ u16 As[2][64][72];
    __shared__ u16 Bs[2][128][72];
    const int bm = blockIdx.y * 64, bn = blockIdx.x * 128;
    const int tid = threadIdx.x;
    const int wave = tid >> 6, lane = tid & 63;
    const int wr = (wave >> 1) * 32, wc = (wave & 1) * 64;
    const int lm = lane & 15, quad = lane >> 4;
    const int sar = tid >> 2, sac = (tid & 3) * 16;
    const int sbr = tid >> 1, sbc = (tid & 1) * 32;

    const u16* Arow = A + (size_t)(bm + sar) * K + sac;
    const u16* Wrow = W + (size_t)(bn + sbr) * K + sbc;

    us8 a0 = *(const us8*)(Arow);
    us8 a1 = *(const us8*)(Arow + 8);
    us8 b0 = *(const us8*)(Wrow);
    us8 b1 = *(const us8*)(Wrow + 8);
    us8 b2 = *(const us8*)(Wrow + 16);
    us8 b3 = *(const us8*)(Wrow + 24);

    f4 acc[2][4];
#pragma unroll
    for (int i = 0; i < 2; i++)
#pragma unroll
        for (int j = 0; j < 4; j++) acc[i][j] = (f4)(0.f);

    const int nk = K >> 6;
    *(us8*)&As[0][sar][sac]     = a0;
    *(us8*)&As[0][sar][sac + 8] = a1;
    *(us8*)&Bs[0][sbr][sbc]      = b0;
    *(us8*)&Bs[0][sbr][sbc + 8]  = b1;
    *(us8*)&Bs[0][sbr][sbc + 16] = b2;
    *(us8*)&Bs[0][sbr][sbc + 24] = b3;
    __syncthreads();

    for (int t = 0; t < nk; t++) {
        const int cb = t & 1;
        if (t + 1 < nk) {
            int off = (t + 1) << 6;
            a0 = *(const us8*)(Arow + off);
            a1 = *(const us8*)(Arow + off + 8);
            b0 = *(const us8*)(Wrow + off);
            b1 = *(const us8*)(Wrow + off + 8);
            b2 = *(const us8*)(Wrow + off + 16);
            b3 = *(const us8*)(Wrow + off + 24);
        }
#pragma unroll
        for (int ks = 0; ks < 2; ks++) {
            s8 af[2], bfr[4];
#pragma unroll
            for (int i = 0; i < 2; i++) af[i] = *(const s8*)&As[cb][wr + i * 16 + lm][ks * 32 + quad * 8];
#pragma unroll
            for (int j = 0; j < 4; j++) bfr[j] = *(const s8*)&Bs[cb][wc + j * 16 + lm][ks * 32 + quad * 8];
#pragma unroll
            for (int i = 0; i < 2; i++)
#pragma unroll
                for (int j = 0; j < 4; j++)
                    acc[i][j] = __builtin_amdgcn_mfma_f32_16x16x32_bf16(af[i], bfr[j], acc[i][j], 0, 0, 0);
        }
        if (t + 1 < nk) {
            const int nb = cb ^ 1;
            *(us8*)&As[nb][sar][sac]     = a0;
            *(us8*)&As[nb][sar][sac + 8] = a1;
            *(us8*)&Bs[nb][sbr][sbc]      = b0;
            *(us8*)&Bs[nb][sbr][sbc + 8]  = b1;
            *(us8*)&Bs[nb][sbr][sbc + 16] = b2;
            *(us8*)&Bs[nb][sbr][sbc + 24] = b3;
            __syncthreads();
        }
    }

#pragma unroll
    for (int j = 0; j < 4; j++) {
        int n = bn + wc + j * 16 + lm;
        float bv = bias[n];
#pragma unroll
        for (int i = 0; i < 2; i++) {
#pragma unroll
            for (int r = 0; r < 4; r++) {
                int m = bm + wr + i * 16 + quad * 4 + r;
                float v = acc[i][j][r] + bv;
                if (RELU) v = fmaxf(v, 0.f);
                C[(size_t)m * N + n] = f2b(v);
            }
        }
    }
}

// ============ Fused flash attention (verified R8 structure) ============
template <int CAUSAL>
__global__ __launch_bounds__(256) void flash_k(
    const u16* __restrict__ Q, int qs,
    const u16* __restrict__ Kp, int ks,
    const u16* __restrict__ V, int vs,
    u16* __restrict__ O, int Sq, int Sk)
{
    __shared__ u16 Qs[64][72];
    __shared__ u16 Ks[128][72];
    __shared__ u16 Vs[64][136];
    __shared__ u16 Ps[4][16][136];
    const int bm = blockIdx.x * 64;
    const int bh = blockIdx.y, b = bh >> 3, h = bh & 7;
    const int tid = threadIdx.x;
    const int wave = tid >> 6, lane = tid & 63;
    const int lm = lane & 15, quad = lane >> 4;

    const u16* Qb = Q + (size_t)(b * Sq + bm) * qs + h * HD;
    {
        int r = tid >> 2, c = (tid & 3) * 16;
        *(us8*)&Qs[r][c]     = *(const us8*)(Qb + (size_t)r * qs + c);
        *(us8*)&Qs[r][c + 8] = *(const us8*)(Qb + (size_t)r * qs + c + 8);
    }

    float mrow[4], lrow[4];
    f4 o[4];
#pragma unroll
    for (int r = 0; r < 4; r++) { mrow[r] = -1e30f; lrow[r] = 0.f; }
#pragma unroll
    for (int nt = 0; nt < 4; nt++) o[nt] = (f4)(0.f);

    const u16* Kb = Kp + (size_t)(b * Sk) * ks + h * HD;
    const u16* Vb = V + (size_t)(b * Sk) * vs + h * HD;
    int nkt = Sk >> 7;
    if (CAUSAL) { int lim = (bm + 63) / 128 + 1; if (lim < nkt) nkt = lim; }

    const int vd = tid & 63, vkb = tid >> 6;
    const int kr = tid >> 3, kc8 = (tid & 7) * 8;

    for (int kt = 0; kt < nkt; kt++) {
        const u16* Kt = Kb + ((size_t)kt << 7) * ks;
        const u16* Vt = Vb + ((size_t)kt << 7) * vs;
#pragma unroll
        for (int p = 0; p < 4; p++) {
            int r = p * 32 + kr;
            *(us8*)&Ks[r][kc8] = *(const us8*)(Kt + (size_t)r * ks + kc8);
        }
#pragma unroll
        for (int p = 0; p < 32; p++) {
            int kv = p * 4 + vkb;
            Vs[vd][kv] = Vt[(size_t)kv * vs + vd];
        }
        __syncthreads();

        f4 sa[8];
#pragma unroll
        for (int nt = 0; nt < 8; nt++) sa[nt] = (f4)(0.f);
#pragma unroll
        for (int ks2 = 0; ks2 < 2; ks2++) {
            s8 aq = *(const s8*)&Qs[wave * 16 + lm][ks2 * 32 + quad * 8];
#pragma unroll
            for (int nt = 0; nt < 8; nt++) {
                s8 bk = *(const s8*)&Ks[nt * 16 + lm][ks2 * 32 + quad * 8];
                sa[nt] = __builtin_amdgcn_mfma_f32_16x16x32_bf16(aq, bk, sa[nt], 0, 0, 0);
            }
        }
        float tmx[4] = {-1e30f, -1e30f, -1e30f, -1e30f};
#pragma unroll
        for (int nt = 0; nt < 8; nt++) {
#pragma unroll
            for (int r = 0; r < 4; r++) {
                float v = sa[nt][r] * 0.125f;
                if (CAUSAL) {
                    int col = (kt << 7) + nt * 16 + lm;
                    int row = bm + wave * 16 + quad * 4 + r;
                    if (col > row) v = -1e30f;
                }
                sa[nt][r] = v;
                tmx[r] = fmaxf(tmx[r], v);
            }
        }
#pragma unroll
        for (int st = 1; st < 16; st <<= 1)
#pragma unroll
            for (int r = 0; r < 4; r++) tmx[r] = fmaxf(tmx[r], __shfl_xor(tmx[r], st));
        float al[4];
#pragma unroll
        for (int r = 0; r < 4; r++) {
            float mn = fmaxf(mrow[r], tmx[r]);
            al[r] = __expf(mrow[r] - mn);
            mrow[r] = mn;
        }
        float ts[4] = {0.f, 0.f, 0.f, 0.f};
#pragma unroll
        for (int nt = 0; nt < 8; nt++) {
#pragma unroll
            for (int r = 0; r < 4; r++) {
                float pe = __expf(sa[nt][r] - mrow[r]);
                sa[nt][r] = pe;
                ts[r] += pe;
            }
        }
#pragma unroll
        for (int st = 1; st < 16; st <<= 1)
#pragma unroll
            for (int r = 0; r < 4; r++) ts[r] += __shfl_xor(ts[r], st);
#pragma unroll
        for (int r = 0; r < 4; r++) lrow[r] = lrow[r] * al[r] + ts[r];
#pragma unroll
        for (int nt = 0; nt < 4; nt++)
#pragma unroll
            for (int r = 0; r < 4; r++) o[nt][r] *= al[r];
#pragma unroll
        for (int nt = 0; nt < 8; nt++)
#pragma unroll
            for (int r = 0; r < 4; r++)
                Ps[wave][quad * 4 + r][nt * 16 + lm] = f2b(sa[nt][r]);
#pragma unroll
        for (int kc = 0; kc < 4; kc++) {
            s8 ap = *(const s8*)&Ps[wave][lm][kc * 32 + quad * 8];
#pragma unroll
            for (int nt = 0; nt < 4; nt++) {
                s8 bv = *(const s8*)&Vs[nt * 16 + lm][kc * 32 + quad * 8];
                o[nt] = __builtin_amdgcn_mfma_f32_16x16x32_bf16(ap, bv, o[nt], 0, 0, 0);
            }
        }
        __syncthreads();
    }

    float inv[4];
#pragma unroll
    for (int r = 0; r < 4; r++) inv[r] = 1.f / lrow[r];
#pragma unroll
    for (int nt = 0; nt < 4; nt++) {
#pragma unroll
        for (int r = 0; r < 4; r++) {
            int m = bm + wave * 16 + quad * 4 + r;
            O[(size_t)(b * Sq + m) * DM + h * HD + nt * 16 + lm] = f2b(o[nt][r] * inv[r]);
        }
    }
}

// ---------------- layernorm: 1 wave per row of 512, no barriers ----------------
__global__ __launch_bounds__(256) void ln_k(u16* __restrict__ x,
                                            const float* __restrict__ g,
                                            const float* __restrict__ b)
{
    const int wave = threadIdx.x >> 6, lane = threadIdx.x & 63;
    const int row = blockIdx.x * 4 + wave;
    u16* xr = x + (size_t)row * DM + lane * 8;
    us8 v8 = *(const us8*)xr;
    float v[8];
    float s = 0.f;
#pragma unroll
    for (int e = 0; e < 8; e++) { v[e] = b2f(v8[e]); s += v[e]; }
#pragma unroll
    for (int st = 1; st < 64; st <<= 1) s += __shfl_xor(s, st);
    float mean = s * (1.f / DM);
    float q = 0.f;
#pragma unroll
    for (int e = 0; e < 8; e++) { float d = v[e] - mean; q += d * d; }
#pragma unroll
    for (int st = 1; st < 64; st <<= 1) q += __shfl_xor(q, st);
    float rstd = rsqrtf(q * (1.f / DM) + 1e-5f);
    f4 g0 = *(const f4*)(g + lane * 8), g1 = *(const f4*)(g + lane * 8 + 4);
    f4 b0 = *(const f4*)(b + lane * 8), b1 = *(const f4*)(b + lane * 8 + 4);
    us8 o;
#pragma unroll
    for (int e = 0; e < 4; e++) {
        o[e]     = f2b((v[e]     - mean) * rstd * g0[e] + b0[e]);
        o[e + 4] = f2b((v[e + 4] - mean) * rstd * g1[e] + b1[e]);
    }
    *(us8*)xr = o;
}

// ---------------- host orchestration ----------------
static inline dim3 mg64(int M, int N) { return dim3(N / 64, M / 64); }
static inline dim3 mg32(int M, int N) { return dim3(N / 64, M / 32); }
static inline dim3 mg128(int M, int N) { return dim3(N / 128, M / 64); }

extern "C" void kernel_launch(void* const* d_in, const int* in_sizes, int n_in,
                              void* d_out, int out_size, void* d_ws, size_t ws_size,
                              hipStream_t stream)
{
    const float* src       = (const float*)d_in[0];
    const float* tgt       = (const float*)d_in[1];
    const float* enc_in_w  = (const float*)d_in[2];
    const float* enc_in_b  = (const float*)d_in[3];
    const float* dec_in_w  = (const float*)d_in[4];
    const float* dec_in_b  = (const float*)d_in[5];
    const float* out_w     = (const float*)d_in[6];
    const float* out_b     = (const float*)d_in[7];
    const float* enc_attn_w = (const float*)d_in[8];
    const float* enc_attn_b = (const float*)d_in[9];
    const float* enc_out_w  = (const float*)d_in[10];
    const float* enc_out_b  = (const float*)d_in[11];
    const float* enc_ff1_w  = (const float*)d_in[12];
    const float* enc_ff1_b  = (const float*)d_in[13];
    const float* enc_ff2_w  = (const float*)d_in[14];
    const float* enc_ff2_b  = (const float*)d_in[15];
    const float* enc_ln1_g  = (const float*)d_in[16];
    const float* enc_ln1_b  = (const float*)d_in[17];
    const float* enc_ln2_g  = (const float*)d_in[18];
    const float* enc_ln2_b  = (const float*)d_in[19];
    const float* dec_sa_w     = (const float*)d_in[20];
    const float* dec_sa_b     = (const float*)d_in[21];
    const float* dec_sa_out_w = (const float*)d_in[22];
    const float* dec_sa_out_b = (const float*)d_in[23];
    const float* dec_ca_w     = (const float*)d_in[24];
    const float* dec_ca_b     = (const float*)d_in[25];
    const float* dec_ca_out_w = (const float*)d_in[26];
    const float* dec_ca_out_b = (const float*)d_in[27];
    const float* dec_ff1_w    = (const float*)d_in[28];
    const float* dec_ff1_b    = (const float*)d_in[29];
    const float* dec_ff2_w    = (const float*)d_in[30];
    const float* dec_ff2_b    = (const float*)d_in[31];
    const float* dec_ln1_g    = (const float*)d_in[32];
    const float* dec_ln1_b    = (const float*)d_in[33];
    const float* dec_ln2_g    = (const float*)d_in[34];
    const float* dec_ln2_b    = (const float*)d_in[35];
    const float* dec_ln3_g    = (const float*)d_in[36];
    const float* dec_ln3_b    = (const float*)d_in[37];

    const int ME = BB * SEQ;  // 2048
    const int MD = BB * TGT;  // 1024
    const int BH = BB * NH;   // 32
    const float SQD = 22.627416997969522f;  // sqrt(512)

    const size_t SZ_ATTN = (size_t)NL * 3 * DM * DM;
    const size_t SZ_OUT  = (size_t)NL * DM * DM;
    const size_t SZ_FF   = (size_t)NL * FFD * DM;

    // ---- workspace layout ----
    float* fp = (float*)d_ws;
    float* kvbias = fp; fp += NL * 2 * DM;
    u16* p = (u16*)fp;
    u16* xa   = p; p += (size_t)ME * DM;
    u16* xb   = p; p += (size_t)ME * DM;
    u16* reg1 = p; p += (size_t)ME * FFD;
    u16* tbuf = p; p += (size_t)ME * DM;
    u16* ya   = p; p += (size_t)MD * DM;
    u16* yb   = p; p += (size_t)MD * DM;
    u16* kvall = p; p += (size_t)ME * NL * 2 * DM;
    u16* src_b     = p; p += (size_t)ME * HD;
    u16* tgt_b     = p; p += (size_t)MD * HD;
    u16* enc_in_wb = p; p += (size_t)DM * HD;
    u16* dec_in_wb = p; p += (size_t)DM * HD;
    u16* out_wb    = p; p += (size_t)HD * DM;
    u16* enc_at_wb = p; p += SZ_ATTN;
    u16* enc_ow_wb = p; p += SZ_OUT;
    u16* enc_f1_wb = p; p += SZ_FF;
    u16* enc_f2_wb = p; p += SZ_FF;
    u16* dec_sa_wb = p; p += SZ_ATTN;
    u16* dec_sao_wb = p; p += SZ_OUT;
    u16* dec_ca_wb = p; p += SZ_ATTN;
    u16* dec_cao_wb = p; p += SZ_OUT;
    u16* dec_f1_wb = p; p += SZ_FF;
    u16* dec_f2_wb = p; p += SZ_FF;
    u16* kvstack   = p; p += (size_t)NL * 2 * DM * DM;

    // ===== single batched cast (21 segments, 8 elems/thread) =====
    CastSegs cs;
    int ns = 0;
    auto seg = [&](const float* s, u16* d, size_t n) {
        cs.src[ns] = s; cs.dst[ns] = d;
        cs.cum[ns + 1] = cs.cum[ns] + (int)(n / 8);
        ns++;
    };
    cs.cum[0] = 0;
    seg(src,          src_b,     (size_t)ME * HD);
    seg(tgt,          tgt_b,     (size_t)MD * HD);
    seg(enc_in_w,     enc_in_wb, (size_t)DM * HD);
    seg(dec_in_w,     dec_in_wb, (size_t)DM * HD);
    seg(out_w,        out_wb,    (size_t)HD * DM);
    seg(enc_attn_w,   enc_at_wb, SZ_ATTN);
    seg(enc_out_w,    enc_ow_wb, SZ_OUT);
    seg(enc_ff1_w,    enc_f1_wb, SZ_FF);
    seg(enc_ff2_w,    enc_f2_wb, SZ_FF);
    seg(dec_sa_w,     dec_sa_wb, SZ_ATTN);
    seg(dec_sa_out_w, dec_sao_wb, SZ_OUT);
    seg(dec_ca_w,     dec_ca_wb, SZ_ATTN);
    seg(dec_ca_out_w, dec_cao_wb, SZ_OUT);
    seg(dec_ff1_w,    dec_f1_wb, SZ_FF);
    seg(dec_ff2_w,    dec_f2_wb, SZ_FF);
    for (int i = 0; i < NL; i++)
        seg(dec_ca_w + (size_t)i * 3 * DM * DM + (size_t)DM * DM,
            kvstack + (size_t)i * 2 * DM * DM, (size_t)2 * DM * DM);
    cs.nseg = ns;
    castseg_k<<<(cs.cum[ns] + 255) / 256, 256, 0, stream>>>(cs);
    kvbias_k<<<(NL * 2 * DM + 255) / 256, 256, 0, stream>>>(dec_ca_b, kvbias);

    // ===== encoder =====
    mgemm_k<0, 0, 64, 1><<<mg64(ME, DM), 256, 0, stream>>>(src_b, enc_in_wb, enc_in_b, nullptr, xa, ME, DM, HD, SQD);

    u16* cur = xa; u16* alt = xb;
    for (int i = 0; i < NL; i++) {
        const u16* W = enc_at_wb + (size_t)i * 3 * DM * DM;
        const float* Bw = enc_attn_b + (size_t)i * 3 * DM;
        mgemm128_k<0><<<mg128(ME, 3 * DM), 256, 0, stream>>>(cur, W, Bw, reg1, ME, 3 * DM, DM);
        flash_k<0><<<dim3(SEQ / 64, BH), 256, 0, stream>>>(reg1, 3 * DM, reg1 + DM, 3 * DM, reg1 + 2 * DM, 3 * DM, tbuf, SEQ, SEQ);
        mgemm_k<0, 0, 32, 0><<<mg32(ME, DM), 256, 0, stream>>>(tbuf, enc_ow_wb + (size_t)i * DM * DM, enc_out_b + (size_t)i * DM, cur, alt, ME, DM, DM, 1.f);
        ln_k<<<ME / 4, 256, 0, stream>>>(alt, enc_ln1_g + (size_t)i * DM, enc_ln1_b + (size_t)i * DM);
        { u16* t = cur; cur = alt; alt = t; }
        mgemm128_k<1><<<mg128(ME, FFD), 256, 0, stream>>>(cur, enc_f1_wb + (size_t)i * FFD * DM, enc_ff1_b + (size_t)i * FFD, reg1, ME, FFD, DM);
        mgemm_k<0, 0, 32, 0><<<mg32(ME, DM), 256, 0, stream>>>(reg1, enc_f2_wb + (size_t)i * DM * FFD, enc_ff2_b + (size_t)i * DM, cur, alt, ME, DM, FFD, 1.f);
        ln_k<<<ME / 4, 256, 0, stream>>>(alt, enc_ln2_g + (size_t)i * DM, enc_ln2_b + (size_t)i * DM);
        { u16* t = cur; cur = alt; alt = t; }
    }
    u16* mem = cur;  // xa (even swaps)

    // ===== all 6 layers' cross-attn K/V projections in one GEMM =====
    mgemm128_k<0><<<mg128(ME, NL * 2 * DM), 256, 0, stream>>>(mem, kvstack, kvbias, kvall, ME, NL * 2 * DM, DM);

    // ===== decoder =====
    mgemm_k<0, 0, 32, 2><<<mg32(MD, DM), 256, 0, stream>>>(tgt_b, dec_in_wb, dec_in_b, nullptr, ya, MD, DM, HD, SQD);

    u16* dc = ya; u16* da = yb;
    for (int i = 0; i < NL; i++) {
        // --- self-attention (causal), fused QKV ---
        const u16* W = dec_sa_wb + (size_t)i * 3 * DM * DM;
        const float* Bw = dec_sa_b + (size_t)i * 3 * DM;
        mgemm128_k<0><<<mg128(MD, 3 * DM), 256, 0, stream>>>(dc, W, Bw, reg1, MD, 3 * DM, DM);
        flash_k<1><<<dim3(TGT / 64, BH), 256, 0, stream>>>(reg1, 3 * DM, reg1 + DM, 3 * DM, reg1 + 2 * DM, 3 * DM, tbuf, TGT, TGT);
        mgemm_k<0, 0, 32, 0><<<mg32(MD, DM), 256, 0, stream>>>(tbuf, dec_sao_wb + (size_t)i * DM * DM, dec_sa_out_b + (size_t)i * DM, dc, da, MD, DM, DM, 1.f);
        ln_k<<<MD / 4, 256, 0, stream>>>(da, dec_ln1_g + (size_t)i * DM, dec_ln1_b + (size_t)i * DM);
        { u16* t = dc; dc = da; da = t; }

        // --- cross-attention (K/V precomputed in kvall) ---
        const u16* Wc = dec_ca_wb + (size_t)i * 3 * DM * DM;
        const float* Bc = dec_ca_b + (size_t)i * 3 * DM;
        u16* qbuf = reg1;
        mgemm_k<0, 0, 32, 0><<<mg32(MD, DM), 256, 0, stream>>>(dc, Wc, Bc, nullptr, qbuf, MD, DM, DM, 1.f);
        const u16* kvl = kvall + (size_t)i * 2 * DM;
        flash_k<0><<<dim3(TGT / 64, BH), 256, 0, stream>>>(qbuf, DM, kvl, NL * 2 * DM, kvl + DM, NL * 2 * DM, tbuf, TGT, SEQ);
        mgemm_k<0, 0, 32, 0><<<mg32(MD, DM), 256, 0, stream>>>(tbuf, dec_cao_wb + (size_t)i * DM * DM, dec_ca_out_b + (size_t)i * DM, dc, da, MD, DM, DM, 1.f);
        ln_k<<<MD / 4, 256, 0, stream>>>(da, dec_ln2_g + (size_t)i * DM, dec_ln2_b + (size_t)i * DM);
        { u16* t = dc; dc = da; da = t; }

        // --- feed-forward ---
        mgemm128_k<1><<<mg128(MD, FFD), 256, 0, stream>>>(dc, dec_f1_wb + (size_t)i * FFD * DM, dec_ff1_b + (size_t)i * FFD, reg1, MD, FFD, DM);
        mgemm_k<0, 0, 32, 0><<<mg32(MD, DM), 256, 0, stream>>>(reg1, dec_f2_wb + (size_t)i * DM * FFD, dec_ff2_b + (size_t)i * DM, dc, da, MD, DM, FFD, 1.f);
        ln_k<<<MD / 4, 256, 0, stream>>>(da, dec_ln3_g + (size_t)i * DM, dec_ln3_b + (size_t)i * DM);
        { u16* t = dc; dc = da; da = t; }
    }

    // ===== final projection (N=64, fp32 into d_out) =====
    mgemm_k<0, 1, 32, 0><<<mg32(MD, HD), 256, 0, stream>>>(dc, out_wb, out_b, nullptr, (float*)d_out, MD, HD, DM, 1.f);
}